// Round 7
// baseline (618.971 us; speedup 1.0000x reference)
//
#include <hip/hip_runtime.h>
#include <stdint.h>

#define B_ 4
#define T_ 2048
#define D_ 2048
#define H_ 16
#define HD_ 128
#define I_ 5632
#define K_ 512
#define S_ 2048
#define D3_ (3 * D_)

typedef float f32x4 __attribute__((ext_vector_type(4)));
typedef short s16x8 __attribute__((ext_vector_type(8)));
typedef __bf16 bf16x8 __attribute__((ext_vector_type(8)));

// ---------- mfma wrapper robust to builtin operand type (short8 vs bf16x8) ----------
template <typename V>
__device__ __forceinline__ auto mfma_try(V a, V b, f32x4 c, int)
    -> decltype(__builtin_amdgcn_mfma_f32_16x16x32_bf16(a, b, c, 0, 0, 0)) {
  return __builtin_amdgcn_mfma_f32_16x16x32_bf16(a, b, c, 0, 0, 0);
}
template <typename V>
__device__ __forceinline__ f32x4 mfma_try(V a, V b, f32x4 c, long) {
  return __builtin_amdgcn_mfma_f32_16x16x32_bf16(
      __builtin_bit_cast(bf16x8, a), __builtin_bit_cast(bf16x8, b), c, 0, 0, 0);
}
__device__ __forceinline__ f32x4 mfma_bf16(s16x8 a, s16x8 b, f32x4 c) {
  return mfma_try(a, b, c, 0);
}

__device__ __forceinline__ void gl_lds16(const void* g, void* l) {
  __builtin_amdgcn_global_load_lds((const __attribute__((address_space(1))) void*)g,
                                   (__attribute__((address_space(3))) void*)l, 16, 0, 0);
}

__device__ __forceinline__ unsigned short f2bf(float f) {
  unsigned u = __float_as_uint(f);
  u += 0x7FFFu + ((u >> 16) & 1);
  return (unsigned short)(u >> 16);
}
__device__ __forceinline__ float bf2f(unsigned short s) {
  return __uint_as_float(((unsigned)s) << 16);
}

// ---------- K1: copy hidden -> out, fused with router scores ----------
__global__ __launch_bounds__(256) void k_copy_scores(const float4* __restrict__ hid,
                                                     float4* __restrict__ dst,
                                                     const float4* __restrict__ rw,
                                                     const float* __restrict__ rb,
                                                     float* __restrict__ scores) {
  int row = blockIdx.x, t = threadIdx.x;
  const float4* hr = hid + (size_t)row * (D_ / 4);
  float4* dr = dst + (size_t)row * (D_ / 4);
  float acc = 0.f;
#pragma unroll
  for (int i = 0; i < 2; i++) {
    float4 v = hr[t + i * 256];
    dr[t + i * 256] = v;
    float4 w = rw[t + i * 256];
    acc += v.x * w.x + v.y * w.y + v.z * w.z + v.w * w.w;
  }
#pragma unroll
  for (int d = 32; d; d >>= 1) acc += __shfl_xor(acc, d);
  __shared__ float red[4];
  if ((t & 63) == 0) red[t >> 6] = acc;
  __syncthreads();
  if (t == 0) scores[row] = red[0] + red[1] + red[2] + red[3] + rb[0];
}

// ---------- K3: exact top-k (bitonic, matches jax.lax.top_k tie-break) ----------
__global__ __launch_bounds__(1024) void k_topk(const float* __restrict__ scores,
                                               int* __restrict__ pos) {
  __shared__ unsigned long long keys[T_];
  __shared__ int sidx[K_];
  int b = blockIdx.x, t = threadIdx.x;
  for (int i = t; i < T_; i += 1024) {
    unsigned u = __float_as_uint(scores[b * T_ + i]);
    u = (u & 0x80000000u) ? ~u : (u | 0x80000000u);
    keys[i] = ((unsigned long long)u << 32) | (unsigned)(~(unsigned)i);
  }
  __syncthreads();
  for (int k = 2; k <= T_; k <<= 1)
    for (int j = k >> 1; j > 0; j >>= 1) {
      for (int i = t; i < T_; i += 1024) {
        int l = i ^ j;
        if (l > i) {
          unsigned long long a = keys[i], c = keys[l];
          bool desc = ((i & k) == 0);
          if (desc ? (a < c) : (a > c)) { keys[i] = c; keys[l] = a; }
        }
      }
      __syncthreads();
    }
  if (t < K_) sidx[t] = (int)(~(unsigned)(keys[t] & 0xFFFFFFFFull));
  __syncthreads();
  for (int k = 2; k <= K_; k <<= 1)
    for (int j = k >> 1; j > 0; j >>= 1) {
      if (t < K_) {
        int i = t, l = i ^ j;
        if (l > i && l < K_) {
          int a = sidx[i], c = sidx[l];
          bool asc = ((i & k) == 0);
          if (asc ? (a > c) : (a < c)) { sidx[i] = c; sidx[l] = a; }
        }
      }
      __syncthreads();
    }
  if (t < K_) pos[b * K_ + t] = sidx[t];
}

// ---------- K4: gather + RMS1 + gate + rope tables ----------
__global__ __launch_bounds__(256) void k_gather(const float* __restrict__ hidden,
    const int* __restrict__ pos, const float* __restrict__ scores,
    const float* __restrict__ ln1w, float* __restrict__ x,
    unsigned short* __restrict__ xn, float* __restrict__ gate,
    float* __restrict__ cosb, float* __restrict__ sinb) {
  int s = blockIdx.x, t = threadIdx.x;
  int b = s >> 9, p = pos[s];
  const float* src = hidden + ((size_t)b * T_ + p) * D_;
  float v[8];
  float ss = 0.f;
#pragma unroll
  for (int i = 0; i < 8; i++) { v[i] = src[t + i * 256]; ss += v[i] * v[i]; }
  __shared__ float red[4];
#pragma unroll
  for (int d = 32; d; d >>= 1) ss += __shfl_xor(ss, d);
  if ((t & 63) == 0) red[t >> 6] = ss;
  __syncthreads();
  ss = red[0] + red[1] + red[2] + red[3];
  float scale = rsqrtf(ss / (float)D_ + 1e-6f);
  float* xd = x + (size_t)s * D_;
  unsigned short* xnd = xn + (size_t)s * D_;
#pragma unroll
  for (int i = 0; i < 8; i++) {
    int c = t + i * 256;
    xd[c] = v[i];
    xnd[c] = f2bf(v[i] * scale * ln1w[c]);
  }
  if (t == 0) gate[s] = 1.f / (1.f + expf(-scores[b * T_ + p]));
  if (t < 64) {
    float invf = powf(10000.0f, -(float)t / 64.0f);
    float f = (float)p * invf;
    cosb[s * 64 + t] = cosf(f);
    sinb[s * 64 + t] = sinf(f);
  }
}

// ---------- K5: transpose + f32->bf16 (weights to Bt layout), ushort4 writes ----------
__global__ __launch_bounds__(256) void k_transpose(const float* __restrict__ src,
                                                   unsigned short* __restrict__ dst,
                                                   int R, int C) {
  __shared__ float tile[32][33];
  int tx = threadIdx.x & 31, ty = threadIdx.x >> 5;
  int c0 = blockIdx.x * 32, r0 = blockIdx.y * 32;
#pragma unroll
  for (int i = 0; i < 4; i++) {
    int r = ty + i * 8;
    tile[r][tx] = src[(size_t)(r0 + r) * C + c0 + tx];
  }
  __syncthreads();
  int drow = threadIdx.x >> 3;        // 0..31 : dst row (c index)
  int dc4 = (threadIdx.x & 7) * 4;    // dst col base (r index)
  ushort4 v;
  v.x = f2bf(tile[dc4 + 0][drow]);
  v.y = f2bf(tile[dc4 + 1][drow]);
  v.z = f2bf(tile[dc4 + 2][drow]);
  v.w = f2bf(tile[dc4 + 3][drow]);
  *(ushort4*)&dst[(size_t)(c0 + drow) * R + r0 + dc4] = v;
}

// ======================================================================
// GEMM template (BK=32, dbuf, counted vmcnt, swizzle, read->MFMA overlap).
// LDS rows are 64 B. Swizzle involution: byte ^= (((row>>1)&3)<<4)
//   (bank-quad = (row&1)*4 + ((row>>1)&3 ^ g) -> 2 lanes/bank = free, m136).
//   Applied to the GLOBAL source (gl_lds dest must be linear) and the read.
// Schedule per K-tile t (buffer b = t&1), L = loads/thread/tile:
//   vmcnt(L) -> barrier -> ds_read frags -> setprio(1) MFMA setprio(0)
//     (compiler emits counted lgkmcnt -> read tail overlaps MFMA head)
//   -> lgkmcnt(0) -> barrier [all waves' reads of buf b done]
//   -> stage tile t+2 into buf b (loads stay in flight across 2 K-tiles)
// ======================================================================
#define SWZ(row) ((((row) >> 1) & 3) << 4)

// 512-thread staging helpers
__device__ __forceinline__ void stage16k(const unsigned short* __restrict__ g, int ldK,
                                         int row0, int k0, char* lds, int tid) {
#pragma unroll
  for (int c = 0; c < 2; c++) {
    int off = c * 8192 + tid * 16;  // 16 KB = 256 rows
    int row = off >> 6;
    int cb = (off & 63) ^ SWZ(row);
    gl_lds16(g + (size_t)(row0 + row) * ldK + k0 + (cb >> 1), lds + off);
  }
}
__device__ __forceinline__ void stage8k(const unsigned short* __restrict__ g, int ldK,
                                        int row0, int k0, char* lds, int tid) {
  int off = tid * 16;  // 8 KB = 128 rows (512 thr)
  int row = off >> 6;
  int cb = (off & 63) ^ SWZ(row);
  gl_lds16(g + (size_t)(row0 + row) * ldK + k0 + (cb >> 1), lds + off);
}
// 256-thread staging helper (128 rows)
__device__ __forceinline__ void stage128r(const unsigned short* __restrict__ g, int ldK,
                                          int row0, int k0, char* lds, int tid) {
#pragma unroll
  for (int c = 0; c < 2; c++) {
    int off = c * 4096 + tid * 16;  // 8 KB = 128 rows (256 thr)
    int row = off >> 6;
    int cb = (off & 63) ^ SWZ(row);
    gl_lds16(g + (size_t)(row0 + row) * ldK + k0 + (cb >> 1), lds + off);
  }
}
__device__ __forceinline__ s16x8 ldfrag(const char* base, int row, int g) {
  return *(const s16x8*)(base + row * 64 + ((g * 16) ^ SWZ(row)));
}

// ---------- K6: fused QKV GEMM, 256x128 tile, 8 waves, bias epilogue ----------
__global__ __launch_bounds__(512, 2) void k_gemm_qkv8(const unsigned short* __restrict__ A,
    const unsigned short* __restrict__ Bt, unsigned short* __restrict__ C,
    const float* __restrict__ bq, const float* __restrict__ bk,
    const float* __restrict__ bv) {
  alignas(16) __shared__ short As[2][256 * 32];
  alignas(16) __shared__ short Bs[2][128 * 32];
  int tid = threadIdx.x;
  int lane = tid & 63, g = lane >> 4, lr = lane & 15;
  int wid = tid >> 6, wm = wid >> 1, wn = wid & 1;
  int m0 = blockIdx.x * 256, n0 = blockIdx.y * 128;
  f32x4 zero4 = {0.f, 0.f, 0.f, 0.f};
  f32x4 acc[4][4];
#pragma unroll
  for (int m = 0; m < 4; m++)
#pragma unroll
    for (int n = 0; n < 4; n++) acc[m][n] = zero4;
  const int nkt = D_ / 32;
  stage16k(A, D_, m0, 0, (char*)As[0], tid);
  stage8k(Bt, D_, n0, 0, (char*)Bs[0], tid);
  stage16k(A, D_, m0, 32, (char*)As[1], tid);
  stage8k(Bt, D_, n0, 32, (char*)Bs[1], tid);
  int arow = wm * 64 + lr;
  int brow = wn * 64 + lr;
  for (int t = 0; t < nkt; t++) {
    int b = t & 1;
    const char* Ab = (const char*)As[b];
    const char* Bb = (const char*)Bs[b];
    if (t + 1 < nkt) asm volatile("s_waitcnt vmcnt(3)" ::: "memory");
    else             asm volatile("s_waitcnt vmcnt(0)" ::: "memory");
    __builtin_amdgcn_s_barrier();
    s16x8 af[4], bf4[4];
#pragma unroll
    for (int i = 0; i < 4; i++) af[i] = ldfrag(Ab, arow + i * 16, g);
#pragma unroll
    for (int i = 0; i < 4; i++) bf4[i] = ldfrag(Bb, brow + i * 16, g);
    __builtin_amdgcn_s_setprio(1);
#pragma unroll
    for (int m = 0; m < 4; m++)
#pragma unroll
      for (int n = 0; n < 4; n++) acc[m][n] = mfma_bf16(af[m], bf4[n], acc[m][n]);
    __builtin_amdgcn_s_setprio(0);
    asm volatile("s_waitcnt lgkmcnt(0)" ::: "memory");
    __builtin_amdgcn_s_barrier();
    if (t + 2 < nkt) {
      stage16k(A, D_, m0, (t + 2) * 32, (char*)As[b], tid);
      stage8k(Bt, D_, n0, (t + 2) * 32, (char*)Bs[b], tid);
    }
  }
#pragma unroll
  for (int m = 0; m < 4; m++)
#pragma unroll
    for (int n = 0; n < 4; n++)
#pragma unroll
      for (int r = 0; r < 4; r++) {
        int row = m0 + wm * 64 + m * 16 + (g << 2) + r;
        int col = n0 + wn * 64 + n * 16 + lr;
        float bias = (col < D_) ? bq[col] : ((col < 2 * D_) ? bk[col - D_] : bv[col - 2 * D_]);
        C[(size_t)row * D3_ + col] = f2bf(acc[m][n][r] + bias);
      }
}

// ---------- K11: fused gate/up GEMM, 256x(128+128) tile, 8 waves, silu*mul ----------
__global__ __launch_bounds__(512, 2) void k_gemm_gup8(const unsigned short* __restrict__ A,
    const unsigned short* __restrict__ Bg, const unsigned short* __restrict__ Bu,
    unsigned short* __restrict__ act) {
  alignas(16) __shared__ short As[2][256 * 32];
  alignas(16) __shared__ short Bgs[2][128 * 32];
  alignas(16) __shared__ short Bus[2][128 * 32];
  int tid = threadIdx.x;
  int lane = tid & 63, g = lane >> 4, lr = lane & 15;
  int wid = tid >> 6, wm = wid >> 1, wn = wid & 1;
  int m0 = blockIdx.x * 256, n0 = blockIdx.y * 128;
  f32x4 zero4 = {0.f, 0.f, 0.f, 0.f};
  f32x4 ag[4][4], au[4][4];
#pragma unroll
  for (int m = 0; m < 4; m++)
#pragma unroll
    for (int n = 0; n < 4; n++) { ag[m][n] = zero4; au[m][n] = zero4; }
  const int nkt = D_ / 32;
  stage16k(A, D_, m0, 0, (char*)As[0], tid);
  stage8k(Bg, D_, n0, 0, (char*)Bgs[0], tid);
  stage8k(Bu, D_, n0, 0, (char*)Bus[0], tid);
  stage16k(A, D_, m0, 32, (char*)As[1], tid);
  stage8k(Bg, D_, n0, 32, (char*)Bgs[1], tid);
  stage8k(Bu, D_, n0, 32, (char*)Bus[1], tid);
  int arow = wm * 64 + lr;
  int brow = wn * 64 + lr;
  for (int t = 0; t < nkt; t++) {
    int b = t & 1;
    const char* Ab = (const char*)As[b];
    const char* Bgb = (const char*)Bgs[b];
    const char* Bub = (const char*)Bus[b];
    if (t + 1 < nkt) asm volatile("s_waitcnt vmcnt(4)" ::: "memory");
    else             asm volatile("s_waitcnt vmcnt(0)" ::: "memory");
    __builtin_amdgcn_s_barrier();
    s16x8 af[4], bg4[4], bu4[4];
#pragma unroll
    for (int i = 0; i < 4; i++) af[i] = ldfrag(Ab, arow + i * 16, g);
#pragma unroll
    for (int i = 0; i < 4; i++) bg4[i] = ldfrag(Bgb, brow + i * 16, g);
#pragma unroll
    for (int i = 0; i < 4; i++) bu4[i] = ldfrag(Bub, brow + i * 16, g);
    __builtin_amdgcn_s_setprio(1);
#pragma unroll
    for (int m = 0; m < 4; m++)
#pragma unroll
      for (int n = 0; n < 4; n++) {
        ag[m][n] = mfma_bf16(af[m], bg4[n], ag[m][n]);
        au[m][n] = mfma_bf16(af[m], bu4[n], au[m][n]);
      }
    __builtin_amdgcn_s_setprio(0);
    asm volatile("s_waitcnt lgkmcnt(0)" ::: "memory");
    __builtin_amdgcn_s_barrier();
    if (t + 2 < nkt) {
      stage16k(A, D_, m0, (t + 2) * 32, (char*)As[b], tid);
      stage8k(Bg, D_, n0, (t + 2) * 32, (char*)Bgs[b], tid);
      stage8k(Bu, D_, n0, (t + 2) * 32, (char*)Bus[b], tid);
    }
  }
#pragma unroll
  for (int m = 0; m < 4; m++)
#pragma unroll
    for (int n = 0; n < 4; n++)
#pragma unroll
      for (int r = 0; r < 4; r++) {
        int row = m0 + wm * 64 + m * 16 + (g << 2) + r;
        int col = n0 + wn * 64 + n * 16 + lr;
        float gv = ag[m][n][r], uv = au[m][n][r];
        float si = gv / (1.f + __expf(-gv));
        act[(size_t)row * I_ + col] = f2bf(si * uv);
      }
}

// ---------- K9: wo GEMM + residual, 128x128 tile, 4 waves, 64x64/wave ----------
__global__ __launch_bounds__(256, 3) void k_gemm_wo128(const unsigned short* __restrict__ A,
    const unsigned short* __restrict__ Bt, const float* __restrict__ xres,
    float* __restrict__ x1) {
  alignas(16) __shared__ short As[2][128 * 32];
  alignas(16) __shared__ short Bs[2][128 * 32];
  int tid = threadIdx.x;
  int lane = tid & 63, g = lane >> 4, lr = lane & 15;
  int w = tid >> 6;
  int wr = (w >> 1) * 64, wc = (w & 1) * 64;
  int m0 = blockIdx.x * 128, n0 = blockIdx.y * 128;
  f32x4 zero4 = {0.f, 0.f, 0.f, 0.f};
  f32x4 acc[4][4];
#pragma unroll
  for (int m = 0; m < 4; m++)
#pragma unroll
    for (int n = 0; n < 4; n++) acc[m][n] = zero4;
  const int nkt = D_ / 32;
  stage128r(A, D_, m0, 0, (char*)As[0], tid);
  stage128r(Bt, D_, n0, 0, (char*)Bs[0], tid);
  stage128r(A, D_, m0, 32, (char*)As[1], tid);
  stage128r(Bt, D_, n0, 32, (char*)Bs[1], tid);
  for (int t = 0; t < nkt; t++) {
    int b = t & 1;
    const char* Ab = (const char*)As[b];
    const char* Bb = (const char*)Bs[b];
    if (t + 1 < nkt) asm volatile("s_waitcnt vmcnt(4)" ::: "memory");
    else             asm volatile("s_waitcnt vmcnt(0)" ::: "memory");
    __builtin_amdgcn_s_barrier();
    s16x8 af[4], bf4[4];
#pragma unroll
    for (int i = 0; i < 4; i++) af[i] = ldfrag(Ab, wr + i * 16 + lr, g);
#pragma unroll
    for (int i = 0; i < 4; i++) bf4[i] = ldfrag(Bb, wc + i * 16 + lr, g);
    __builtin_amdgcn_s_setprio(1);
#pragma unroll
    for (int m = 0; m < 4; m++)
#pragma unroll
      for (int n = 0; n < 4; n++) acc[m][n] = mfma_bf16(af[m], bf4[n], acc[m][n]);
    __builtin_amdgcn_s_setprio(0);
    asm volatile("s_waitcnt lgkmcnt(0)" ::: "memory");
    __builtin_amdgcn_s_barrier();
    if (t + 2 < nkt) {
      stage128r(A, D_, m0, (t + 2) * 32, (char*)As[b], tid);
      stage128r(Bt, D_, n0, (t + 2) * 32, (char*)Bs[b], tid);
    }
  }
#pragma unroll
  for (int m = 0; m < 4; m++)
#pragma unroll
    for (int n = 0; n < 4; n++)
#pragma unroll
      for (int r = 0; r < 4; r++) {
        int row = m0 + wr + m * 16 + (g << 2) + r;
        int col = n0 + wc + n * 16 + lr;
        x1[(size_t)row * D_ + col] = acc[m][n][r] + xres[(size_t)row * D_ + col];
      }
}

// ---------- K12: down GEMM + residual + blend + scatter, 128x128 tile ----------
__global__ __launch_bounds__(256, 3) void k_gemm_down128(const unsigned short* __restrict__ A,
    const unsigned short* __restrict__ Bt, const float* __restrict__ x1,
    const float* __restrict__ x, const float* __restrict__ gate,
    const int* __restrict__ pos, float* __restrict__ out) {
  alignas(16) __shared__ short As[2][128 * 32];
  alignas(16) __shared__ short Bs[2][128 * 32];
  int tid = threadIdx.x;
  int lane = tid & 63, g = lane >> 4, lr = lane & 15;
  int w = tid >> 6;
  int wr = (w >> 1) * 64, wc = (w & 1) * 64;
  int m0 = blockIdx.x * 128, n0 = blockIdx.y * 128;
  f32x4 zero4 = {0.f, 0.f, 0.f, 0.f};
  f32x4 acc[4][4];
#pragma unroll
  for (int m = 0; m < 4; m++)
#pragma unroll
    for (int n = 0; n < 4; n++) acc[m][n] = zero4;
  const int nkt = I_ / 32;
  stage128r(A, I_, m0, 0, (char*)As[0], tid);
  stage128r(Bt, I_, n0, 0, (char*)Bs[0], tid);
  stage128r(A, I_, m0, 32, (char*)As[1], tid);
  stage128r(Bt, I_, n0, 32, (char*)Bs[1], tid);
  for (int t = 0; t < nkt; t++) {
    int b = t & 1;
    const char* Ab = (const char*)As[b];
    const char* Bb = (const char*)Bs[b];
    if (t + 1 < nkt) asm volatile("s_waitcnt vmcnt(4)" ::: "memory");
    else             asm volatile("s_waitcnt vmcnt(0)" ::: "memory");
    __builtin_amdgcn_s_barrier();
    s16x8 af[4], bf4[4];
#pragma unroll
    for (int i = 0; i < 4; i++) af[i] = ldfrag(Ab, wr + i * 16 + lr, g);
#pragma unroll
    for (int i = 0; i < 4; i++) bf4[i] = ldfrag(Bb, wc + i * 16 + lr, g);
    __builtin_amdgcn_s_setprio(1);
#pragma unroll
    for (int m = 0; m < 4; m++)
#pragma unroll
      for (int n = 0; n < 4; n++) acc[m][n] = mfma_bf16(af[m], bf4[n], acc[m][n]);
    __builtin_amdgcn_s_setprio(0);
    asm volatile("s_waitcnt lgkmcnt(0)" ::: "memory");
    __builtin_amdgcn_s_barrier();
    if (t + 2 < nkt) {
      stage128r(A, I_, m0, (t + 2) * 32, (char*)As[b], tid);
      stage128r(Bt, I_, n0, (t + 2) * 32, (char*)Bs[b], tid);
    }
  }
#pragma unroll
  for (int m = 0; m < 4; m++)
#pragma unroll
    for (int n = 0; n < 4; n++)
#pragma unroll
      for (int r = 0; r < 4; r++) {
        int srow = m0 + wr + m * 16 + (g << 2) + r;
        int col = n0 + wc + n * 16 + lr;
        float proc = acc[m][n][r] + x1[(size_t)srow * D_ + col];
        float gt = gate[srow];
        float xv = x[(size_t)srow * D_ + col];
        int bb = srow >> 9;
        int p = pos[srow];
        out[((size_t)bb * T_ + p) * D_ + col] = gt * proc + (1.f - gt) * xv;
      }
}

// ---------- K7: RoPE + head relayout (q,k row-major per head; v transposed) ----------
__global__ __launch_bounds__(256) void k_rope(const unsigned short* __restrict__ qkv,
    const float* __restrict__ cosb, const float* __restrict__ sinb,
    unsigned short* __restrict__ qh, unsigned short* __restrict__ kh,
    unsigned short* __restrict__ vT) {
  int s0 = blockIdx.x * 64;
  int h = blockIdx.y;
  int t = threadIdx.x;
#pragma unroll
  for (int i = 0; i < 16; i++) {
    int flat = t + i * 256;
    int r = flat >> 6, dp = flat & 63;
    int s = s0 + r;
    float c = cosb[s * 64 + dp], sn = sinb[s * 64 + dp];
    const unsigned short* qrow = qkv + (size_t)s * D3_ + h * HD_;
    float q1 = bf2f(qrow[dp]), q2 = bf2f(qrow[dp + 64]);
    unsigned short* qdst = qh + ((size_t)h * S_ + s) * HD_;
    qdst[dp] = f2bf(q1 * c - q2 * sn);
    qdst[dp + 64] = f2bf(q2 * c + q1 * sn);
    const unsigned short* krow = qrow + D_;
    float k1 = bf2f(krow[dp]), k2 = bf2f(krow[dp + 64]);
    unsigned short* kdst = kh + ((size_t)h * S_ + s) * HD_;
    kdst[dp] = f2bf(k1 * c - k2 * sn);
    kdst[dp + 64] = f2bf(k2 * c + k1 * sn);
  }
  __shared__ unsigned short vt[128][66];
#pragma unroll
  for (int i = 0; i < 32; i++) {
    int flat = t + i * 256;
    int r = flat >> 7, d = flat & 127;
    vt[d][r] = qkv[(size_t)(s0 + r) * D3_ + 2 * D_ + h * HD_ + d];
  }
  __syncthreads();
#pragma unroll
  for (int i = 0; i < 32; i++) {
    int flat = t + i * 256;
    int d = flat >> 6, sc = flat & 63;
    vT[((size_t)h * HD_ + d) * S_ + s0 + sc] = vt[d][sc];
  }
}

// ======================================================================
// K8: flash attention (q-tile 64, LPT order, swizzled LDS, dbuf KV)
// ======================================================================
__device__ __forceinline__ void stage_kv(const unsigned short* __restrict__ kh,
                                         const unsigned short* __restrict__ vT,
                                         size_t hbase, int kt, char* KsB, char* VsB, int tid) {
#pragma unroll
  for (int c = 0; c < 4; c++) {
    int off = c * 4096 + tid * 16;
    int row = off >> 8;
    int cb = (off & 255) ^ ((row & 7) << 4);
    gl_lds16(kh + hbase + (size_t)(kt * 64 + row) * HD_ + (cb >> 1), KsB + off);
  }
#pragma unroll
  for (int c = 0; c < 4; c++) {
    int off = c * 4096 + tid * 16;
    int row = off >> 7;
    int cb = (off & 127) ^ ((row & 7) << 4);
    gl_lds16(vT + hbase + (size_t)row * S_ + kt * 64 + (cb >> 1), VsB + off);
  }
}

__global__ __launch_bounds__(256, 2) void k_attn(const unsigned short* __restrict__ qh,
                                                 const unsigned short* __restrict__ kh,
                                                 const unsigned short* __restrict__ vT,
                                                 unsigned short* __restrict__ ao) {
  alignas(16) __shared__ short Ks[2][64 * 128];   // [kv][d], 256B rows, swizzled
  alignas(16) __shared__ short Vs[2][128 * 64];   // [d][kv], 128B rows, swizzled
  alignas(16) __shared__ short Ps[4][16 * 64];    // per-wave P, 128B rows, swizzled
  int bidx = blockIdx.x;
  int head = bidx & 15;
  int slot = bidx >> 4;                      // 0..31
  int qt = (slot < 16) ? (31 - slot) : (slot - 16);
  int q0 = qt * 64;
  int tid = threadIdx.x, w = tid >> 6, lane = tid & 63, g = lane >> 4, lr = lane & 15;
  size_t hbase = (size_t)head * S_ * HD_;
  int qw = q0 + w * 16;
  char* PsW = (char*)&Ps[w][0];
  s16x8 qf[4];
#pragma unroll
  for (int ks = 0; ks < 4; ks++)
    qf[ks] = *(const s16x8*)&qh[hbase + (size_t)(qw + lr) * HD_ + ks * 32 + g * 8];
  f32x4 o[8];
  f32x4 zero4 = {0.f, 0.f, 0.f, 0.f};
#pragma unroll
  for (int nf = 0; nf < 8; nf++) o[nf] = zero4;
  float m_i[4], l_i[4];
#pragma unroll
  for (int r = 0; r < 4; r++) { m_i[r] = -1e30f; l_i[r] = 0.f; }
  const float sc = 0.08838834764831843f;  // 1/sqrt(128)

  stage_kv(kh, vT, hbase, 0, (char*)Ks[0], (char*)Vs[0], tid);
  if (qt > 0) stage_kv(kh, vT, hbase, 1, (char*)Ks[1], (char*)Vs[1], tid);

  for (int kt = 0; kt <= qt; kt++) {
    int b = kt & 1;
    const char* KsB = (const char*)Ks[b];
    const char* VsB = (const char*)Vs[b];
    if (kt < qt) asm volatile("s_waitcnt vmcnt(8)" ::: "memory");
    else         asm volatile("s_waitcnt vmcnt(0)" ::: "memory");
    __builtin_amdgcn_s_barrier();
    f32x4 sacc[4];
#pragma unroll
    for (int nf = 0; nf < 4; nf++) sacc[nf] = zero4;
#pragma unroll
    for (int ks = 0; ks < 4; ks++) {
      s16x8 kf[4];
#pragma unroll
      for (int nf = 0; nf < 4; nf++) {
        int row = nf * 16 + lr;
        kf[nf] = *(const s16x8*)(KsB + row * 256 + (((ks << 6) + (g << 4)) ^ ((row & 7) << 4)));
      }
#pragma unroll
      for (int nf = 0; nf < 4; nf++) sacc[nf] = mfma_bf16(qf[ks], kf[nf], sacc[nf]);
    }
    bool diag = (kt == qt);
#pragma unroll
    for (int r = 0; r < 4; r++) {
      int prow = (g << 2) + r;
      int qrow = qw + prow;
      float pv[4];
      float mx = -1e30f;
#pragma unroll
      for (int nf = 0; nf < 4; nf++) {
        float vv = sacc[nf][r] * sc;
        if (diag) {
          int kc = kt * 64 + nf * 16 + lr;
          vv = (kc <= qrow) ? vv : -1e30f;
        }
        pv[nf] = vv;
        mx = fmaxf(mx, vv);
      }
#pragma unroll
      for (int d = 1; d < 16; d <<= 1) mx = fmaxf(mx, __shfl_xor(mx, d));
      float mold = m_i[r], mnew = fmaxf(mold, mx);
      float corr = __expf(mold - mnew);
      float ssum = 0.f;
#pragma unroll
      for (int nf = 0; nf < 4; nf++) {
        float pe = __expf(pv[nf] - mnew);
        int cb = ((nf * 16 + lr) << 1) ^ ((prow & 7) << 4);
        *(unsigned short*)(PsW + prow * 128 + cb) = f2bf(pe);
        ssum += pe;
      }
#pragma unroll
      for (int d = 1; d < 16; d <<= 1) ssum += __shfl_xor(ssum, d);
      l_i[r] = l_i[r] * corr + ssum;
      m_i[r] = mnew;
#pragma unroll
      for (int nf = 0; nf < 8; nf++) o[nf][r] *= corr;
    }
    s16x8 pa[2];
#pragma unroll
    for (int ks = 0; ks < 2; ks++)
      pa[ks] = *(const s16x8*)(PsW + lr * 128 + (((ks << 6) + (g << 4)) ^ ((lr & 7) << 4)));
#pragma unroll
    for (int nf = 0; nf < 8; nf++) {
#pragma unroll
      for (int ks = 0; ks < 2; ks++) {
        int row = nf * 16 + lr;
        s16x8 vb = *(const s16x8*)(VsB + row * 128 + (((ks << 6) + (g << 4)) ^ ((row & 7) << 4)));
        o[nf] = mfma_bf16(pa[ks], vb, o[nf]);
      }
    }
    asm volatile("s_waitcnt lgkmcnt(0)" ::: "memory");
    __builtin_amdgcn_s_barrier();
    if (kt + 2 <= qt)
      stage_kv(kh, vT, hbase, kt + 2, (char*)Ks[b], (char*)Vs[b], tid);
  }
#pragma unroll
  for (int nf = 0; nf < 8; nf++)
#pragma unroll
    for (int r = 0; r < 4; r++) {
      int row = qw + (g << 2) + r;
      int col = head * HD_ + nf * 16 + lr;
      ao[(size_t)row * D_ + col] = f2bf(o[nf][r] / l_i[r]);
    }
}

// ---------- K10: RMS2 ----------
__global__ __launch_bounds__(256) void k_rms2(const float* __restrict__ x1,
                                              const float* __restrict__ ln2w,
                                              unsigned short* __restrict__ xn2) {
  int s = blockIdx.x, t = threadIdx.x;
  const float* src = x1 + (size_t)s * D_;
  float v[8];
  float ss = 0.f;
#pragma unroll
  for (int i = 0; i < 8; i++) { v[i] = src[t + i * 256]; ss += v[i] * v[i]; }
  __shared__ float red[4];
#pragma unroll
  for (int d = 32; d; d >>= 1) ss += __shfl_xor(ss, d);
  if ((t & 63) == 0) red[t >> 6] = ss;
  __syncthreads();
  ss = red[0] + red[1] + red[2] + red[3];
  float scale = rsqrtf(ss / (float)D_ + 1e-6f);
  unsigned short* dst = xn2 + (size_t)s * D_;
#pragma unroll
  for (int i = 0; i < 8; i++) {
    int c = t + i * 256;
    dst[c] = f2bf(v[i] * scale * ln2w[c]);
  }
}

extern "C" void kernel_launch(void* const* d_in, const int* in_sizes, int n_in,
                              void* d_out, int out_size, void* d_ws, size_t ws_size,
                              hipStream_t stream) {
  (void)in_sizes; (void)n_in; (void)out_size; (void)ws_size;
  const float* hidden = (const float*)d_in[0];
  const float* router_w = (const float*)d_in[1];
  const float* router_b = (const float*)d_in[2];
  const float* ln1w = (const float*)d_in[3];
  const float* ln2w = (const float*)d_in[4];
  const float* wq = (const float*)d_in[5];
  const float* bq = (const float*)d_in[6];
  const float* wk = (const float*)d_in[7];
  const float* bk = (const float*)d_in[8];
  const float* wv = (const float*)d_in[9];
  const float* bv = (const float*)d_in[10];
  const float* wo = (const float*)d_in[11];
  const float* wg = (const float*)d_in[12];
  const float* wu = (const float*)d_in[13];
  const float* wd = (const float*)d_in[14];
  float* out = (float*)d_out;

  char* ws = (char*)d_ws;
  size_t off = 0;
  auto alloc = [&](size_t bytes) {
    char* p = ws + off;
    off += (bytes + 255) & ~(size_t)255;
    return p;
  };
  unsigned short* wqkvT = (unsigned short*)alloc(3ull * D_ * D_ * 2);
  unsigned short* woT = (unsigned short*)alloc((size_t)D_ * D_ * 2);
  unsigned short* wgT = (unsigned short*)alloc((size_t)I_ * D_ * 2);
  unsigned short* wuT = (unsigned short*)alloc((size_t)I_ * D_ * 2);
  unsigned short* wdT = (unsigned short*)alloc((size_t)D_ * I_ * 2);
  float* scores = (float*)alloc((size_t)B_ * T_ * 4);
  int* pos = (int*)alloc((size_t)S_ * 4);
  float* gate = (float*)alloc((size_t)S_ * 4);
  float* x = (float*)alloc((size_t)S_ * D_ * 4);
  float* x1 = (float*)alloc((size_t)S_ * D_ * 4);
  unsigned short* xn = (unsigned short*)alloc((size_t)S_ * D_ * 2);  // reused as x1n
  float* cosb = (float*)alloc((size_t)S_ * 64 * 4);
  float* sinb = (float*)alloc((size_t)S_ * 64 * 4);
  unsigned short* qkv = (unsigned short*)alloc((size_t)S_ * D3_ * 2);  // reused as act
  unsigned short* qh = (unsigned short*)alloc((size_t)H_ * S_ * HD_ * 2);
  unsigned short* kh = (unsigned short*)alloc((size_t)H_ * S_ * HD_ * 2);
  unsigned short* vT = (unsigned short*)alloc((size_t)H_ * S_ * HD_ * 2);
  unsigned short* ao = (unsigned short*)alloc((size_t)S_ * D_ * 2);

  k_copy_scores<<<B_ * T_, 256, 0, stream>>>((const float4*)hidden, (float4*)out,
                                             (const float4*)router_w, router_b, scores);

  k_transpose<<<dim3(D_ / 32, D_ / 32), 256, 0, stream>>>(wq, wqkvT, D_, D_);
  k_transpose<<<dim3(D_ / 32, D_ / 32), 256, 0, stream>>>(wk, wqkvT + (size_t)D_ * D_, D_, D_);
  k_transpose<<<dim3(D_ / 32, D_ / 32), 256, 0, stream>>>(wv, wqkvT + 2ull * D_ * D_, D_, D_);
  k_transpose<<<dim3(D_ / 32, D_ / 32), 256, 0, stream>>>(wo, woT, D_, D_);
  k_transpose<<<dim3(I_ / 32, D_ / 32), 256, 0, stream>>>(wg, wgT, D_, I_);
  k_transpose<<<dim3(I_ / 32, D_ / 32), 256, 0, stream>>>(wu, wuT, D_, I_);
  k_transpose<<<dim3(D_ / 32, I_ / 32), 256, 0, stream>>>(wd, wdT, I_, D_);

  k_topk<<<B_, 1024, 0, stream>>>(scores, pos);
  k_gather<<<S_, 256, 0, stream>>>(hidden, pos, scores, ln1w, x, xn, gate, cosb, sinb);

  k_gemm_qkv8<<<dim3(S_ / 256, D3_ / 128), 512, 0, stream>>>(xn, wqkvT, qkv, bq, bk, bv);
  k_rope<<<dim3(S_ / 64, H_), 256, 0, stream>>>(qkv, cosb, sinb, qh, kh, vT);
  k_attn<<<32 * H_, 256, 0, stream>>>(qh, kh, vT, ao);
  k_gemm_wo128<<<dim3(S_ / 128, D_ / 128), 256, 0, stream>>>(ao, woT, x, x1);
  k_rms2<<<S_, 256, 0, stream>>>(x1, ln2w, xn);
  k_gemm_gup8<<<dim3(S_ / 256, I_ / 128), 512, 0, stream>>>(xn, wgT, wuT, qkv);
  k_gemm_down128<<<dim3(S_ / 128, D_ / 128), 256, 0, stream>>>(qkv, wdT, x1, x, gate, pos, out);
}

// Round 8
// 583.420 us; speedup vs baseline: 1.0609x; 1.0609x over previous
//
#include <hip/hip_runtime.h>
#include <stdint.h>

#define B_ 4
#define T_ 2048
#define D_ 2048
#define H_ 16
#define HD_ 128
#define I_ 5632
#define K_ 512
#define S_ 2048
#define D3_ (3 * D_)

typedef float f32x4 __attribute__((ext_vector_type(4)));
typedef short s16x8 __attribute__((ext_vector_type(8)));
typedef __bf16 bf16x8 __attribute__((ext_vector_type(8)));

// ---------- mfma wrapper robust to builtin operand type (short8 vs bf16x8) ----------
template <typename V>
__device__ __forceinline__ auto mfma_try(V a, V b, f32x4 c, int)
    -> decltype(__builtin_amdgcn_mfma_f32_16x16x32_bf16(a, b, c, 0, 0, 0)) {
  return __builtin_amdgcn_mfma_f32_16x16x32_bf16(a, b, c, 0, 0, 0);
}
template <typename V>
__device__ __forceinline__ f32x4 mfma_try(V a, V b, f32x4 c, long) {
  return __builtin_amdgcn_mfma_f32_16x16x32_bf16(
      __builtin_bit_cast(bf16x8, a), __builtin_bit_cast(bf16x8, b), c, 0, 0, 0);
}
__device__ __forceinline__ f32x4 mfma_bf16(s16x8 a, s16x8 b, f32x4 c) {
  return mfma_try(a, b, c, 0);
}

__device__ __forceinline__ void gl_lds16(const void* g, void* l) {
  __builtin_amdgcn_global_load_lds((const __attribute__((address_space(1))) void*)g,
                                   (__attribute__((address_space(3))) void*)l, 16, 0, 0);
}

__device__ __forceinline__ unsigned short f2bf(float f) {
  unsigned u = __float_as_uint(f);
  u += 0x7FFFu + ((u >> 16) & 1);
  return (unsigned short)(u >> 16);
}
__device__ __forceinline__ float bf2f(unsigned short s) {
  return __uint_as_float(((unsigned)s) << 16);
}

// ---------- K1: copy hidden -> out, fused with router scores ----------
__global__ __launch_bounds__(256) void k_copy_scores(const float4* __restrict__ hid,
                                                     float4* __restrict__ dst,
                                                     const float4* __restrict__ rw,
                                                     const float* __restrict__ rb,
                                                     float* __restrict__ scores) {
  int row = blockIdx.x, t = threadIdx.x;
  const float4* hr = hid + (size_t)row * (D_ / 4);
  float4* dr = dst + (size_t)row * (D_ / 4);
  float acc = 0.f;
#pragma unroll
  for (int i = 0; i < 2; i++) {
    float4 v = hr[t + i * 256];
    dr[t + i * 256] = v;
    float4 w = rw[t + i * 256];
    acc += v.x * w.x + v.y * w.y + v.z * w.z + v.w * w.w;
  }
#pragma unroll
  for (int d = 32; d; d >>= 1) acc += __shfl_xor(acc, d);
  __shared__ float red[4];
  if ((t & 63) == 0) red[t >> 6] = acc;
  __syncthreads();
  if (t == 0) scores[row] = red[0] + red[1] + red[2] + red[3] + rb[0];
}

// ---------- K3: exact top-k (bitonic, matches jax.lax.top_k tie-break) ----------
__global__ __launch_bounds__(1024) void k_topk(const float* __restrict__ scores,
                                               int* __restrict__ pos) {
  __shared__ unsigned long long keys[T_];
  __shared__ int sidx[K_];
  int b = blockIdx.x, t = threadIdx.x;
  for (int i = t; i < T_; i += 1024) {
    unsigned u = __float_as_uint(scores[b * T_ + i]);
    u = (u & 0x80000000u) ? ~u : (u | 0x80000000u);
    keys[i] = ((unsigned long long)u << 32) | (unsigned)(~(unsigned)i);
  }
  __syncthreads();
  for (int k = 2; k <= T_; k <<= 1)
    for (int j = k >> 1; j > 0; j >>= 1) {
      for (int i = t; i < T_; i += 1024) {
        int l = i ^ j;
        if (l > i) {
          unsigned long long a = keys[i], c = keys[l];
          bool desc = ((i & k) == 0);
          if (desc ? (a < c) : (a > c)) { keys[i] = c; keys[l] = a; }
        }
      }
      __syncthreads();
    }
  if (t < K_) sidx[t] = (int)(~(unsigned)(keys[t] & 0xFFFFFFFFull));
  __syncthreads();
  for (int k = 2; k <= K_; k <<= 1)
    for (int j = k >> 1; j > 0; j >>= 1) {
      if (t < K_) {
        int i = t, l = i ^ j;
        if (l > i && l < K_) {
          int a = sidx[i], c = sidx[l];
          bool asc = ((i & k) == 0);
          if (asc ? (a > c) : (a < c)) { sidx[i] = c; sidx[l] = a; }
        }
      }
      __syncthreads();
    }
  if (t < K_) pos[b * K_ + t] = sidx[t];
}

// ---------- K4: gather + RMS1 + gate + rope tables ----------
__global__ __launch_bounds__(256) void k_gather(const float* __restrict__ hidden,
    const int* __restrict__ pos, const float* __restrict__ scores,
    const float* __restrict__ ln1w, float* __restrict__ x,
    unsigned short* __restrict__ xn, float* __restrict__ gate,
    float* __restrict__ cosb, float* __restrict__ sinb) {
  int s = blockIdx.x, t = threadIdx.x;
  int b = s >> 9, p = pos[s];
  const float* src = hidden + ((size_t)b * T_ + p) * D_;
  float v[8];
  float ss = 0.f;
#pragma unroll
  for (int i = 0; i < 8; i++) { v[i] = src[t + i * 256]; ss += v[i] * v[i]; }
  __shared__ float red[4];
#pragma unroll
  for (int d = 32; d; d >>= 1) ss += __shfl_xor(ss, d);
  if ((t & 63) == 0) red[t >> 6] = ss;
  __syncthreads();
  ss = red[0] + red[1] + red[2] + red[3];
  float scale = rsqrtf(ss / (float)D_ + 1e-6f);
  float* xd = x + (size_t)s * D_;
  unsigned short* xnd = xn + (size_t)s * D_;
#pragma unroll
  for (int i = 0; i < 8; i++) {
    int c = t + i * 256;
    xd[c] = v[i];
    xnd[c] = f2bf(v[i] * scale * ln1w[c]);
  }
  if (t == 0) gate[s] = 1.f / (1.f + expf(-scores[b * T_ + p]));
  if (t < 64) {
    float invf = powf(10000.0f, -(float)t / 64.0f);
    float f = (float)p * invf;
    cosb[s * 64 + t] = cosf(f);
    sinb[s * 64 + t] = sinf(f);
  }
}

// ---------- K5: transpose + f32->bf16 (weights to Bt layout), ushort4 writes ----------
__global__ __launch_bounds__(256) void k_transpose(const float* __restrict__ src,
                                                   unsigned short* __restrict__ dst,
                                                   int R, int C) {
  __shared__ float tile[32][33];
  int tx = threadIdx.x & 31, ty = threadIdx.x >> 5;
  int c0 = blockIdx.x * 32, r0 = blockIdx.y * 32;
#pragma unroll
  for (int i = 0; i < 4; i++) {
    int r = ty + i * 8;
    tile[r][tx] = src[(size_t)(r0 + r) * C + c0 + tx];
  }
  __syncthreads();
  int drow = threadIdx.x >> 3;        // 0..31 : dst row (c index)
  int dc4 = (threadIdx.x & 7) * 4;    // dst col base (r index)
  ushort4 v;
  v.x = f2bf(tile[dc4 + 0][drow]);
  v.y = f2bf(tile[dc4 + 1][drow]);
  v.z = f2bf(tile[dc4 + 2][drow]);
  v.w = f2bf(tile[dc4 + 3][drow]);
  *(ushort4*)&dst[(size_t)(c0 + drow) * R + r0 + dc4] = v;
}

// ======================================================================
// GEMM templates (BK=32, counted vmcnt, SWZ swizzle).
// Swizzle involution: byte ^= (((row>>1)&3)<<4) — 2 lanes/bank = free (m136).
// Applied to GLOBAL source (gl_lds dest must be linear) and to the read.
//
// 3-buffer single-barrier schedule (qkv8, wo64, down64):
//   per K-tile t: lgkmcnt(0)[free, MFMAs consumed reads] + vmcnt(3) -> barrier
//   -> stage(t+2) into buf (t+2)%3 [≠ read buf, ≠ in-flight buf; all waves'
//      reads of it drained by the lgkm+barrier] -> ds_read buf t%3 -> MFMA.
//   ONE barrier per K-tile; stage issued earliest (~2 iters before its vmcnt).
//
// 2-buffer 2-barrier schedule (gup8, LDS-bound — R6 proven):
//   vmcnt(4) -> bar -> reads -> lgkmcnt(0) -> bar -> stage(t+2) -> MFMA.
// ======================================================================
#define SWZ(row) ((((row) >> 1) & 3) << 4)

// 512-thread staging helpers
__device__ __forceinline__ void stage16k(const unsigned short* __restrict__ g, int ldK,
                                         int row0, int k0, char* lds, int tid) {
#pragma unroll
  for (int c = 0; c < 2; c++) {
    int off = c * 8192 + tid * 16;  // 16 KB = 256 rows
    int row = off >> 6;
    int cb = (off & 63) ^ SWZ(row);
    gl_lds16(g + (size_t)(row0 + row) * ldK + k0 + (cb >> 1), lds + off);
  }
}
__device__ __forceinline__ void stage8k(const unsigned short* __restrict__ g, int ldK,
                                        int row0, int k0, char* lds, int tid) {
  int off = tid * 16;  // 8 KB = 128 rows (512 thr)
  int row = off >> 6;
  int cb = (off & 63) ^ SWZ(row);
  gl_lds16(g + (size_t)(row0 + row) * ldK + k0 + (cb >> 1), lds + off);
}
// 256-thread staging helpers
__device__ __forceinline__ void stage64r(const unsigned short* __restrict__ g, int ldK,
                                         int row0, int k0, char* lds, int tid) {
  int off = tid * 16;  // 4 KB = 64 rows (256 thr)
  int row = off >> 6;
  int cb = (off & 63) ^ SWZ(row);
  gl_lds16(g + (size_t)(row0 + row) * ldK + k0 + (cb >> 1), lds + off);
}
__device__ __forceinline__ void stage128r(const unsigned short* __restrict__ g, int ldK,
                                          int row0, int k0, char* lds, int tid) {
#pragma unroll
  for (int c = 0; c < 2; c++) {
    int off = c * 4096 + tid * 16;  // 8 KB = 128 rows (256 thr)
    int row = off >> 6;
    int cb = (off & 63) ^ SWZ(row);
    gl_lds16(g + (size_t)(row0 + row) * ldK + k0 + (cb >> 1), lds + off);
  }
}
__device__ __forceinline__ s16x8 ldfrag(const char* base, int row, int g) {
  return *(const s16x8*)(base + row * 64 + ((g * 16) ^ SWZ(row)));
}

// ---------- K6: fused QKV GEMM, 256x128 tile, 8 waves, 3-buf 1-barrier ----------
__global__ __launch_bounds__(512, 2) void k_gemm_qkv8(const unsigned short* __restrict__ A,
    const unsigned short* __restrict__ Bt, unsigned short* __restrict__ C,
    const float* __restrict__ bq, const float* __restrict__ bk,
    const float* __restrict__ bv) {
  alignas(16) __shared__ short As[3 * 256 * 32];
  alignas(16) __shared__ short Bs[3 * 128 * 32];
  int tid = threadIdx.x;
  int lane = tid & 63, g = lane >> 4, lr = lane & 15;
  int wid = tid >> 6, wm = wid >> 1, wn = wid & 1;
  int m0 = blockIdx.x * 256, n0 = blockIdx.y * 128;
  f32x4 zero4 = {0.f, 0.f, 0.f, 0.f};
  f32x4 acc[4][4];
#pragma unroll
  for (int m = 0; m < 4; m++)
#pragma unroll
    for (int n = 0; n < 4; n++) acc[m][n] = zero4;
  const int nkt = D_ / 32;
  stage16k(A, D_, m0, 0, (char*)As, tid);
  stage8k(Bt, D_, n0, 0, (char*)Bs, tid);
  stage16k(A, D_, m0, 32, (char*)As + 16384, tid);
  stage8k(Bt, D_, n0, 32, (char*)Bs + 8192, tid);
  int arow = wm * 64 + lr;
  int brow = wn * 64 + lr;
  for (int t = 0; t < nkt; t++) {
    int b = t % 3;
    const char* Ab = (const char*)As + b * 16384;
    const char* Bb = (const char*)Bs + b * 8192;
    if (t + 1 < nkt) asm volatile("s_waitcnt vmcnt(3) lgkmcnt(0)" ::: "memory");
    else             asm volatile("s_waitcnt vmcnt(0) lgkmcnt(0)" ::: "memory");
    __builtin_amdgcn_s_barrier();
    if (t + 2 < nkt) {
      int nb = (t + 2) % 3;
      stage16k(A, D_, m0, (t + 2) * 32, (char*)As + nb * 16384, tid);
      stage8k(Bt, D_, n0, (t + 2) * 32, (char*)Bs + nb * 8192, tid);
    }
    s16x8 af[4], bf4[4];
#pragma unroll
    for (int i = 0; i < 4; i++) af[i] = ldfrag(Ab, arow + i * 16, g);
#pragma unroll
    for (int i = 0; i < 4; i++) bf4[i] = ldfrag(Bb, brow + i * 16, g);
    __builtin_amdgcn_s_setprio(1);
#pragma unroll
    for (int m = 0; m < 4; m++)
#pragma unroll
      for (int n = 0; n < 4; n++) acc[m][n] = mfma_bf16(af[m], bf4[n], acc[m][n]);
    __builtin_amdgcn_s_setprio(0);
  }
#pragma unroll
  for (int m = 0; m < 4; m++)
#pragma unroll
    for (int n = 0; n < 4; n++)
#pragma unroll
      for (int r = 0; r < 4; r++) {
        int row = m0 + wm * 64 + m * 16 + (g << 2) + r;
        int col = n0 + wn * 64 + n * 16 + lr;
        float bias = (col < D_) ? bq[col] : ((col < 2 * D_) ? bk[col - D_] : bv[col - 2 * D_]);
        C[(size_t)row * D3_ + col] = f2bf(acc[m][n][r] + bias);
      }
}

// ---------- K11: fused gate/up GEMM, 256x(128+128), 8 waves — R6 proven ----------
__global__ __launch_bounds__(512, 2) void k_gemm_gup8(const unsigned short* __restrict__ A,
    const unsigned short* __restrict__ Bg, const unsigned short* __restrict__ Bu,
    unsigned short* __restrict__ act) {
  alignas(16) __shared__ short As[2][256 * 32];
  alignas(16) __shared__ short Bgs[2][128 * 32];
  alignas(16) __shared__ short Bus[2][128 * 32];
  int tid = threadIdx.x;
  int lane = tid & 63, g = lane >> 4, lr = lane & 15;
  int wid = tid >> 6, wm = wid >> 1, wn = wid & 1;
  int m0 = blockIdx.x * 256, n0 = blockIdx.y * 128;
  f32x4 zero4 = {0.f, 0.f, 0.f, 0.f};
  f32x4 ag[4][4], au[4][4];
#pragma unroll
  for (int m = 0; m < 4; m++)
#pragma unroll
    for (int n = 0; n < 4; n++) { ag[m][n] = zero4; au[m][n] = zero4; }
  const int nkt = D_ / 32;
  stage16k(A, D_, m0, 0, (char*)As[0], tid);
  stage8k(Bg, D_, n0, 0, (char*)Bgs[0], tid);
  stage8k(Bu, D_, n0, 0, (char*)Bus[0], tid);
  stage16k(A, D_, m0, 32, (char*)As[1], tid);
  stage8k(Bg, D_, n0, 32, (char*)Bgs[1], tid);
  stage8k(Bu, D_, n0, 32, (char*)Bus[1], tid);
  int arow = wm * 64 + lr;
  int brow = wn * 64 + lr;
  for (int t = 0; t < nkt; t++) {
    int b = t & 1;
    const char* Ab = (const char*)As[b];
    const char* Bgb = (const char*)Bgs[b];
    const char* Bub = (const char*)Bus[b];
    if (t + 1 < nkt) asm volatile("s_waitcnt vmcnt(4)" ::: "memory");
    else             asm volatile("s_waitcnt vmcnt(0)" ::: "memory");
    __builtin_amdgcn_s_barrier();
    s16x8 af[4], bg4[4], bu4[4];
#pragma unroll
    for (int i = 0; i < 4; i++) af[i] = ldfrag(Ab, arow + i * 16, g);
#pragma unroll
    for (int i = 0; i < 4; i++) bg4[i] = ldfrag(Bgb, brow + i * 16, g);
#pragma unroll
    for (int i = 0; i < 4; i++) bu4[i] = ldfrag(Bub, brow + i * 16, g);
    asm volatile("s_waitcnt lgkmcnt(0)" ::: "memory");
    __builtin_amdgcn_s_barrier();
    if (t + 2 < nkt) {
      stage16k(A, D_, m0, (t + 2) * 32, (char*)As[b], tid);
      stage8k(Bg, D_, n0, (t + 2) * 32, (char*)Bgs[b], tid);
      stage8k(Bu, D_, n0, (t + 2) * 32, (char*)Bus[b], tid);
    }
    __builtin_amdgcn_s_setprio(1);
#pragma unroll
    for (int m = 0; m < 4; m++)
#pragma unroll
      for (int n = 0; n < 4; n++) {
        ag[m][n] = mfma_bf16(af[m], bg4[n], ag[m][n]);
        au[m][n] = mfma_bf16(af[m], bu4[n], au[m][n]);
      }
    __builtin_amdgcn_s_setprio(0);
  }
#pragma unroll
  for (int m = 0; m < 4; m++)
#pragma unroll
    for (int n = 0; n < 4; n++)
#pragma unroll
      for (int r = 0; r < 4; r++) {
        int row = m0 + wm * 64 + m * 16 + (g << 2) + r;
        int col = n0 + wn * 64 + n * 16 + lr;
        float gv = ag[m][n][r], uv = au[m][n][r];
        float si = gv / (1.f + __expf(-gv));
        act[(size_t)row * I_ + col] = f2bf(si * uv);
      }
}

// ---------- K9: wo GEMM + residual, 64x128 tile, 4 waves, 3-buf 1-barrier ----------
__global__ __launch_bounds__(256, 2) void k_gemm_wo64(const unsigned short* __restrict__ A,
    const unsigned short* __restrict__ Bt, const float* __restrict__ xres,
    float* __restrict__ x1) {
  alignas(16) __shared__ short As[3 * 64 * 32];
  alignas(16) __shared__ short Bs[3 * 128 * 32];
  int tid = threadIdx.x;
  int lane = tid & 63, g = lane >> 4, lr = lane & 15, wid = tid >> 6;
  int m0 = blockIdx.x * 64, n0 = blockIdx.y * 128;
  f32x4 zero4 = {0.f, 0.f, 0.f, 0.f};
  f32x4 acc[4][2];
#pragma unroll
  for (int m = 0; m < 4; m++)
#pragma unroll
    for (int n = 0; n < 2; n++) acc[m][n] = zero4;
  const int nkt = D_ / 32;
  stage64r(A, D_, m0, 0, (char*)As, tid);
  stage128r(Bt, D_, n0, 0, (char*)Bs, tid);
  stage64r(A, D_, m0, 32, (char*)As + 4096, tid);
  stage128r(Bt, D_, n0, 32, (char*)Bs + 8192, tid);
  for (int t = 0; t < nkt; t++) {
    int b = t % 3;
    const char* Ab = (const char*)As + b * 4096;
    const char* Bb = (const char*)Bs + b * 8192;
    if (t + 1 < nkt) asm volatile("s_waitcnt vmcnt(3) lgkmcnt(0)" ::: "memory");
    else             asm volatile("s_waitcnt vmcnt(0) lgkmcnt(0)" ::: "memory");
    __builtin_amdgcn_s_barrier();
    if (t + 2 < nkt) {
      int nb = (t + 2) % 3;
      stage64r(A, D_, m0, (t + 2) * 32, (char*)As + nb * 4096, tid);
      stage128r(Bt, D_, n0, (t + 2) * 32, (char*)Bs + nb * 8192, tid);
    }
    s16x8 af[4], bf2[2];
#pragma unroll
    for (int i = 0; i < 4; i++) af[i] = ldfrag(Ab, i * 16 + lr, g);
#pragma unroll
    for (int j = 0; j < 2; j++) bf2[j] = ldfrag(Bb, wid * 32 + j * 16 + lr, g);
    __builtin_amdgcn_s_setprio(1);
#pragma unroll
    for (int m = 0; m < 4; m++)
#pragma unroll
      for (int n = 0; n < 2; n++) acc[m][n] = mfma_bf16(af[m], bf2[n], acc[m][n]);
    __builtin_amdgcn_s_setprio(0);
  }
#pragma unroll
  for (int m = 0; m < 4; m++)
#pragma unroll
    for (int n = 0; n < 2; n++)
#pragma unroll
      for (int r = 0; r < 4; r++) {
        int row = m0 + m * 16 + (g << 2) + r;
        int col = n0 + wid * 32 + n * 16 + lr;
        x1[(size_t)row * D_ + col] = acc[m][n][r] + xres[(size_t)row * D_ + col];
      }
}

// ---------- K12: down GEMM + residual + blend + scatter, 64x128, 3-buf ----------
__global__ __launch_bounds__(256, 2) void k_gemm_down64(const unsigned short* __restrict__ A,
    const unsigned short* __restrict__ Bt, const float* __restrict__ x1,
    const float* __restrict__ x, const float* __restrict__ gate,
    const int* __restrict__ pos, float* __restrict__ out) {
  alignas(16) __shared__ short As[3 * 64 * 32];
  alignas(16) __shared__ short Bs[3 * 128 * 32];
  int tid = threadIdx.x;
  int lane = tid & 63, g = lane >> 4, lr = lane & 15, wid = tid >> 6;
  int m0 = blockIdx.x * 64, n0 = blockIdx.y * 128;
  f32x4 zero4 = {0.f, 0.f, 0.f, 0.f};
  f32x4 acc[4][2];
#pragma unroll
  for (int m = 0; m < 4; m++)
#pragma unroll
    for (int n = 0; n < 2; n++) acc[m][n] = zero4;
  const int nkt = I_ / 32;
  stage64r(A, I_, m0, 0, (char*)As, tid);
  stage128r(Bt, I_, n0, 0, (char*)Bs, tid);
  stage64r(A, I_, m0, 32, (char*)As + 4096, tid);
  stage128r(Bt, I_, n0, 32, (char*)Bs + 8192, tid);
  for (int t = 0; t < nkt; t++) {
    int b = t % 3;
    const char* Ab = (const char*)As + b * 4096;
    const char* Bb = (const char*)Bs + b * 8192;
    if (t + 1 < nkt) asm volatile("s_waitcnt vmcnt(3) lgkmcnt(0)" ::: "memory");
    else             asm volatile("s_waitcnt vmcnt(0) lgkmcnt(0)" ::: "memory");
    __builtin_amdgcn_s_barrier();
    if (t + 2 < nkt) {
      int nb = (t + 2) % 3;
      stage64r(A, I_, m0, (t + 2) * 32, (char*)As + nb * 4096, tid);
      stage128r(Bt, I_, n0, (t + 2) * 32, (char*)Bs + nb * 8192, tid);
    }
    s16x8 af[4], bf2[2];
#pragma unroll
    for (int i = 0; i < 4; i++) af[i] = ldfrag(Ab, i * 16 + lr, g);
#pragma unroll
    for (int j = 0; j < 2; j++) bf2[j] = ldfrag(Bb, wid * 32 + j * 16 + lr, g);
    __builtin_amdgcn_s_setprio(1);
#pragma unroll
    for (int m = 0; m < 4; m++)
#pragma unroll
      for (int n = 0; n < 2; n++) acc[m][n] = mfma_bf16(af[m], bf2[n], acc[m][n]);
    __builtin_amdgcn_s_setprio(0);
  }
#pragma unroll
  for (int m = 0; m < 4; m++)
#pragma unroll
    for (int n = 0; n < 2; n++)
#pragma unroll
      for (int r = 0; r < 4; r++) {
        int srow = m0 + m * 16 + (g << 2) + r;
        int col = n0 + wid * 32 + n * 16 + lr;
        float proc = acc[m][n][r] + x1[(size_t)srow * D_ + col];
        float gt = gate[srow];
        float xv = x[(size_t)srow * D_ + col];
        int bb = srow >> 9;
        int p = pos[srow];
        out[((size_t)bb * T_ + p) * D_ + col] = gt * proc + (1.f - gt) * xv;
      }
}

// ---------- K7: RoPE + head relayout (q,k row-major per head; v transposed) ----------
__global__ __launch_bounds__(256) void k_rope(const unsigned short* __restrict__ qkv,
    const float* __restrict__ cosb, const float* __restrict__ sinb,
    unsigned short* __restrict__ qh, unsigned short* __restrict__ kh,
    unsigned short* __restrict__ vT) {
  int s0 = blockIdx.x * 64;
  int h = blockIdx.y;
  int t = threadIdx.x;
#pragma unroll
  for (int i = 0; i < 16; i++) {
    int flat = t + i * 256;
    int r = flat >> 6, dp = flat & 63;
    int s = s0 + r;
    float c = cosb[s * 64 + dp], sn = sinb[s * 64 + dp];
    const unsigned short* qrow = qkv + (size_t)s * D3_ + h * HD_;
    float q1 = bf2f(qrow[dp]), q2 = bf2f(qrow[dp + 64]);
    unsigned short* qdst = qh + ((size_t)h * S_ + s) * HD_;
    qdst[dp] = f2bf(q1 * c - q2 * sn);
    qdst[dp + 64] = f2bf(q2 * c + q1 * sn);
    const unsigned short* krow = qrow + D_;
    float k1 = bf2f(krow[dp]), k2 = bf2f(krow[dp + 64]);
    unsigned short* kdst = kh + ((size_t)h * S_ + s) * HD_;
    kdst[dp] = f2bf(k1 * c - k2 * sn);
    kdst[dp + 64] = f2bf(k2 * c + k1 * sn);
  }
  __shared__ unsigned short vt[128][66];
#pragma unroll
  for (int i = 0; i < 32; i++) {
    int flat = t + i * 256;
    int r = flat >> 7, d = flat & 127;
    vt[d][r] = qkv[(size_t)(s0 + r) * D3_ + 2 * D_ + h * HD_ + d];
  }
  __syncthreads();
#pragma unroll
  for (int i = 0; i < 32; i++) {
    int flat = t + i * 256;
    int d = flat >> 6, sc = flat & 63;
    vT[((size_t)h * HD_ + d) * S_ + s0 + sc] = vt[d][sc];
  }
}

// ======================================================================
// K8: flash attention (q-tile 64, LPT order, swizzled LDS, dbuf KV)
// ======================================================================
__device__ __forceinline__ void stage_kv(const unsigned short* __restrict__ kh,
                                         const unsigned short* __restrict__ vT,
                                         size_t hbase, int kt, char* KsB, char* VsB, int tid) {
#pragma unroll
  for (int c = 0; c < 4; c++) {
    int off = c * 4096 + tid * 16;
    int row = off >> 8;
    int cb = (off & 255) ^ ((row & 7) << 4);
    gl_lds16(kh + hbase + (size_t)(kt * 64 + row) * HD_ + (cb >> 1), KsB + off);
  }
#pragma unroll
  for (int c = 0; c < 4; c++) {
    int off = c * 4096 + tid * 16;
    int row = off >> 7;
    int cb = (off & 127) ^ ((row & 7) << 4);
    gl_lds16(vT + hbase + (size_t)row * S_ + kt * 64 + (cb >> 1), VsB + off);
  }
}

__global__ __launch_bounds__(256, 2) void k_attn(const unsigned short* __restrict__ qh,
                                                 const unsigned short* __restrict__ kh,
                                                 const unsigned short* __restrict__ vT,
                                                 unsigned short* __restrict__ ao) {
  alignas(16) __shared__ short Ks[2][64 * 128];   // [kv][d], 256B rows, swizzled
  alignas(16) __shared__ short Vs[2][128 * 64];   // [d][kv], 128B rows, swizzled
  alignas(16) __shared__ short Ps[4][16 * 64];    // per-wave P, 128B rows, swizzled
  int bidx = blockIdx.x;
  int head = bidx & 15;
  int slot = bidx >> 4;                      // 0..31
  int qt = (slot < 16) ? (31 - slot) : (slot - 16);
  int q0 = qt * 64;
  int tid = threadIdx.x, w = tid >> 6, lane = tid & 63, g = lane >> 4, lr = lane & 15;
  size_t hbase = (size_t)head * S_ * HD_;
  int qw = q0 + w * 16;
  char* PsW = (char*)&Ps[w][0];
  s16x8 qf[4];
#pragma unroll
  for (int ks = 0; ks < 4; ks++)
    qf[ks] = *(const s16x8*)&qh[hbase + (size_t)(qw + lr) * HD_ + ks * 32 + g * 8];
  f32x4 o[8];
  f32x4 zero4 = {0.f, 0.f, 0.f, 0.f};
#pragma unroll
  for (int nf = 0; nf < 8; nf++) o[nf] = zero4;
  float m_i[4], l_i[4];
#pragma unroll
  for (int r = 0; r < 4; r++) { m_i[r] = -1e30f; l_i[r] = 0.f; }
  const float sc = 0.08838834764831843f;  // 1/sqrt(128)

  stage_kv(kh, vT, hbase, 0, (char*)Ks[0], (char*)Vs[0], tid);
  if (qt > 0) stage_kv(kh, vT, hbase, 1, (char*)Ks[1], (char*)Vs[1], tid);

  for (int kt = 0; kt <= qt; kt++) {
    int b = kt & 1;
    const char* KsB = (const char*)Ks[b];
    const char* VsB = (const char*)Vs[b];
    if (kt < qt) asm volatile("s_waitcnt vmcnt(8)" ::: "memory");
    else         asm volatile("s_waitcnt vmcnt(0)" ::: "memory");
    __builtin_amdgcn_s_barrier();
    f32x4 sacc[4];
#pragma unroll
    for (int nf = 0; nf < 4; nf++) sacc[nf] = zero4;
#pragma unroll
    for (int ks = 0; ks < 4; ks++) {
      s16x8 kf[4];
#pragma unroll
      for (int nf = 0; nf < 4; nf++) {
        int row = nf * 16 + lr;
        kf[nf] = *(const s16x8*)(KsB + row * 256 + (((ks << 6) + (g << 4)) ^ ((row & 7) << 4)));
      }
#pragma unroll
      for (int nf = 0; nf < 4; nf++) sacc[nf] = mfma_bf16(qf[ks], kf[nf], sacc[nf]);
    }
    bool diag = (kt == qt);
#pragma unroll
    for (int r = 0; r < 4; r++) {
      int prow = (g << 2) + r;
      int qrow = qw + prow;
      float pv[4];
      float mx = -1e30f;
#pragma unroll
      for (int nf = 0; nf < 4; nf++) {
        float vv = sacc[nf][r] * sc;
        if (diag) {
          int kc = kt * 64 + nf * 16 + lr;
          vv = (kc <= qrow) ? vv : -1e30f;
        }
        pv[nf] = vv;
        mx = fmaxf(mx, vv);
      }
#pragma unroll
      for (int d = 1; d < 16; d <<= 1) mx = fmaxf(mx, __shfl_xor(mx, d));
      float mold = m_i[r], mnew = fmaxf(mold, mx);
      float corr = __expf(mold - mnew);
      float ssum = 0.f;
#pragma unroll
      for (int nf = 0; nf < 4; nf++) {
        float pe = __expf(pv[nf] - mnew);
        int cb = ((nf * 16 + lr) << 1) ^ ((prow & 7) << 4);
        *(unsigned short*)(PsW + prow * 128 + cb) = f2bf(pe);
        ssum += pe;
      }
#pragma unroll
      for (int d = 1; d < 16; d <<= 1) ssum += __shfl_xor(ssum, d);
      l_i[r] = l_i[r] * corr + ssum;
      m_i[r] = mnew;
#pragma unroll
      for (int nf = 0; nf < 8; nf++) o[nf][r] *= corr;
    }
    s16x8 pa[2];
#pragma unroll
    for (int ks = 0; ks < 2; ks++)
      pa[ks] = *(const s16x8*)(PsW + lr * 128 + (((ks << 6) + (g << 4)) ^ ((lr & 7) << 4)));
#pragma unroll
    for (int nf = 0; nf < 8; nf++) {
#pragma unroll
      for (int ks = 0; ks < 2; ks++) {
        int row = nf * 16 + lr;
        s16x8 vb = *(const s16x8*)(VsB + row * 128 + (((ks << 6) + (g << 4)) ^ ((row & 7) << 4)));
        o[nf] = mfma_bf16(pa[ks], vb, o[nf]);
      }
    }
    asm volatile("s_waitcnt lgkmcnt(0)" ::: "memory");
    __builtin_amdgcn_s_barrier();
    if (kt + 2 <= qt)
      stage_kv(kh, vT, hbase, kt + 2, (char*)Ks[b], (char*)Vs[b], tid);
  }
#pragma unroll
  for (int nf = 0; nf < 8; nf++)
#pragma unroll
    for (int r = 0; r < 4; r++) {
      int row = qw + (g << 2) + r;
      int col = head * HD_ + nf * 16 + lr;
      ao[(size_t)row * D_ + col] = f2bf(o[nf][r] / l_i[r]);
    }
}

// ---------- K10: RMS2 ----------
__global__ __launch_bounds__(256) void k_rms2(const float* __restrict__ x1,
                                              const float* __restrict__ ln2w,
                                              unsigned short* __restrict__ xn2) {
  int s = blockIdx.x, t = threadIdx.x;
  const float* src = x1 + (size_t)s * D_;
  float v[8];
  float ss = 0.f;
#pragma unroll
  for (int i = 0; i < 8; i++) { v[i] = src[t + i * 256]; ss += v[i] * v[i]; }
  __shared__ float red[4];
#pragma unroll
  for (int d = 32; d; d >>= 1) ss += __shfl_xor(ss, d);
  if ((t & 63) == 0) red[t >> 6] = ss;
  __syncthreads();
  ss = red[0] + red[1] + red[2] + red[3];
  float scale = rsqrtf(ss / (float)D_ + 1e-6f);
  unsigned short* dst = xn2 + (size_t)s * D_;
#pragma unroll
  for (int i = 0; i < 8; i++) {
    int c = t + i * 256;
    dst[c] = f2bf(v[i] * scale * ln2w[c]);
  }
}

extern "C" void kernel_launch(void* const* d_in, const int* in_sizes, int n_in,
                              void* d_out, int out_size, void* d_ws, size_t ws_size,
                              hipStream_t stream) {
  (void)in_sizes; (void)n_in; (void)out_size; (void)ws_size;
  const float* hidden = (const float*)d_in[0];
  const float* router_w = (const float*)d_in[1];
  const float* router_b = (const float*)d_in[2];
  const float* ln1w = (const float*)d_in[3];
  const float* ln2w = (const float*)d_in[4];
  const float* wq = (const float*)d_in[5];
  const float* bq = (const float*)d_in[6];
  const float* wk = (const float*)d_in[7];
  const float* bk = (const float*)d_in[8];
  const float* wv = (const float*)d_in[9];
  const float* bv = (const float*)d_in[10];
  const float* wo = (const float*)d_in[11];
  const float* wg = (const float*)d_in[12];
  const float* wu = (const float*)d_in[13];
  const float* wd = (const float*)d_in[14];
  float* out = (float*)d_out;

  char* ws = (char*)d_ws;
  size_t off = 0;
  auto alloc = [&](size_t bytes) {
    char* p = ws + off;
    off += (bytes + 255) & ~(size_t)255;
    return p;
  };
  unsigned short* wqkvT = (unsigned short*)alloc(3ull * D_ * D_ * 2);
  unsigned short* woT = (unsigned short*)alloc((size_t)D_ * D_ * 2);
  unsigned short* wgT = (unsigned short*)alloc((size_t)I_ * D_ * 2);
  unsigned short* wuT = (unsigned short*)alloc((size_t)I_ * D_ * 2);
  unsigned short* wdT = (unsigned short*)alloc((size_t)D_ * I_ * 2);
  float* scores = (float*)alloc((size_t)B_ * T_ * 4);
  int* pos = (int*)alloc((size_t)S_ * 4);
  float* gate = (float*)alloc((size_t)S_ * 4);
  float* x = (float*)alloc((size_t)S_ * D_ * 4);
  float* x1 = (float*)alloc((size_t)S_ * D_ * 4);
  unsigned short* xn = (unsigned short*)alloc((size_t)S_ * D_ * 2);  // reused as x1n
  float* cosb = (float*)alloc((size_t)S_ * 64 * 4);
  float* sinb = (float*)alloc((size_t)S_ * 64 * 4);
  unsigned short* qkv = (unsigned short*)alloc((size_t)S_ * D3_ * 2);  // reused as act
  unsigned short* qh = (unsigned short*)alloc((size_t)H_ * S_ * HD_ * 2);
  unsigned short* kh = (unsigned short*)alloc((size_t)H_ * S_ * HD_ * 2);
  unsigned short* vT = (unsigned short*)alloc((size_t)H_ * S_ * HD_ * 2);
  unsigned short* ao = (unsigned short*)alloc((size_t)S_ * D_ * 2);

  k_copy_scores<<<B_ * T_, 256, 0, stream>>>((const float4*)hidden, (float4*)out,
                                             (const float4*)router_w, router_b, scores);

  k_transpose<<<dim3(D_ / 32, D_ / 32), 256, 0, stream>>>(wq, wqkvT, D_, D_);
  k_transpose<<<dim3(D_ / 32, D_ / 32), 256, 0, stream>>>(wk, wqkvT + (size_t)D_ * D_, D_, D_);
  k_transpose<<<dim3(D_ / 32, D_ / 32), 256, 0, stream>>>(wv, wqkvT + 2ull * D_ * D_, D_, D_);
  k_transpose<<<dim3(D_ / 32, D_ / 32), 256, 0, stream>>>(wo, woT, D_, D_);
  k_transpose<<<dim3(I_ / 32, D_ / 32), 256, 0, stream>>>(wg, wgT, D_, I_);
  k_transpose<<<dim3(I_ / 32, D_ / 32), 256, 0, stream>>>(wu, wuT, D_, I_);
  k_transpose<<<dim3(D_ / 32, I_ / 32), 256, 0, stream>>>(wd, wdT, I_, D_);

  k_topk<<<B_, 1024, 0, stream>>>(scores, pos);
  k_gather<<<S_, 256, 0, stream>>>(hidden, pos, scores, ln1w, x, xn, gate, cosb, sinb);

  k_gemm_qkv8<<<dim3(S_ / 256, D3_ / 128), 512, 0, stream>>>(xn, wqkvT, qkv, bq, bk, bv);
  k_rope<<<dim3(S_ / 64, H_), 256, 0, stream>>>(qkv, cosb, sinb, qh, kh, vT);
  k_attn<<<32 * H_, 256, 0, stream>>>(qh, kh, vT, ao);
  k_gemm_wo64<<<dim3(S_ / 64, D_ / 128), 256, 0, stream>>>(ao, woT, x, x1);
  k_rms2<<<S_, 256, 0, stream>>>(x1, ln2w, xn);
  k_gemm_gup8<<<dim3(S_ / 256, I_ / 128), 512, 0, stream>>>(xn, wgT, wuT, qkv);
  k_gemm_down64<<<dim3(S_ / 64, D_ / 128), 256, 0, stream>>>(qkv, wdT, x1, x, gate, pos, out);
}

// Round 9
// 580.956 us; speedup vs baseline: 1.0654x; 1.0042x over previous
//
#include <hip/hip_runtime.h>
#include <stdint.h>

#define B_ 4
#define T_ 2048
#define D_ 2048
#define H_ 16
#define HD_ 128
#define I_ 5632
#define K_ 512
#define S_ 2048
#define D3_ (3 * D_)

typedef float f32x4 __attribute__((ext_vector_type(4)));
typedef short s16x8 __attribute__((ext_vector_type(8)));
typedef __bf16 bf16x8 __attribute__((ext_vector_type(8)));

// ---------- mfma wrapper robust to builtin operand type (short8 vs bf16x8) ----------
template <typename V>
__device__ __forceinline__ auto mfma_try(V a, V b, f32x4 c, int)
    -> decltype(__builtin_amdgcn_mfma_f32_16x16x32_bf16(a, b, c, 0, 0, 0)) {
  return __builtin_amdgcn_mfma_f32_16x16x32_bf16(a, b, c, 0, 0, 0);
}
template <typename V>
__device__ __forceinline__ f32x4 mfma_try(V a, V b, f32x4 c, long) {
  return __builtin_amdgcn_mfma_f32_16x16x32_bf16(
      __builtin_bit_cast(bf16x8, a), __builtin_bit_cast(bf16x8, b), c, 0, 0, 0);
}
__device__ __forceinline__ f32x4 mfma_bf16(s16x8 a, s16x8 b, f32x4 c) {
  return mfma_try(a, b, c, 0);
}

__device__ __forceinline__ void gl_lds16(const void* g, void* l) {
  __builtin_amdgcn_global_load_lds((const __attribute__((address_space(1))) void*)g,
                                   (__attribute__((address_space(3))) void*)l, 16, 0, 0);
}

__device__ __forceinline__ unsigned short f2bf(float f) {
  unsigned u = __float_as_uint(f);
  u += 0x7FFFu + ((u >> 16) & 1);
  return (unsigned short)(u >> 16);
}
__device__ __forceinline__ float bf2f(unsigned short s) {
  return __uint_as_float(((unsigned)s) << 16);
}

// ---------- K1: copy hidden -> out, fused with router scores ----------
__global__ __launch_bounds__(256) void k_copy_scores(const float4* __restrict__ hid,
                                                     float4* __restrict__ dst,
                                                     const float4* __restrict__ rw,
                                                     const float* __restrict__ rb,
                                                     float* __restrict__ scores) {
  int row = blockIdx.x, t = threadIdx.x;
  const float4* hr = hid + (size_t)row * (D_ / 4);
  float4* dr = dst + (size_t)row * (D_ / 4);
  float acc = 0.f;
#pragma unroll
  for (int i = 0; i < 2; i++) {
    float4 v = hr[t + i * 256];
    dr[t + i * 256] = v;
    float4 w = rw[t + i * 256];
    acc += v.x * w.x + v.y * w.y + v.z * w.z + v.w * w.w;
  }
#pragma unroll
  for (int d = 32; d; d >>= 1) acc += __shfl_xor(acc, d);
  __shared__ float red[4];
  if ((t & 63) == 0) red[t >> 6] = acc;
  __syncthreads();
  if (t == 0) scores[row] = red[0] + red[1] + red[2] + red[3] + rb[0];
}

// ---------- K3: exact top-k (bitonic, matches jax.lax.top_k tie-break) ----------
__global__ __launch_bounds__(1024) void k_topk(const float* __restrict__ scores,
                                               int* __restrict__ pos) {
  __shared__ unsigned long long keys[T_];
  __shared__ int sidx[K_];
  int b = blockIdx.x, t = threadIdx.x;
  for (int i = t; i < T_; i += 1024) {
    unsigned u = __float_as_uint(scores[b * T_ + i]);
    u = (u & 0x80000000u) ? ~u : (u | 0x80000000u);
    keys[i] = ((unsigned long long)u << 32) | (unsigned)(~(unsigned)i);
  }
  __syncthreads();
  for (int k = 2; k <= T_; k <<= 1)
    for (int j = k >> 1; j > 0; j >>= 1) {
      for (int i = t; i < T_; i += 1024) {
        int l = i ^ j;
        if (l > i) {
          unsigned long long a = keys[i], c = keys[l];
          bool desc = ((i & k) == 0);
          if (desc ? (a < c) : (a > c)) { keys[i] = c; keys[l] = a; }
        }
      }
      __syncthreads();
    }
  if (t < K_) sidx[t] = (int)(~(unsigned)(keys[t] & 0xFFFFFFFFull));
  __syncthreads();
  for (int k = 2; k <= K_; k <<= 1)
    for (int j = k >> 1; j > 0; j >>= 1) {
      if (t < K_) {
        int i = t, l = i ^ j;
        if (l > i && l < K_) {
          int a = sidx[i], c = sidx[l];
          bool asc = ((i & k) == 0);
          if (asc ? (a > c) : (a < c)) { sidx[i] = c; sidx[l] = a; }
        }
      }
      __syncthreads();
    }
  if (t < K_) pos[b * K_ + t] = sidx[t];
}

// ---------- K4: gather + RMS1 + gate + rope tables ----------
__global__ __launch_bounds__(256) void k_gather(const float* __restrict__ hidden,
    const int* __restrict__ pos, const float* __restrict__ scores,
    const float* __restrict__ ln1w, float* __restrict__ x,
    unsigned short* __restrict__ xn, float* __restrict__ gate,
    float* __restrict__ cosb, float* __restrict__ sinb) {
  int s = blockIdx.x, t = threadIdx.x;
  int b = s >> 9, p = pos[s];
  const float* src = hidden + ((size_t)b * T_ + p) * D_;
  float v[8];
  float ss = 0.f;
#pragma unroll
  for (int i = 0; i < 8; i++) { v[i] = src[t + i * 256]; ss += v[i] * v[i]; }
  __shared__ float red[4];
#pragma unroll
  for (int d = 32; d; d >>= 1) ss += __shfl_xor(ss, d);
  if ((t & 63) == 0) red[t >> 6] = ss;
  __syncthreads();
  ss = red[0] + red[1] + red[2] + red[3];
  float scale = rsqrtf(ss / (float)D_ + 1e-6f);
  float* xd = x + (size_t)s * D_;
  unsigned short* xnd = xn + (size_t)s * D_;
#pragma unroll
  for (int i = 0; i < 8; i++) {
    int c = t + i * 256;
    xd[c] = v[i];
    xnd[c] = f2bf(v[i] * scale * ln1w[c]);
  }
  if (t == 0) gate[s] = 1.f / (1.f + expf(-scores[b * T_ + p]));
  if (t < 64) {
    float invf = powf(10000.0f, -(float)t / 64.0f);
    float f = (float)p * invf;
    cosb[s * 64 + t] = cosf(f);
    sinb[s * 64 + t] = sinf(f);
  }
}

// ---------- K5: transpose + f32->bf16 (weights to Bt layout), ushort4 writes ----------
__global__ __launch_bounds__(256) void k_transpose(const float* __restrict__ src,
                                                   unsigned short* __restrict__ dst,
                                                   int R, int C) {
  __shared__ float tile[32][33];
  int tx = threadIdx.x & 31, ty = threadIdx.x >> 5;
  int c0 = blockIdx.x * 32, r0 = blockIdx.y * 32;
#pragma unroll
  for (int i = 0; i < 4; i++) {
    int r = ty + i * 8;
    tile[r][tx] = src[(size_t)(r0 + r) * C + c0 + tx];
  }
  __syncthreads();
  int drow = threadIdx.x >> 3;        // 0..31 : dst row (c index)
  int dc4 = (threadIdx.x & 7) * 4;    // dst col base (r index)
  ushort4 v;
  v.x = f2bf(tile[dc4 + 0][drow]);
  v.y = f2bf(tile[dc4 + 1][drow]);
  v.z = f2bf(tile[dc4 + 2][drow]);
  v.w = f2bf(tile[dc4 + 3][drow]);
  *(ushort4*)&dst[(size_t)(c0 + drow) * R + r0 + dc4] = v;
}

// ======================================================================
// GEMM templates (BK=32, 2-buf, counted vmcnt, SWZ swizzle, MFMA-split).
// Swizzle involution: byte ^= (((row>>1)&3)<<4) — 2 lanes/bank = free (m136).
// Applied to GLOBAL source (gl_lds dest must be linear) and to the read.
// Schedule per K-tile t (buffer b = t&1), L = loads/thread/tile:
//   vmcnt(L) -> barrier -> ds_read all frags -> MFMA half 1
//     (no explicit lgkm drain before it: compiler emits COUNTED lgkmcnt,
//      so the MFMA head overlaps the read tail)
//   -> lgkmcnt(0) -> barrier [all waves' reads of buf b done]
//   -> stage tile t+2 into buf b -> MFMA half 2 (overlaps stage issue).
// Stage -> its vmcnt consumer distance stays ~1.5-2 iters (R7 lesson).
// ======================================================================
#define SWZ(row) ((((row) >> 1) & 3) << 4)

// 512-thread staging helpers
__device__ __forceinline__ void stage16k(const unsigned short* __restrict__ g, int ldK,
                                         int row0, int k0, char* lds, int tid) {
#pragma unroll
  for (int c = 0; c < 2; c++) {
    int off = c * 8192 + tid * 16;  // 16 KB = 256 rows
    int row = off >> 6;
    int cb = (off & 63) ^ SWZ(row);
    gl_lds16(g + (size_t)(row0 + row) * ldK + k0 + (cb >> 1), lds + off);
  }
}
__device__ __forceinline__ void stage8k(const unsigned short* __restrict__ g, int ldK,
                                        int row0, int k0, char* lds, int tid) {
  int off = tid * 16;  // 8 KB = 128 rows (512 thr)
  int row = off >> 6;
  int cb = (off & 63) ^ SWZ(row);
  gl_lds16(g + (size_t)(row0 + row) * ldK + k0 + (cb >> 1), lds + off);
}
// 256-thread staging helper (128 rows)
__device__ __forceinline__ void stage128r(const unsigned short* __restrict__ g, int ldK,
                                          int row0, int k0, char* lds, int tid) {
#pragma unroll
  for (int c = 0; c < 2; c++) {
    int off = c * 4096 + tid * 16;  // 8 KB = 128 rows (256 thr)
    int row = off >> 6;
    int cb = (off & 63) ^ SWZ(row);
    gl_lds16(g + (size_t)(row0 + row) * ldK + k0 + (cb >> 1), lds + off);
  }
}
__device__ __forceinline__ s16x8 ldfrag(const char* base, int row, int g) {
  return *(const s16x8*)(base + row * 64 + ((g * 16) ^ SWZ(row)));
}

// ---------- K6: fused QKV GEMM, 256x128 tile, 8 waves, bias epilogue ----------
__global__ __launch_bounds__(512, 2) void k_gemm_qkv8(const unsigned short* __restrict__ A,
    const unsigned short* __restrict__ Bt, unsigned short* __restrict__ C,
    const float* __restrict__ bq, const float* __restrict__ bk,
    const float* __restrict__ bv) {
  alignas(16) __shared__ short As[2][256 * 32];
  alignas(16) __shared__ short Bs[2][128 * 32];
  int tid = threadIdx.x;
  int lane = tid & 63, g = lane >> 4, lr = lane & 15;
  int wid = tid >> 6, wm = wid >> 1, wn = wid & 1;
  int m0 = blockIdx.x * 256, n0 = blockIdx.y * 128;
  f32x4 zero4 = {0.f, 0.f, 0.f, 0.f};
  f32x4 acc[4][4];
#pragma unroll
  for (int m = 0; m < 4; m++)
#pragma unroll
    for (int n = 0; n < 4; n++) acc[m][n] = zero4;
  const int nkt = D_ / 32;
  stage16k(A, D_, m0, 0, (char*)As[0], tid);
  stage8k(Bt, D_, n0, 0, (char*)Bs[0], tid);
  stage16k(A, D_, m0, 32, (char*)As[1], tid);
  stage8k(Bt, D_, n0, 32, (char*)Bs[1], tid);
  int arow = wm * 64 + lr;
  int brow = wn * 64 + lr;
  for (int t = 0; t < nkt; t++) {
    int b = t & 1;
    const char* Ab = (const char*)As[b];
    const char* Bb = (const char*)Bs[b];
    if (t + 1 < nkt) asm volatile("s_waitcnt vmcnt(3)" ::: "memory");
    else             asm volatile("s_waitcnt vmcnt(0)" ::: "memory");
    __builtin_amdgcn_s_barrier();
    s16x8 af[4], bf4[4];
#pragma unroll
    for (int i = 0; i < 4; i++) af[i] = ldfrag(Ab, arow + i * 16, g);
#pragma unroll
    for (int i = 0; i < 4; i++) bf4[i] = ldfrag(Bb, brow + i * 16, g);
    __builtin_amdgcn_s_setprio(1);
#pragma unroll
    for (int m = 0; m < 4; m++)
#pragma unroll
      for (int n = 0; n < 2; n++) acc[m][n] = mfma_bf16(af[m], bf4[n], acc[m][n]);
    __builtin_amdgcn_s_setprio(0);
    asm volatile("s_waitcnt lgkmcnt(0)" ::: "memory");
    __builtin_amdgcn_s_barrier();
    if (t + 2 < nkt) {
      stage16k(A, D_, m0, (t + 2) * 32, (char*)As[b], tid);
      stage8k(Bt, D_, n0, (t + 2) * 32, (char*)Bs[b], tid);
    }
    __builtin_amdgcn_s_setprio(1);
#pragma unroll
    for (int m = 0; m < 4; m++)
#pragma unroll
      for (int n = 2; n < 4; n++) acc[m][n] = mfma_bf16(af[m], bf4[n], acc[m][n]);
    __builtin_amdgcn_s_setprio(0);
  }
#pragma unroll
  for (int m = 0; m < 4; m++)
#pragma unroll
    for (int n = 0; n < 4; n++)
#pragma unroll
      for (int r = 0; r < 4; r++) {
        int row = m0 + wm * 64 + m * 16 + (g << 2) + r;
        int col = n0 + wn * 64 + n * 16 + lr;
        float bias = (col < D_) ? bq[col] : ((col < 2 * D_) ? bk[col - D_] : bv[col - 2 * D_]);
        C[(size_t)row * D3_ + col] = f2bf(acc[m][n][r] + bias);
      }
}

// ---------- K11: fused gate/up GEMM, 256x(128+128), 8 waves, MFMA-split ----------
__global__ __launch_bounds__(512, 2) void k_gemm_gup8(const unsigned short* __restrict__ A,
    const unsigned short* __restrict__ Bg, const unsigned short* __restrict__ Bu,
    unsigned short* __restrict__ act) {
  alignas(16) __shared__ short As[2][256 * 32];
  alignas(16) __shared__ short Bgs[2][128 * 32];
  alignas(16) __shared__ short Bus[2][128 * 32];
  int tid = threadIdx.x;
  int lane = tid & 63, g = lane >> 4, lr = lane & 15;
  int wid = tid >> 6, wm = wid >> 1, wn = wid & 1;
  int m0 = blockIdx.x * 256, n0 = blockIdx.y * 128;
  f32x4 zero4 = {0.f, 0.f, 0.f, 0.f};
  f32x4 ag[4][4], au[4][4];
#pragma unroll
  for (int m = 0; m < 4; m++)
#pragma unroll
    for (int n = 0; n < 4; n++) { ag[m][n] = zero4; au[m][n] = zero4; }
  const int nkt = D_ / 32;
  stage16k(A, D_, m0, 0, (char*)As[0], tid);
  stage8k(Bg, D_, n0, 0, (char*)Bgs[0], tid);
  stage8k(Bu, D_, n0, 0, (char*)Bus[0], tid);
  stage16k(A, D_, m0, 32, (char*)As[1], tid);
  stage8k(Bg, D_, n0, 32, (char*)Bgs[1], tid);
  stage8k(Bu, D_, n0, 32, (char*)Bus[1], tid);
  int arow = wm * 64 + lr;
  int brow = wn * 64 + lr;
  for (int t = 0; t < nkt; t++) {
    int b = t & 1;
    const char* Ab = (const char*)As[b];
    const char* Bgb = (const char*)Bgs[b];
    const char* Bub = (const char*)Bus[b];
    if (t + 1 < nkt) asm volatile("s_waitcnt vmcnt(4)" ::: "memory");
    else             asm volatile("s_waitcnt vmcnt(0)" ::: "memory");
    __builtin_amdgcn_s_barrier();
    s16x8 af[4], bg4[4], bu4[4];
#pragma unroll
    for (int i = 0; i < 4; i++) af[i] = ldfrag(Ab, arow + i * 16, g);
#pragma unroll
    for (int i = 0; i < 4; i++) bg4[i] = ldfrag(Bgb, brow + i * 16, g);
#pragma unroll
    for (int i = 0; i < 4; i++) bu4[i] = ldfrag(Bub, brow + i * 16, g);
    __builtin_amdgcn_s_setprio(1);
#pragma unroll
    for (int m = 0; m < 4; m++)
#pragma unroll
      for (int n = 0; n < 4; n++) ag[m][n] = mfma_bf16(af[m], bg4[n], ag[m][n]);
    __builtin_amdgcn_s_setprio(0);
    asm volatile("s_waitcnt lgkmcnt(0)" ::: "memory");
    __builtin_amdgcn_s_barrier();
    if (t + 2 < nkt) {
      stage16k(A, D_, m0, (t + 2) * 32, (char*)As[b], tid);
      stage8k(Bg, D_, n0, (t + 2) * 32, (char*)Bgs[b], tid);
      stage8k(Bu, D_, n0, (t + 2) * 32, (char*)Bus[b], tid);
    }
    __builtin_amdgcn_s_setprio(1);
#pragma unroll
    for (int m = 0; m < 4; m++)
#pragma unroll
      for (int n = 0; n < 4; n++) au[m][n] = mfma_bf16(af[m], bu4[n], au[m][n]);
    __builtin_amdgcn_s_setprio(0);
  }
#pragma unroll
  for (int m = 0; m < 4; m++)
#pragma unroll
    for (int n = 0; n < 4; n++)
#pragma unroll
      for (int r = 0; r < 4; r++) {
        int row = m0 + wm * 64 + m * 16 + (g << 2) + r;
        int col = n0 + wn * 64 + n * 16 + lr;
        float gv = ag[m][n][r], uv = au[m][n][r];
        float si = gv / (1.f + __expf(-gv));
        act[(size_t)row * I_ + col] = f2bf(si * uv);
      }
}

// ---------- K9: wo GEMM + residual, 128x128 tile, 4 waves, 3 blk/CU ----------
__global__ __launch_bounds__(256, 3) void k_gemm_wo128(const unsigned short* __restrict__ A,
    const unsigned short* __restrict__ Bt, const float* __restrict__ xres,
    float* __restrict__ x1) {
  alignas(16) __shared__ short As[2][128 * 32];
  alignas(16) __shared__ short Bs[2][128 * 32];
  int tid = threadIdx.x;
  int lane = tid & 63, g = lane >> 4, lr = lane & 15;
  int w = tid >> 6;
  int wr = (w >> 1) * 64, wc = (w & 1) * 64;
  int m0 = blockIdx.x * 128, n0 = blockIdx.y * 128;
  f32x4 zero4 = {0.f, 0.f, 0.f, 0.f};
  f32x4 acc[4][4];
#pragma unroll
  for (int m = 0; m < 4; m++)
#pragma unroll
    for (int n = 0; n < 4; n++) acc[m][n] = zero4;
  const int nkt = D_ / 32;
  stage128r(A, D_, m0, 0, (char*)As[0], tid);
  stage128r(Bt, D_, n0, 0, (char*)Bs[0], tid);
  stage128r(A, D_, m0, 32, (char*)As[1], tid);
  stage128r(Bt, D_, n0, 32, (char*)Bs[1], tid);
  for (int t = 0; t < nkt; t++) {
    int b = t & 1;
    const char* Ab = (const char*)As[b];
    const char* Bb = (const char*)Bs[b];
    if (t + 1 < nkt) asm volatile("s_waitcnt vmcnt(4)" ::: "memory");
    else             asm volatile("s_waitcnt vmcnt(0)" ::: "memory");
    __builtin_amdgcn_s_barrier();
    s16x8 af[4], bf4[4];
#pragma unroll
    for (int i = 0; i < 4; i++) af[i] = ldfrag(Ab, wr + i * 16 + lr, g);
#pragma unroll
    for (int i = 0; i < 4; i++) bf4[i] = ldfrag(Bb, wc + i * 16 + lr, g);
    __builtin_amdgcn_s_setprio(1);
#pragma unroll
    for (int m = 0; m < 4; m++)
#pragma unroll
      for (int n = 0; n < 2; n++) acc[m][n] = mfma_bf16(af[m], bf4[n], acc[m][n]);
    __builtin_amdgcn_s_setprio(0);
    asm volatile("s_waitcnt lgkmcnt(0)" ::: "memory");
    __builtin_amdgcn_s_barrier();
    if (t + 2 < nkt) {
      stage128r(A, D_, m0, (t + 2) * 32, (char*)As[b], tid);
      stage128r(Bt, D_, n0, (t + 2) * 32, (char*)Bs[b], tid);
    }
    __builtin_amdgcn_s_setprio(1);
#pragma unroll
    for (int m = 0; m < 4; m++)
#pragma unroll
      for (int n = 2; n < 4; n++) acc[m][n] = mfma_bf16(af[m], bf4[n], acc[m][n]);
    __builtin_amdgcn_s_setprio(0);
  }
#pragma unroll
  for (int m = 0; m < 4; m++)
#pragma unroll
    for (int n = 0; n < 4; n++)
#pragma unroll
      for (int r = 0; r < 4; r++) {
        int row = m0 + wr + m * 16 + (g << 2) + r;
        int col = n0 + wc + n * 16 + lr;
        x1[(size_t)row * D_ + col] = acc[m][n][r] + xres[(size_t)row * D_ + col];
      }
}

// ---------- K12: down GEMM + residual + blend + scatter, 128x128, 3 blk/CU ----------
__global__ __launch_bounds__(256, 3) void k_gemm_down128(const unsigned short* __restrict__ A,
    const unsigned short* __restrict__ Bt, const float* __restrict__ x1,
    const float* __restrict__ x, const float* __restrict__ gate,
    const int* __restrict__ pos, float* __restrict__ out) {
  alignas(16) __shared__ short As[2][128 * 32];
  alignas(16) __shared__ short Bs[2][128 * 32];
  int tid = threadIdx.x;
  int lane = tid & 63, g = lane >> 4, lr = lane & 15;
  int w = tid >> 6;
  int wr = (w >> 1) * 64, wc = (w & 1) * 64;
  int m0 = blockIdx.x * 128, n0 = blockIdx.y * 128;
  f32x4 zero4 = {0.f, 0.f, 0.f, 0.f};
  f32x4 acc[4][4];
#pragma unroll
  for (int m = 0; m < 4; m++)
#pragma unroll
    for (int n = 0; n < 4; n++) acc[m][n] = zero4;
  const int nkt = I_ / 32;
  stage128r(A, I_, m0, 0, (char*)As[0], tid);
  stage128r(Bt, I_, n0, 0, (char*)Bs[0], tid);
  stage128r(A, I_, m0, 32, (char*)As[1], tid);
  stage128r(Bt, I_, n0, 32, (char*)Bs[1], tid);
  for (int t = 0; t < nkt; t++) {
    int b = t & 1;
    const char* Ab = (const char*)As[b];
    const char* Bb = (const char*)Bs[b];
    if (t + 1 < nkt) asm volatile("s_waitcnt vmcnt(4)" ::: "memory");
    else             asm volatile("s_waitcnt vmcnt(0)" ::: "memory");
    __builtin_amdgcn_s_barrier();
    s16x8 af[4], bf4[4];
#pragma unroll
    for (int i = 0; i < 4; i++) af[i] = ldfrag(Ab, wr + i * 16 + lr, g);
#pragma unroll
    for (int i = 0; i < 4; i++) bf4[i] = ldfrag(Bb, wc + i * 16 + lr, g);
    __builtin_amdgcn_s_setprio(1);
#pragma unroll
    for (int m = 0; m < 4; m++)
#pragma unroll
      for (int n = 0; n < 2; n++) acc[m][n] = mfma_bf16(af[m], bf4[n], acc[m][n]);
    __builtin_amdgcn_s_setprio(0);
    asm volatile("s_waitcnt lgkmcnt(0)" ::: "memory");
    __builtin_amdgcn_s_barrier();
    if (t + 2 < nkt) {
      stage128r(A, I_, m0, (t + 2) * 32, (char*)As[b], tid);
      stage128r(Bt, I_, n0, (t + 2) * 32, (char*)Bs[b], tid);
    }
    __builtin_amdgcn_s_setprio(1);
#pragma unroll
    for (int m = 0; m < 4; m++)
#pragma unroll
      for (int n = 2; n < 4; n++) acc[m][n] = mfma_bf16(af[m], bf4[n], acc[m][n]);
    __builtin_amdgcn_s_setprio(0);
  }
#pragma unroll
  for (int m = 0; m < 4; m++)
#pragma unroll
    for (int n = 0; n < 4; n++)
#pragma unroll
      for (int r = 0; r < 4; r++) {
        int srow = m0 + wr + m * 16 + (g << 2) + r;
        int col = n0 + wc + n * 16 + lr;
        float proc = acc[m][n][r] + x1[(size_t)srow * D_ + col];
        float gt = gate[srow];
        float xv = x[(size_t)srow * D_ + col];
        int bb = srow >> 9;
        int p = pos[srow];
        out[((size_t)bb * T_ + p) * D_ + col] = gt * proc + (1.f - gt) * xv;
      }
}

// ---------- K7: RoPE + head relayout (q,k row-major per head; v transposed) ----------
__global__ __launch_bounds__(256) void k_rope(const unsigned short* __restrict__ qkv,
    const float* __restrict__ cosb, const float* __restrict__ sinb,
    unsigned short* __restrict__ qh, unsigned short* __restrict__ kh,
    unsigned short* __restrict__ vT) {
  int s0 = blockIdx.x * 64;
  int h = blockIdx.y;
  int t = threadIdx.x;
#pragma unroll
  for (int i = 0; i < 16; i++) {
    int flat = t + i * 256;
    int r = flat >> 6, dp = flat & 63;
    int s = s0 + r;
    float c = cosb[s * 64 + dp], sn = sinb[s * 64 + dp];
    const unsigned short* qrow = qkv + (size_t)s * D3_ + h * HD_;
    float q1 = bf2f(qrow[dp]), q2 = bf2f(qrow[dp + 64]);
    unsigned short* qdst = qh + ((size_t)h * S_ + s) * HD_;
    qdst[dp] = f2bf(q1 * c - q2 * sn);
    qdst[dp + 64] = f2bf(q2 * c + q1 * sn);
    const unsigned short* krow = qrow + D_;
    float k1 = bf2f(krow[dp]), k2 = bf2f(krow[dp + 64]);
    unsigned short* kdst = kh + ((size_t)h * S_ + s) * HD_;
    kdst[dp] = f2bf(k1 * c - k2 * sn);
    kdst[dp + 64] = f2bf(k2 * c + k1 * sn);
  }
  __shared__ unsigned short vt[128][66];
#pragma unroll
  for (int i = 0; i < 32; i++) {
    int flat = t + i * 256;
    int r = flat >> 7, d = flat & 127;
    vt[d][r] = qkv[(size_t)(s0 + r) * D3_ + 2 * D_ + h * HD_ + d];
  }
  __syncthreads();
#pragma unroll
  for (int i = 0; i < 32; i++) {
    int flat = t + i * 256;
    int d = flat >> 6, sc = flat & 63;
    vT[((size_t)h * HD_ + d) * S_ + s0 + sc] = vt[d][sc];
  }
}

// ======================================================================
// K8: flash attention (q-tile 64, LPT order, swizzled LDS, dbuf KV)
// ======================================================================
__device__ __forceinline__ void stage_kv(const unsigned short* __restrict__ kh,
                                         const unsigned short* __restrict__ vT,
                                         size_t hbase, int kt, char* KsB, char* VsB, int tid) {
#pragma unroll
  for (int c = 0; c < 4; c++) {
    int off = c * 4096 + tid * 16;
    int row = off >> 8;
    int cb = (off & 255) ^ ((row & 7) << 4);
    gl_lds16(kh + hbase + (size_t)(kt * 64 + row) * HD_ + (cb >> 1), KsB + off);
  }
#pragma unroll
  for (int c = 0; c < 4; c++) {
    int off = c * 4096 + tid * 16;
    int row = off >> 7;
    int cb = (off & 127) ^ ((row & 7) << 4);
    gl_lds16(vT + hbase + (size_t)row * S_ + kt * 64 + (cb >> 1), VsB + off);
  }
}

__global__ __launch_bounds__(256, 2) void k_attn(const unsigned short* __restrict__ qh,
                                                 const unsigned short* __restrict__ kh,
                                                 const unsigned short* __restrict__ vT,
                                                 unsigned short* __restrict__ ao) {
  alignas(16) __shared__ short Ks[2][64 * 128];   // [kv][d], 256B rows, swizzled
  alignas(16) __shared__ short Vs[2][128 * 64];   // [d][kv], 128B rows, swizzled
  alignas(16) __shared__ short Ps[4][16 * 64];    // per-wave P, 128B rows, swizzled
  int bidx = blockIdx.x;
  int head = bidx & 15;
  int slot = bidx >> 4;                      // 0..31
  int qt = (slot < 16) ? (31 - slot) : (slot - 16);
  int q0 = qt * 64;
  int tid = threadIdx.x, w = tid >> 6, lane = tid & 63, g = lane >> 4, lr = lane & 15;
  size_t hbase = (size_t)head * S_ * HD_;
  int qw = q0 + w * 16;
  char* PsW = (char*)&Ps[w][0];
  s16x8 qf[4];
#pragma unroll
  for (int ks = 0; ks < 4; ks++)
    qf[ks] = *(const s16x8*)&qh[hbase + (size_t)(qw + lr) * HD_ + ks * 32 + g * 8];
  f32x4 o[8];
  f32x4 zero4 = {0.f, 0.f, 0.f, 0.f};
#pragma unroll
  for (int nf = 0; nf < 8; nf++) o[nf] = zero4;
  float m_i[4], l_i[4];
#pragma unroll
  for (int r = 0; r < 4; r++) { m_i[r] = -1e30f; l_i[r] = 0.f; }
  const float sc = 0.08838834764831843f;  // 1/sqrt(128)

  stage_kv(kh, vT, hbase, 0, (char*)Ks[0], (char*)Vs[0], tid);
  if (qt > 0) stage_kv(kh, vT, hbase, 1, (char*)Ks[1], (char*)Vs[1], tid);

  for (int kt = 0; kt <= qt; kt++) {
    int b = kt & 1;
    const char* KsB = (const char*)Ks[b];
    const char* VsB = (const char*)Vs[b];
    if (kt < qt) asm volatile("s_waitcnt vmcnt(8)" ::: "memory");
    else         asm volatile("s_waitcnt vmcnt(0)" ::: "memory");
    __builtin_amdgcn_s_barrier();
    f32x4 sacc[4];
#pragma unroll
    for (int nf = 0; nf < 4; nf++) sacc[nf] = zero4;
#pragma unroll
    for (int ks = 0; ks < 4; ks++) {
      s16x8 kf[4];
#pragma unroll
      for (int nf = 0; nf < 4; nf++) {
        int row = nf * 16 + lr;
        kf[nf] = *(const s16x8*)(KsB + row * 256 + (((ks << 6) + (g << 4)) ^ ((row & 7) << 4)));
      }
#pragma unroll
      for (int nf = 0; nf < 4; nf++) sacc[nf] = mfma_bf16(qf[ks], kf[nf], sacc[nf]);
    }
    bool diag = (kt == qt);
#pragma unroll
    for (int r = 0; r < 4; r++) {
      int prow = (g << 2) + r;
      int qrow = qw + prow;
      float pv[4];
      float mx = -1e30f;
#pragma unroll
      for (int nf = 0; nf < 4; nf++) {
        float vv = sacc[nf][r] * sc;
        if (diag) {
          int kc = kt * 64 + nf * 16 + lr;
          vv = (kc <= qrow) ? vv : -1e30f;
        }
        pv[nf] = vv;
        mx = fmaxf(mx, vv);
      }
#pragma unroll
      for (int d = 1; d < 16; d <<= 1) mx = fmaxf(mx, __shfl_xor(mx, d));
      float mold = m_i[r], mnew = fmaxf(mold, mx);
      float corr = __expf(mold - mnew);
      float ssum = 0.f;
#pragma unroll
      for (int nf = 0; nf < 4; nf++) {
        float pe = __expf(pv[nf] - mnew);
        int cb = ((nf * 16 + lr) << 1) ^ ((prow & 7) << 4);
        *(unsigned short*)(PsW + prow * 128 + cb) = f2bf(pe);
        ssum += pe;
      }
#pragma unroll
      for (int d = 1; d < 16; d <<= 1) ssum += __shfl_xor(ssum, d);
      l_i[r] = l_i[r] * corr + ssum;
      m_i[r] = mnew;
#pragma unroll
      for (int nf = 0; nf < 8; nf++) o[nf][r] *= corr;
    }
    s16x8 pa[2];
#pragma unroll
    for (int ks = 0; ks < 2; ks++)
      pa[ks] = *(const s16x8*)(PsW + lr * 128 + (((ks << 6) + (g << 4)) ^ ((lr & 7) << 4)));
#pragma unroll
    for (int nf = 0; nf < 8; nf++) {
#pragma unroll
      for (int ks = 0; ks < 2; ks++) {
        int row = nf * 16 + lr;
        s16x8 vb = *(const s16x8*)(VsB + row * 128 + (((ks << 6) + (g << 4)) ^ ((row & 7) << 4)));
        o[nf] = mfma_bf16(pa[ks], vb, o[nf]);
      }
    }
    asm volatile("s_waitcnt lgkmcnt(0)" ::: "memory");
    __builtin_amdgcn_s_barrier();
    if (kt + 2 <= qt)
      stage_kv(kh, vT, hbase, kt + 2, (char*)Ks[b], (char*)Vs[b], tid);
  }
#pragma unroll
  for (int nf = 0; nf < 8; nf++)
#pragma unroll
    for (int r = 0; r < 4; r++) {
      int row = qw + (g << 2) + r;
      int col = head * HD_ + nf * 16 + lr;
      ao[(size_t)row * D_ + col] = f2bf(o[nf][r] / l_i[r]);
    }
}

// ---------- K10: RMS2 ----------
__global__ __launch_bounds__(256) void k_rms2(const float* __restrict__ x1,
                                              const float* __restrict__ ln2w,
                                              unsigned short* __restrict__ xn2) {
  int s = blockIdx.x, t = threadIdx.x;
  const float* src = x1 + (size_t)s * D_;
  float v[8];
  float ss = 0.f;
#pragma unroll
  for (int i = 0; i < 8; i++) { v[i] = src[t + i * 256]; ss += v[i] * v[i]; }
  __shared__ float red[4];
#pragma unroll
  for (int d = 32; d; d >>= 1) ss += __shfl_xor(ss, d);
  if ((t & 63) == 0) red[t >> 6] = ss;
  __syncthreads();
  ss = red[0] + red[1] + red[2] + red[3];
  float scale = rsqrtf(ss / (float)D_ + 1e-6f);
  unsigned short* dst = xn2 + (size_t)s * D_;
#pragma unroll
  for (int i = 0; i < 8; i++) {
    int c = t + i * 256;
    dst[c] = f2bf(v[i] * scale * ln2w[c]);
  }
}

extern "C" void kernel_launch(void* const* d_in, const int* in_sizes, int n_in,
                              void* d_out, int out_size, void* d_ws, size_t ws_size,
                              hipStream_t stream) {
  (void)in_sizes; (void)n_in; (void)out_size; (void)ws_size;
  const float* hidden = (const float*)d_in[0];
  const float* router_w = (const float*)d_in[1];
  const float* router_b = (const float*)d_in[2];
  const float* ln1w = (const float*)d_in[3];
  const float* ln2w = (const float*)d_in[4];
  const float* wq = (const float*)d_in[5];
  const float* bq = (const float*)d_in[6];
  const float* wk = (const float*)d_in[7];
  const float* bk = (const float*)d_in[8];
  const float* wv = (const float*)d_in[9];
  const float* bv = (const float*)d_in[10];
  const float* wo = (const float*)d_in[11];
  const float* wg = (const float*)d_in[12];
  const float* wu = (const float*)d_in[13];
  const float* wd = (const float*)d_in[14];
  float* out = (float*)d_out;

  char* ws = (char*)d_ws;
  size_t off = 0;
  auto alloc = [&](size_t bytes) {
    char* p = ws + off;
    off += (bytes + 255) & ~(size_t)255;
    return p;
  };
  unsigned short* wqkvT = (unsigned short*)alloc(3ull * D_ * D_ * 2);
  unsigned short* woT = (unsigned short*)alloc((size_t)D_ * D_ * 2);
  unsigned short* wgT = (unsigned short*)alloc((size_t)I_ * D_ * 2);
  unsigned short* wuT = (unsigned short*)alloc((size_t)I_ * D_ * 2);
  unsigned short* wdT = (unsigned short*)alloc((size_t)D_ * I_ * 2);
  float* scores = (float*)alloc((size_t)B_ * T_ * 4);
  int* pos = (int*)alloc((size_t)S_ * 4);
  float* gate = (float*)alloc((size_t)S_ * 4);
  float* x = (float*)alloc((size_t)S_ * D_ * 4);
  float* x1 = (float*)alloc((size_t)S_ * D_ * 4);
  unsigned short* xn = (unsigned short*)alloc((size_t)S_ * D_ * 2);  // reused as x1n
  float* cosb = (float*)alloc((size_t)S_ * 64 * 4);
  float* sinb = (float*)alloc((size_t)S_ * 64 * 4);
  unsigned short* qkv = (unsigned short*)alloc((size_t)S_ * D3_ * 2);  // reused as act
  unsigned short* qh = (unsigned short*)alloc((size_t)H_ * S_ * HD_ * 2);
  unsigned short* kh = (unsigned short*)alloc((size_t)H_ * S_ * HD_ * 2);
  unsigned short* vT = (unsigned short*)alloc((size_t)H_ * S_ * HD_ * 2);
  unsigned short* ao = (unsigned short*)alloc((size_t)S_ * D_ * 2);

  k_copy_scores<<<B_ * T_, 256, 0, stream>>>((const float4*)hidden, (float4*)out,
                                             (const float4*)router_w, router_b, scores);

  k_transpose<<<dim3(D_ / 32, D_ / 32), 256, 0, stream>>>(wq, wqkvT, D_, D_);
  k_transpose<<<dim3(D_ / 32, D_ / 32), 256, 0, stream>>>(wk, wqkvT + (size_t)D_ * D_, D_, D_);
  k_transpose<<<dim3(D_ / 32, D_ / 32), 256, 0, stream>>>(wv, wqkvT + 2ull * D_ * D_, D_, D_);
  k_transpose<<<dim3(D_ / 32, D_ / 32), 256, 0, stream>>>(wo, woT, D_, D_);
  k_transpose<<<dim3(I_ / 32, D_ / 32), 256, 0, stream>>>(wg, wgT, D_, I_);
  k_transpose<<<dim3(I_ / 32, D_ / 32), 256, 0, stream>>>(wu, wuT, D_, I_);
  k_transpose<<<dim3(D_ / 32, I_ / 32), 256, 0, stream>>>(wd, wdT, I_, D_);

  k_topk<<<B_, 1024, 0, stream>>>(scores, pos);
  k_gather<<<S_, 256, 0, stream>>>(hidden, pos, scores, ln1w, x, xn, gate, cosb, sinb);

  k_gemm_qkv8<<<dim3(S_ / 256, D3_ / 128), 512, 0, stream>>>(xn, wqkvT, qkv, bq, bk, bv);
  k_rope<<<dim3(S_ / 64, H_), 256, 0, stream>>>(qkv, cosb, sinb, qh, kh, vT);
  k_attn<<<32 * H_, 256, 0, stream>>>(qh, kh, vT, ao);
  k_gemm_wo128<<<dim3(S_ / 128, D_ / 128), 256, 0, stream>>>(ao, woT, x, x1);
  k_rms2<<<S_, 256, 0, stream>>>(x1, ln2w, xn);
  k_gemm_gup8<<<dim3(S_ / 256, I_ / 128), 512, 0, stream>>>(xn, wgT, wuT, qkv);
  k_gemm_down128<<<dim3(S_ / 128, D_ / 128), 256, 0, stream>>>(qkv, wdT, x1, x, gate, pos, out);
}

// Round 10
// 537.518 us; speedup vs baseline: 1.1515x; 1.0808x over previous
//
#include <hip/hip_runtime.h>
#include <stdint.h>

#define B_ 4
#define T_ 2048
#define D_ 2048
#define H_ 16
#define HD_ 128
#define I_ 5632
#define K_ 512
#define S_ 2048
#define D3_ (3 * D_)

typedef float f32x4 __attribute__((ext_vector_type(4)));
typedef short s16x8 __attribute__((ext_vector_type(8)));
typedef __bf16 bf16x8 __attribute__((ext_vector_type(8)));

// ---------- mfma wrapper robust to builtin operand type (short8 vs bf16x8) ----------
template <typename V>
__device__ __forceinline__ auto mfma_try(V a, V b, f32x4 c, int)
    -> decltype(__builtin_amdgcn_mfma_f32_16x16x32_bf16(a, b, c, 0, 0, 0)) {
  return __builtin_amdgcn_mfma_f32_16x16x32_bf16(a, b, c, 0, 0, 0);
}
template <typename V>
__device__ __forceinline__ f32x4 mfma_try(V a, V b, f32x4 c, long) {
  return __builtin_amdgcn_mfma_f32_16x16x32_bf16(
      __builtin_bit_cast(bf16x8, a), __builtin_bit_cast(bf16x8, b), c, 0, 0, 0);
}
__device__ __forceinline__ f32x4 mfma_bf16(s16x8 a, s16x8 b, f32x4 c) {
  return mfma_try(a, b, c, 0);
}

__device__ __forceinline__ void gl_lds16(const void* g, void* l) {
  __builtin_amdgcn_global_load_lds((const __attribute__((address_space(1))) void*)g,
                                   (__attribute__((address_space(3))) void*)l, 16, 0, 0);
}

__device__ __forceinline__ unsigned short f2bf(float f) {
  unsigned u = __float_as_uint(f);
  u += 0x7FFFu + ((u >> 16) & 1);
  return (unsigned short)(u >> 16);
}
__device__ __forceinline__ float bf2f(unsigned short s) {
  return __uint_as_float(((unsigned)s) << 16);
}

// ---------- K1: copy hidden -> out, fused with router scores ----------
__global__ __launch_bounds__(256) void k_copy_scores(const float4* __restrict__ hid,
                                                     float4* __restrict__ dst,
                                                     const float4* __restrict__ rw,
                                                     const float* __restrict__ rb,
                                                     float* __restrict__ scores) {
  int row = blockIdx.x, t = threadIdx.x;
  const float4* hr = hid + (size_t)row * (D_ / 4);
  float4* dr = dst + (size_t)row * (D_ / 4);
  float acc = 0.f;
#pragma unroll
  for (int i = 0; i < 2; i++) {
    float4 v = hr[t + i * 256];
    dr[t + i * 256] = v;
    float4 w = rw[t + i * 256];
    acc += v.x * w.x + v.y * w.y + v.z * w.z + v.w * w.w;
  }
#pragma unroll
  for (int d = 32; d; d >>= 1) acc += __shfl_xor(acc, d);
  __shared__ float red[4];
  if ((t & 63) == 0) red[t >> 6] = acc;
  __syncthreads();
  if (t == 0) scores[row] = red[0] + red[1] + red[2] + red[3] + rb[0];
}

// ---------- K3: exact top-k (bitonic, matches jax.lax.top_k tie-break) ----------
__global__ __launch_bounds__(1024) void k_topk(const float* __restrict__ scores,
                                               int* __restrict__ pos) {
  __shared__ unsigned long long keys[T_];
  __shared__ int sidx[K_];
  int b = blockIdx.x, t = threadIdx.x;
  for (int i = t; i < T_; i += 1024) {
    unsigned u = __float_as_uint(scores[b * T_ + i]);
    u = (u & 0x80000000u) ? ~u : (u | 0x80000000u);
    keys[i] = ((unsigned long long)u << 32) | (unsigned)(~(unsigned)i);
  }
  __syncthreads();
  for (int k = 2; k <= T_; k <<= 1)
    for (int j = k >> 1; j > 0; j >>= 1) {
      for (int i = t; i < T_; i += 1024) {
        int l = i ^ j;
        if (l > i) {
          unsigned long long a = keys[i], c = keys[l];
          bool desc = ((i & k) == 0);
          if (desc ? (a < c) : (a > c)) { keys[i] = c; keys[l] = a; }
        }
      }
      __syncthreads();
    }
  if (t < K_) sidx[t] = (int)(~(unsigned)(keys[t] & 0xFFFFFFFFull));
  __syncthreads();
  for (int k = 2; k <= K_; k <<= 1)
    for (int j = k >> 1; j > 0; j >>= 1) {
      if (t < K_) {
        int i = t, l = i ^ j;
        if (l > i && l < K_) {
          int a = sidx[i], c = sidx[l];
          bool asc = ((i & k) == 0);
          if (asc ? (a > c) : (a < c)) { sidx[i] = c; sidx[l] = a; }
        }
      }
      __syncthreads();
    }
  if (t < K_) pos[b * K_ + t] = sidx[t];
}

// ---------- K4: gather + RMS1 + gate + rope tables ----------
__global__ __launch_bounds__(256) void k_gather(const float* __restrict__ hidden,
    const int* __restrict__ pos, const float* __restrict__ scores,
    const float* __restrict__ ln1w, float* __restrict__ x,
    unsigned short* __restrict__ xn, float* __restrict__ gate,
    float* __restrict__ cosb, float* __restrict__ sinb) {
  int s = blockIdx.x, t = threadIdx.x;
  int b = s >> 9, p = pos[s];
  const float* src = hidden + ((size_t)b * T_ + p) * D_;
  float v[8];
  float ss = 0.f;
#pragma unroll
  for (int i = 0; i < 8; i++) { v[i] = src[t + i * 256]; ss += v[i] * v[i]; }
  __shared__ float red[4];
#pragma unroll
  for (int d = 32; d; d >>= 1) ss += __shfl_xor(ss, d);
  if ((t & 63) == 0) red[t >> 6] = ss;
  __syncthreads();
  ss = red[0] + red[1] + red[2] + red[3];
  float scale = rsqrtf(ss / (float)D_ + 1e-6f);
  float* xd = x + (size_t)s * D_;
  unsigned short* xnd = xn + (size_t)s * D_;
#pragma unroll
  for (int i = 0; i < 8; i++) {
    int c = t + i * 256;
    xd[c] = v[i];
    xnd[c] = f2bf(v[i] * scale * ln1w[c]);
  }
  if (t == 0) gate[s] = 1.f / (1.f + expf(-scores[b * T_ + p]));
  if (t < 64) {
    float invf = powf(10000.0f, -(float)t / 64.0f);
    float f = (float)p * invf;
    cosb[s * 64 + t] = cosf(f);
    sinb[s * 64 + t] = sinf(f);
  }
}

// ---------- K5: transpose + f32->bf16 (weights to Bt layout), ushort4 writes ----------
__global__ __launch_bounds__(256) void k_transpose(const float* __restrict__ src,
                                                   unsigned short* __restrict__ dst,
                                                   int R, int C) {
  __shared__ float tile[32][33];
  int tx = threadIdx.x & 31, ty = threadIdx.x >> 5;
  int c0 = blockIdx.x * 32, r0 = blockIdx.y * 32;
#pragma unroll
  for (int i = 0; i < 4; i++) {
    int r = ty + i * 8;
    tile[r][tx] = src[(size_t)(r0 + r) * C + c0 + tx];
  }
  __syncthreads();
  int drow = threadIdx.x >> 3;
  int dc4 = (threadIdx.x & 7) * 4;
  ushort4 v;
  v.x = f2bf(tile[dc4 + 0][drow]);
  v.y = f2bf(tile[dc4 + 1][drow]);
  v.z = f2bf(tile[dc4 + 2][drow]);
  v.w = f2bf(tile[dc4 + 3][drow]);
  *(ushort4*)&dst[(size_t)(c0 + drow) * R + r0 + dc4] = v;
}

// ======================================================================
// 2-phase GEMM helpers (R6-proven skeleton; 64B rows, SWZ swizzle)
// ======================================================================
#define SWZ(row) ((((row) >> 1) & 3) << 4)

__device__ __forceinline__ void stage16k(const unsigned short* __restrict__ g, int ldK,
                                         int row0, int k0, char* lds, int tid) {
#pragma unroll
  for (int c = 0; c < 2; c++) {
    int off = c * 8192 + tid * 16;
    int row = off >> 6;
    int cb = (off & 63) ^ SWZ(row);
    gl_lds16(g + (size_t)(row0 + row) * ldK + k0 + (cb >> 1), lds + off);
  }
}
__device__ __forceinline__ void stage8k(const unsigned short* __restrict__ g, int ldK,
                                        int row0, int k0, char* lds, int tid) {
  int off = tid * 16;
  int row = off >> 6;
  int cb = (off & 63) ^ SWZ(row);
  gl_lds16(g + (size_t)(row0 + row) * ldK + k0 + (cb >> 1), lds + off);
}
__device__ __forceinline__ void stage64r(const unsigned short* __restrict__ g, int ldK,
                                         int row0, int k0, char* lds, int tid) {
  int off = tid * 16;
  int row = off >> 6;
  int cb = (off & 63) ^ SWZ(row);
  gl_lds16(g + (size_t)(row0 + row) * ldK + k0 + (cb >> 1), lds + off);
}
__device__ __forceinline__ void stage128r(const unsigned short* __restrict__ g, int ldK,
                                          int row0, int k0, char* lds, int tid) {
#pragma unroll
  for (int c = 0; c < 2; c++) {
    int off = c * 4096 + tid * 16;
    int row = off >> 6;
    int cb = (off & 63) ^ SWZ(row);
    gl_lds16(g + (size_t)(row0 + row) * ldK + k0 + (cb >> 1), lds + off);
  }
}
__device__ __forceinline__ s16x8 ldfrag(const char* base, int row, int g) {
  return *(const s16x8*)(base + row * 64 + ((g * 16) ^ SWZ(row)));
}

// ---------- K6: fused QKV GEMM, 256x128 tile, 8 waves (R6 schedule) ----------
__global__ __launch_bounds__(512, 2) void k_gemm_qkv8(const unsigned short* __restrict__ A,
    const unsigned short* __restrict__ Bt, unsigned short* __restrict__ C,
    const float* __restrict__ bq, const float* __restrict__ bk,
    const float* __restrict__ bv) {
  alignas(16) __shared__ short As[2][256 * 32];
  alignas(16) __shared__ short Bs[2][128 * 32];
  int tid = threadIdx.x;
  int lane = tid & 63, g = lane >> 4, lr = lane & 15;
  int wid = tid >> 6, wm = wid >> 1, wn = wid & 1;
  int m0 = blockIdx.x * 256, n0 = blockIdx.y * 128;
  f32x4 zero4 = {0.f, 0.f, 0.f, 0.f};
  f32x4 acc[4][4];
#pragma unroll
  for (int m = 0; m < 4; m++)
#pragma unroll
    for (int n = 0; n < 4; n++) acc[m][n] = zero4;
  const int nkt = D_ / 32;
  stage16k(A, D_, m0, 0, (char*)As[0], tid);
  stage8k(Bt, D_, n0, 0, (char*)Bs[0], tid);
  stage16k(A, D_, m0, 32, (char*)As[1], tid);
  stage8k(Bt, D_, n0, 32, (char*)Bs[1], tid);
  int arow = wm * 64 + lr;
  int brow = wn * 64 + lr;
  for (int t = 0; t < nkt; t++) {
    int b = t & 1;
    const char* Ab = (const char*)As[b];
    const char* Bb = (const char*)Bs[b];
    if (t + 1 < nkt) asm volatile("s_waitcnt vmcnt(3)" ::: "memory");
    else             asm volatile("s_waitcnt vmcnt(0)" ::: "memory");
    __builtin_amdgcn_s_barrier();
    s16x8 af[4], bf4[4];
#pragma unroll
    for (int i = 0; i < 4; i++) af[i] = ldfrag(Ab, arow + i * 16, g);
#pragma unroll
    for (int i = 0; i < 4; i++) bf4[i] = ldfrag(Bb, brow + i * 16, g);
    asm volatile("s_waitcnt lgkmcnt(0)" ::: "memory");
    __builtin_amdgcn_s_barrier();
    if (t + 2 < nkt) {
      stage16k(A, D_, m0, (t + 2) * 32, (char*)As[b], tid);
      stage8k(Bt, D_, n0, (t + 2) * 32, (char*)Bs[b], tid);
    }
    __builtin_amdgcn_s_setprio(1);
#pragma unroll
    for (int m = 0; m < 4; m++)
#pragma unroll
      for (int n = 0; n < 4; n++) acc[m][n] = mfma_bf16(af[m], bf4[n], acc[m][n]);
    __builtin_amdgcn_s_setprio(0);
  }
#pragma unroll
  for (int m = 0; m < 4; m++)
#pragma unroll
    for (int n = 0; n < 4; n++)
#pragma unroll
      for (int r = 0; r < 4; r++) {
        int row = m0 + wm * 64 + m * 16 + (g << 2) + r;
        int col = n0 + wn * 64 + n * 16 + lr;
        float bias = (col < D_) ? bq[col] : ((col < 2 * D_) ? bk[col - D_] : bv[col - 2 * D_]);
        C[(size_t)row * D3_ + col] = f2bf(acc[m][n][r] + bias);
      }
}

// ======================================================================
// K11: fused gate/up GEMM — 8-PHASE schedule (T2+T3+T4+T5, m201 port).
// Tile: 256 M x 128 N(both gate&up). BK=64, 2 K-tiles/iter, 2 buffers.
// Buffer layout (64KB each): A 256x128B @0, Bg 128x128B @32768, Bu @49152.
// 128B rows; swizzle involution byte ^= ((row&7)<<4) (8 slots, 2 lanes/bank).
// 8 phases/iter; 1x 16KB stage unit per phase; counted vmcnt(4) at P1/P4/P5/P8
// (= allow 2 units outstanding); vmcnt(0) at P4 of last iter only.
// Stage FIFO per iter i (t0=2i,t1=2i+1,t2=2i+2,t3=2i+3):
//   P1:t1.A1  P2:t1.Bg  P3:t1.Bu  P4:t2.A0  P5:t2.A1  P6:t2.Bg  P7:t2.Bu  P8:t3.A0
// Ledger verified: each K-tile's 4 units drained before its first read;
// each region's restage is >=1 phase after its last read.
// ======================================================================
__device__ __forceinline__ void stage_u(const unsigned short* __restrict__ g, int ldK,
                                        int grow0, int k0, char* ldsbase, int tid) {
#pragma unroll
  for (int c = 0; c < 2; c++) {
    int off = c * 8192 + tid * 16;       // 16KB unit = 128 rows x 128B
    int row = off >> 7;
    int cb = (off & 127) ^ ((row & 7) << 4);
    gl_lds16(g + (size_t)(grow0 + row) * ldK + k0 + (cb >> 1), ldsbase + off);
  }
}
__device__ __forceinline__ s16x8 ldfrag128(const char* base, int row, int byteoff) {
  return *(const s16x8*)(base + row * 128 + (byteoff ^ ((row & 7) << 4)));
}

#define GUP_MFMA(AF, BB, ACC)                                       \
  __builtin_amdgcn_s_barrier();                                     \
  asm volatile("s_waitcnt lgkmcnt(0)" ::: "memory");                \
  __builtin_amdgcn_sched_barrier(0);                                \
  __builtin_amdgcn_s_setprio(1);                                    \
  _Pragma("unroll") for (int m = 0; m < 4; m++)                     \
    _Pragma("unroll") for (int n = 0; n < 4; n++)                   \
      ACC[m][n] = mfma_bf16(AF[m], BB[n], ACC[m][n]);               \
  __builtin_amdgcn_s_setprio(0);                                    \
  __builtin_amdgcn_s_barrier();

__global__ __launch_bounds__(512, 1) void k_gemm_gup8p(const unsigned short* __restrict__ A,
    const unsigned short* __restrict__ Bg, const unsigned short* __restrict__ Bu,
    unsigned short* __restrict__ act) {
  alignas(16) __shared__ char L[2][65536];
  int tid = threadIdx.x;
  int lane = tid & 63, g = lane >> 4, lr = lane & 15;
  int wid = tid >> 6, wm = wid >> 1, wn = wid & 1;
  int m0 = blockIdx.x * 256, n0 = blockIdx.y * 128;
  f32x4 zero4 = {0.f, 0.f, 0.f, 0.f};
  f32x4 ag[4][4], au[4][4];
#pragma unroll
  for (int m = 0; m < 4; m++)
#pragma unroll
    for (int n = 0; n < 4; n++) { ag[m][n] = zero4; au[m][n] = zero4; }
  int arow = wm * 64 + lr;   // + q*16 -> rows within A region (0..255)
  int brow = wn * 64 + lr;   // + q*16 -> rows within B regions (0..127)
  const int NI = D_ / 128;   // 16 iterations, 2 K-tiles each
  // prologue: t0 all 4 units -> buf0 ; t1.A0 -> buf1
  stage_u(A, D_, m0, 0, &L[0][0], tid);
  stage_u(A, D_, m0 + 128, 0, &L[0][16384], tid);
  stage_u(Bg, D_, n0, 0, &L[0][32768], tid);
  stage_u(Bu, D_, n0, 0, &L[0][49152], tid);
  stage_u(A, D_, m0, 64, &L[1][0], tid);
  asm volatile("s_waitcnt vmcnt(2)" ::: "memory");
  __builtin_amdgcn_s_barrier();
  for (int i = 0; i < NI; i++) {
    const char* B0 = &L[0][0];
    const char* B1 = &L[1][0];
    int k1 = i * 128 + 64;
    int k2 = i * 128 + 128;
    int k3 = i * 128 + 192;
    bool more = (i + 1 < NI);
    s16x8 af0[4], af1[4], bb[4];
    // ---- P1: gate kh0 (buf0); stage t1.A1 ----
#pragma unroll
    for (int q = 0; q < 4; q++) af0[q] = ldfrag128(B0, arow + q * 16, g * 16);
#pragma unroll
    for (int q = 0; q < 4; q++) bb[q] = ldfrag128(B0 + 32768, brow + q * 16, g * 16);
    stage_u(A, D_, m0 + 128, k1, &L[1][16384], tid);
    asm volatile("s_waitcnt vmcnt(4)" ::: "memory");
    GUP_MFMA(af0, bb, ag);
    // ---- P2: up kh0 (buf0); stage t1.Bg ----
#pragma unroll
    for (int q = 0; q < 4; q++) bb[q] = ldfrag128(B0 + 49152, brow + q * 16, g * 16);
    stage_u(Bg, D_, n0, k1, &L[1][32768], tid);
    GUP_MFMA(af0, bb, au);
    // ---- P3: gate kh1 (buf0); stage t1.Bu ----
#pragma unroll
    for (int q = 0; q < 4; q++) af1[q] = ldfrag128(B0, arow + q * 16, 64 + g * 16);
#pragma unroll
    for (int q = 0; q < 4; q++) bb[q] = ldfrag128(B0 + 32768, brow + q * 16, 64 + g * 16);
    stage_u(Bu, D_, n0, k1, &L[1][49152], tid);
    GUP_MFMA(af1, bb, ag);
    // ---- P4: up kh1 (buf0); stage t2.A0 ----
#pragma unroll
    for (int q = 0; q < 4; q++) bb[q] = ldfrag128(B0 + 49152, brow + q * 16, 64 + g * 16);
    if (more) {
      stage_u(A, D_, m0, k2, &L[0][0], tid);
      asm volatile("s_waitcnt vmcnt(4)" ::: "memory");
    } else {
      asm volatile("s_waitcnt vmcnt(0)" ::: "memory");
    }
    GUP_MFMA(af1, bb, au);
    // ---- P5: gate kh0 (buf1); stage t2.A1 ----
#pragma unroll
    for (int q = 0; q < 4; q++) af0[q] = ldfrag128(B1, arow + q * 16, g * 16);
#pragma unroll
    for (int q = 0; q < 4; q++) bb[q] = ldfrag128(B1 + 32768, brow + q * 16, g * 16);
    if (more) stage_u(A, D_, m0 + 128, k2, &L[0][16384], tid);
    asm volatile("s_waitcnt vmcnt(4)" ::: "memory");
    GUP_MFMA(af0, bb, ag);
    // ---- P6: up kh0 (buf1); stage t2.Bg ----
#pragma unroll
    for (int q = 0; q < 4; q++) bb[q] = ldfrag128(B1 + 49152, brow + q * 16, g * 16);
    if (more) stage_u(Bg, D_, n0, k2, &L[0][32768], tid);
    GUP_MFMA(af0, bb, au);
    // ---- P7: gate kh1 (buf1); stage t2.Bu ----
#pragma unroll
    for (int q = 0; q < 4; q++) af1[q] = ldfrag128(B1, arow + q * 16, 64 + g * 16);
#pragma unroll
    for (int q = 0; q < 4; q++) bb[q] = ldfrag128(B1 + 32768, brow + q * 16, 64 + g * 16);
    if (more) stage_u(Bu, D_, n0, k2, &L[0][49152], tid);
    GUP_MFMA(af1, bb, ag);
    // ---- P8: up kh1 (buf1); stage t3.A0 ----
#pragma unroll
    for (int q = 0; q < 4; q++) bb[q] = ldfrag128(B1 + 49152, brow + q * 16, 64 + g * 16);
    if (more) stage_u(A, D_, m0, k3, &L[1][0], tid);
    asm volatile("s_waitcnt vmcnt(4)" ::: "memory");
    GUP_MFMA(af1, bb, au);
  }
#pragma unroll
  for (int m = 0; m < 4; m++)
#pragma unroll
    for (int n = 0; n < 4; n++)
#pragma unroll
      for (int r = 0; r < 4; r++) {
        int row = m0 + wm * 64 + m * 16 + (g << 2) + r;
        int col = n0 + wn * 64 + n * 16 + lr;
        float gv = ag[m][n][r], uv = au[m][n][r];
        float si = gv / (1.f + __expf(-gv));
        act[(size_t)row * I_ + col] = f2bf(si * uv);
      }
}

// ---------- K9: wo GEMM + residual, 64x128 tile, 4 waves (R6 schedule) ----------
__global__ __launch_bounds__(256, 2) void k_gemm_wo64(const unsigned short* __restrict__ A,
    const unsigned short* __restrict__ Bt, const float* __restrict__ xres,
    float* __restrict__ x1) {
  alignas(16) __shared__ short As[2][64 * 32];
  alignas(16) __shared__ short Bs[2][128 * 32];
  int tid = threadIdx.x;
  int lane = tid & 63, g = lane >> 4, lr = lane & 15, wid = tid >> 6;
  int m0 = blockIdx.x * 64, n0 = blockIdx.y * 128;
  f32x4 zero4 = {0.f, 0.f, 0.f, 0.f};
  f32x4 acc[4][2];
#pragma unroll
  for (int m = 0; m < 4; m++)
#pragma unroll
    for (int n = 0; n < 2; n++) acc[m][n] = zero4;
  const int nkt = D_ / 32;
  stage64r(A, D_, m0, 0, (char*)As[0], tid);
  stage128r(Bt, D_, n0, 0, (char*)Bs[0], tid);
  stage64r(A, D_, m0, 32, (char*)As[1], tid);
  stage128r(Bt, D_, n0, 32, (char*)Bs[1], tid);
  for (int t = 0; t < nkt; t++) {
    int b = t & 1;
    const char* Ab = (const char*)As[b];
    const char* Bb = (const char*)Bs[b];
    if (t + 1 < nkt) asm volatile("s_waitcnt vmcnt(3)" ::: "memory");
    else             asm volatile("s_waitcnt vmcnt(0)" ::: "memory");
    __builtin_amdgcn_s_barrier();
    s16x8 af[4], bf2[2];
#pragma unroll
    for (int i = 0; i < 4; i++) af[i] = ldfrag(Ab, i * 16 + lr, g);
#pragma unroll
    for (int j = 0; j < 2; j++) bf2[j] = ldfrag(Bb, wid * 32 + j * 16 + lr, g);
    asm volatile("s_waitcnt lgkmcnt(0)" ::: "memory");
    __builtin_amdgcn_s_barrier();
    if (t + 2 < nkt) {
      stage64r(A, D_, m0, (t + 2) * 32, (char*)As[b], tid);
      stage128r(Bt, D_, n0, (t + 2) * 32, (char*)Bs[b], tid);
    }
    __builtin_amdgcn_s_setprio(1);
#pragma unroll
    for (int m = 0; m < 4; m++)
#pragma unroll
      for (int n = 0; n < 2; n++) acc[m][n] = mfma_bf16(af[m], bf2[n], acc[m][n]);
    __builtin_amdgcn_s_setprio(0);
  }
#pragma unroll
  for (int m = 0; m < 4; m++)
#pragma unroll
    for (int n = 0; n < 2; n++)
#pragma unroll
      for (int r = 0; r < 4; r++) {
        int row = m0 + m * 16 + (g << 2) + r;
        int col = n0 + wid * 32 + n * 16 + lr;
        x1[(size_t)row * D_ + col] = acc[m][n][r] + xres[(size_t)row * D_ + col];
      }
}

// ---------- K12: down GEMM + residual + blend + scatter, 64x128 (R6) ----------
__global__ __launch_bounds__(256, 2) void k_gemm_down64(const unsigned short* __restrict__ A,
    const unsigned short* __restrict__ Bt, const float* __restrict__ x1,
    const float* __restrict__ x, const float* __restrict__ gate,
    const int* __restrict__ pos, float* __restrict__ out) {
  alignas(16) __shared__ short As[2][64 * 32];
  alignas(16) __shared__ short Bs[2][128 * 32];
  int tid = threadIdx.x;
  int lane = tid & 63, g = lane >> 4, lr = lane & 15, wid = tid >> 6;
  int m0 = blockIdx.x * 64, n0 = blockIdx.y * 128;
  f32x4 zero4 = {0.f, 0.f, 0.f, 0.f};
  f32x4 acc[4][2];
#pragma unroll
  for (int m = 0; m < 4; m++)
#pragma unroll
    for (int n = 0; n < 2; n++) acc[m][n] = zero4;
  const int nkt = I_ / 32;
  stage64r(A, I_, m0, 0, (char*)As[0], tid);
  stage128r(Bt, I_, n0, 0, (char*)Bs[0], tid);
  stage64r(A, I_, m0, 32, (char*)As[1], tid);
  stage128r(Bt, I_, n0, 32, (char*)Bs[1], tid);
  for (int t = 0; t < nkt; t++) {
    int b = t & 1;
    const char* Ab = (const char*)As[b];
    const char* Bb = (const char*)Bs[b];
    if (t + 1 < nkt) asm volatile("s_waitcnt vmcnt(3)" ::: "memory");
    else             asm volatile("s_waitcnt vmcnt(0)" ::: "memory");
    __builtin_amdgcn_s_barrier();
    s16x8 af[4], bf2[2];
#pragma unroll
    for (int i = 0; i < 4; i++) af[i] = ldfrag(Ab, i * 16 + lr, g);
#pragma unroll
    for (int j = 0; j < 2; j++) bf2[j] = ldfrag(Bb, wid * 32 + j * 16 + lr, g);
    asm volatile("s_waitcnt lgkmcnt(0)" ::: "memory");
    __builtin_amdgcn_s_barrier();
    if (t + 2 < nkt) {
      stage64r(A, I_, m0, (t + 2) * 32, (char*)As[b], tid);
      stage128r(Bt, I_, n0, (t + 2) * 32, (char*)Bs[b], tid);
    }
    __builtin_amdgcn_s_setprio(1);
#pragma unroll
    for (int m = 0; m < 4; m++)
#pragma unroll
      for (int n = 0; n < 2; n++) acc[m][n] = mfma_bf16(af[m], bf2[n], acc[m][n]);
    __builtin_amdgcn_s_setprio(0);
  }
#pragma unroll
  for (int m = 0; m < 4; m++)
#pragma unroll
    for (int n = 0; n < 2; n++)
#pragma unroll
      for (int r = 0; r < 4; r++) {
        int srow = m0 + m * 16 + (g << 2) + r;
        int col = n0 + wid * 32 + n * 16 + lr;
        float proc = acc[m][n][r] + x1[(size_t)srow * D_ + col];
        float gt = gate[srow];
        float xv = x[(size_t)srow * D_ + col];
        int bb = srow >> 9;
        int p = pos[srow];
        out[((size_t)bb * T_ + p) * D_ + col] = gt * proc + (1.f - gt) * xv;
      }
}

// ---------- K7: RoPE + head relayout (q,k row-major per head; v transposed) ----------
__global__ __launch_bounds__(256) void k_rope(const unsigned short* __restrict__ qkv,
    const float* __restrict__ cosb, const float* __restrict__ sinb,
    unsigned short* __restrict__ qh, unsigned short* __restrict__ kh,
    unsigned short* __restrict__ vT) {
  int s0 = blockIdx.x * 64;
  int h = blockIdx.y;
  int t = threadIdx.x;
#pragma unroll
  for (int i = 0; i < 16; i++) {
    int flat = t + i * 256;
    int r = flat >> 6, dp = flat & 63;
    int s = s0 + r;
    float c = cosb[s * 64 + dp], sn = sinb[s * 64 + dp];
    const unsigned short* qrow = qkv + (size_t)s * D3_ + h * HD_;
    float q1 = bf2f(qrow[dp]), q2 = bf2f(qrow[dp + 64]);
    unsigned short* qdst = qh + ((size_t)h * S_ + s) * HD_;
    qdst[dp] = f2bf(q1 * c - q2 * sn);
    qdst[dp + 64] = f2bf(q2 * c + q1 * sn);
    const unsigned short* krow = qrow + D_;
    float k1 = bf2f(krow[dp]), k2 = bf2f(krow[dp + 64]);
    unsigned short* kdst = kh + ((size_t)h * S_ + s) * HD_;
    kdst[dp] = f2bf(k1 * c - k2 * sn);
    kdst[dp + 64] = f2bf(k2 * c + k1 * sn);
  }
  __shared__ unsigned short vt[128][66];
#pragma unroll
  for (int i = 0; i < 32; i++) {
    int flat = t + i * 256;
    int r = flat >> 7, d = flat & 127;
    vt[d][r] = qkv[(size_t)(s0 + r) * D3_ + 2 * D_ + h * HD_ + d];
  }
  __syncthreads();
#pragma unroll
  for (int i = 0; i < 32; i++) {
    int flat = t + i * 256;
    int d = flat >> 6, sc = flat & 63;
    vT[((size_t)h * HD_ + d) * S_ + s0 + sc] = vt[d][sc];
  }
}

// ======================================================================
// K8: flash attention (q-tile 64, LPT order, swizzled LDS, dbuf KV)
// ======================================================================
__device__ __forceinline__ void stage_kv(const unsigned short* __restrict__ kh,
                                         const unsigned short* __restrict__ vT,
                                         size_t hbase, int kt, char* KsB, char* VsB, int tid) {
#pragma unroll
  for (int c = 0; c < 4; c++) {
    int off = c * 4096 + tid * 16;
    int row = off >> 8;
    int cb = (off & 255) ^ ((row & 7) << 4);
    gl_lds16(kh + hbase + (size_t)(kt * 64 + row) * HD_ + (cb >> 1), KsB + off);
  }
#pragma unroll
  for (int c = 0; c < 4; c++) {
    int off = c * 4096 + tid * 16;
    int row = off >> 7;
    int cb = (off & 127) ^ ((row & 7) << 4);
    gl_lds16(vT + hbase + (size_t)row * S_ + kt * 64 + (cb >> 1), VsB + off);
  }
}

__global__ __launch_bounds__(256, 2) void k_attn(const unsigned short* __restrict__ qh,
                                                 const unsigned short* __restrict__ kh,
                                                 const unsigned short* __restrict__ vT,
                                                 unsigned short* __restrict__ ao) {
  alignas(16) __shared__ short Ks[2][64 * 128];
  alignas(16) __shared__ short Vs[2][128 * 64];
  alignas(16) __shared__ short Ps[4][16 * 64];
  int bidx = blockIdx.x;
  int head = bidx & 15;
  int slot = bidx >> 4;
  int qt = (slot < 16) ? (31 - slot) : (slot - 16);
  int q0 = qt * 64;
  int tid = threadIdx.x, w = tid >> 6, lane = tid & 63, g = lane >> 4, lr = lane & 15;
  size_t hbase = (size_t)head * S_ * HD_;
  int qw = q0 + w * 16;
  char* PsW = (char*)&Ps[w][0];
  s16x8 qf[4];
#pragma unroll
  for (int ks = 0; ks < 4; ks++)
    qf[ks] = *(const s16x8*)&qh[hbase + (size_t)(qw + lr) * HD_ + ks * 32 + g * 8];
  f32x4 o[8];
  f32x4 zero4 = {0.f, 0.f, 0.f, 0.f};
#pragma unroll
  for (int nf = 0; nf < 8; nf++) o[nf] = zero4;
  float m_i[4], l_i[4];
#pragma unroll
  for (int r = 0; r < 4; r++) { m_i[r] = -1e30f; l_i[r] = 0.f; }
  const float sc = 0.08838834764831843f;

  stage_kv(kh, vT, hbase, 0, (char*)Ks[0], (char*)Vs[0], tid);
  if (qt > 0) stage_kv(kh, vT, hbase, 1, (char*)Ks[1], (char*)Vs[1], tid);

  for (int kt = 0; kt <= qt; kt++) {
    int b = kt & 1;
    const char* KsB = (const char*)Ks[b];
    const char* VsB = (const char*)Vs[b];
    if (kt < qt) asm volatile("s_waitcnt vmcnt(8)" ::: "memory");
    else         asm volatile("s_waitcnt vmcnt(0)" ::: "memory");
    __builtin_amdgcn_s_barrier();
    f32x4 sacc[4];
#pragma unroll
    for (int nf = 0; nf < 4; nf++) sacc[nf] = zero4;
#pragma unroll
    for (int ks = 0; ks < 4; ks++) {
      s16x8 kf[4];
#pragma unroll
      for (int nf = 0; nf < 4; nf++) {
        int row = nf * 16 + lr;
        kf[nf] = *(const s16x8*)(KsB + row * 256 + (((ks << 6) + (g << 4)) ^ ((row & 7) << 4)));
      }
#pragma unroll
      for (int nf = 0; nf < 4; nf++) sacc[nf] = mfma_bf16(qf[ks], kf[nf], sacc[nf]);
    }
    bool diag = (kt == qt);
#pragma unroll
    for (int r = 0; r < 4; r++) {
      int prow = (g << 2) + r;
      int qrow = qw + prow;
      float pv[4];
      float mx = -1e30f;
#pragma unroll
      for (int nf = 0; nf < 4; nf++) {
        float vv = sacc[nf][r] * sc;
        if (diag) {
          int kc = kt * 64 + nf * 16 + lr;
          vv = (kc <= qrow) ? vv : -1e30f;
        }
        pv[nf] = vv;
        mx = fmaxf(mx, vv);
      }
#pragma unroll
      for (int d = 1; d < 16; d <<= 1) mx = fmaxf(mx, __shfl_xor(mx, d));
      float mold = m_i[r], mnew = fmaxf(mold, mx);
      float corr = __expf(mold - mnew);
      float ssum = 0.f;
#pragma unroll
      for (int nf = 0; nf < 4; nf++) {
        float pe = __expf(pv[nf] - mnew);
        int cb = ((nf * 16 + lr) << 1) ^ ((prow & 7) << 4);
        *(unsigned short*)(PsW + prow * 128 + cb) = f2bf(pe);
        ssum += pe;
      }
#pragma unroll
      for (int d = 1; d < 16; d <<= 1) ssum += __shfl_xor(ssum, d);
      l_i[r] = l_i[r] * corr + ssum;
      m_i[r] = mnew;
#pragma unroll
      for (int nf = 0; nf < 8; nf++) o[nf][r] *= corr;
    }
    s16x8 pa[2];
#pragma unroll
    for (int ks = 0; ks < 2; ks++)
      pa[ks] = *(const s16x8*)(PsW + lr * 128 + (((ks << 6) + (g << 4)) ^ ((lr & 7) << 4)));
#pragma unroll
    for (int nf = 0; nf < 8; nf++) {
#pragma unroll
      for (int ks = 0; ks < 2; ks++) {
        int row = nf * 16 + lr;
        s16x8 vb = *(const s16x8*)(VsB + row * 128 + (((ks << 6) + (g << 4)) ^ ((row & 7) << 4)));
        o[nf] = mfma_bf16(pa[ks], vb, o[nf]);
      }
    }
    asm volatile("s_waitcnt lgkmcnt(0)" ::: "memory");
    __builtin_amdgcn_s_barrier();
    if (kt + 2 <= qt)
      stage_kv(kh, vT, hbase, kt + 2, (char*)Ks[b], (char*)Vs[b], tid);
  }
#pragma unroll
  for (int nf = 0; nf < 8; nf++)
#pragma unroll
    for (int r = 0; r < 4; r++) {
      int row = qw + (g << 2) + r;
      int col = head * HD_ + nf * 16 + lr;
      ao[(size_t)row * D_ + col] = f2bf(o[nf][r] / l_i[r]);
    }
}

// ---------- K10: RMS2 ----------
__global__ __launch_bounds__(256) void k_rms2(const float* __restrict__ x1,
                                              const float* __restrict__ ln2w,
                                              unsigned short* __restrict__ xn2) {
  int s = blockIdx.x, t = threadIdx.x;
  const float* src = x1 + (size_t)s * D_;
  float v[8];
  float ss = 0.f;
#pragma unroll
  for (int i = 0; i < 8; i++) { v[i] = src[t + i * 256]; ss += v[i] * v[i]; }
  __shared__ float red[4];
#pragma unroll
  for (int d = 32; d; d >>= 1) ss += __shfl_xor(ss, d);
  if ((t & 63) == 0) red[t >> 6] = ss;
  __syncthreads();
  ss = red[0] + red[1] + red[2] + red[3];
  float scale = rsqrtf(ss / (float)D_ + 1e-6f);
  unsigned short* dst = xn2 + (size_t)s * D_;
#pragma unroll
  for (int i = 0; i < 8; i++) {
    int c = t + i * 256;
    dst[c] = f2bf(v[i] * scale * ln2w[c]);
  }
}

extern "C" void kernel_launch(void* const* d_in, const int* in_sizes, int n_in,
                              void* d_out, int out_size, void* d_ws, size_t ws_size,
                              hipStream_t stream) {
  (void)in_sizes; (void)n_in; (void)out_size; (void)ws_size;
  const float* hidden = (const float*)d_in[0];
  const float* router_w = (const float*)d_in[1];
  const float* router_b = (const float*)d_in[2];
  const float* ln1w = (const float*)d_in[3];
  const float* ln2w = (const float*)d_in[4];
  const float* wq = (const float*)d_in[5];
  const float* bq = (const float*)d_in[6];
  const float* wk = (const float*)d_in[7];
  const float* bk = (const float*)d_in[8];
  const float* wv = (const float*)d_in[9];
  const float* bv = (const float*)d_in[10];
  const float* wo = (const float*)d_in[11];
  const float* wg = (const float*)d_in[12];
  const float* wu = (const float*)d_in[13];
  const float* wd = (const float*)d_in[14];
  float* out = (float*)d_out;

  char* ws = (char*)d_ws;
  size_t off = 0;
  auto alloc = [&](size_t bytes) {
    char* p = ws + off;
    off += (bytes + 255) & ~(size_t)255;
    return p;
  };
  unsigned short* wqkvT = (unsigned short*)alloc(3ull * D_ * D_ * 2);
  unsigned short* woT = (unsigned short*)alloc((size_t)D_ * D_ * 2);
  unsigned short* wgT = (unsigned short*)alloc((size_t)I_ * D_ * 2);
  unsigned short* wuT = (unsigned short*)alloc((size_t)I_ * D_ * 2);
  unsigned short* wdT = (unsigned short*)alloc((size_t)D_ * I_ * 2);
  float* scores = (float*)alloc((size_t)B_ * T_ * 4);
  int* pos = (int*)alloc((size_t)S_ * 4);
  float* gate = (float*)alloc((size_t)S_ * 4);
  float* x = (float*)alloc((size_t)S_ * D_ * 4);
  float* x1 = (float*)alloc((size_t)S_ * D_ * 4);
  unsigned short* xn = (unsigned short*)alloc((size_t)S_ * D_ * 2);  // reused as x1n
  float* cosb = (float*)alloc((size_t)S_ * 64 * 4);
  float* sinb = (float*)alloc((size_t)S_ * 64 * 4);
  unsigned short* qkv = (unsigned short*)alloc((size_t)S_ * D3_ * 2);  // reused as act
  unsigned short* qh = (unsigned short*)alloc((size_t)H_ * S_ * HD_ * 2);
  unsigned short* kh = (unsigned short*)alloc((size_t)H_ * S_ * HD_ * 2);
  unsigned short* vT = (unsigned short*)alloc((size_t)H_ * S_ * HD_ * 2);
  unsigned short* ao = (unsigned short*)alloc((size_t)S_ * D_ * 2);

  k_copy_scores<<<B_ * T_, 256, 0, stream>>>((const float4*)hidden, (float4*)out,
                                             (const float4*)router_w, router_b, scores);

  k_transpose<<<dim3(D_ / 32, D_ / 32), 256, 0, stream>>>(wq, wqkvT, D_, D_);
  k_transpose<<<dim3(D_ / 32, D_ / 32), 256, 0, stream>>>(wk, wqkvT + (size_t)D_ * D_, D_, D_);
  k_transpose<<<dim3(D_ / 32, D_ / 32), 256, 0, stream>>>(wv, wqkvT + 2ull * D_ * D_, D_, D_);
  k_transpose<<<dim3(D_ / 32, D_ / 32), 256, 0, stream>>>(wo, woT, D_, D_);
  k_transpose<<<dim3(I_ / 32, D_ / 32), 256, 0, stream>>>(wg, wgT, D_, I_);
  k_transpose<<<dim3(I_ / 32, D_ / 32), 256, 0, stream>>>(wu, wuT, D_, I_);
  k_transpose<<<dim3(D_ / 32, I_ / 32), 256, 0, stream>>>(wd, wdT, I_, D_);

  k_topk<<<B_, 1024, 0, stream>>>(scores, pos);
  k_gather<<<S_, 256, 0, stream>>>(hidden, pos, scores, ln1w, x, xn, gate, cosb, sinb);

  k_gemm_qkv8<<<dim3(S_ / 256, D3_ / 128), 512, 0, stream>>>(xn, wqkvT, qkv, bq, bk, bv);
  k_rope<<<dim3(S_ / 64, H_), 256, 0, stream>>>(qkv, cosb, sinb, qh, kh, vT);
  k_attn<<<32 * H_, 256, 0, stream>>>(qh, kh, vT, ao);
  k_gemm_wo64<<<dim3(S_ / 64, D_ / 128), 256, 0, stream>>>(ao, woT, x, x1);
  k_rms2<<<S_, 256, 0, stream>>>(x1, ln2w, xn);
  k_gemm_gup8p<<<dim3(S_ / 256, I_ / 128), 512, 0, stream>>>(xn, wgT, wuT, qkv);
  k_gemm_down64<<<dim3(S_ / 64, D_ / 128), 256, 0, stream>>>(qkv, wdT, x1, x, gate, pos, out);
}

// Round 11
// 523.478 us; speedup vs baseline: 1.1824x; 1.0268x over previous
//
#include <hip/hip_runtime.h>
#include <stdint.h>

#define B_ 4
#define T_ 2048
#define D_ 2048
#define H_ 16
#define HD_ 128
#define I_ 5632
#define K_ 512
#define S_ 2048
#define D3_ (3 * D_)

typedef float f32x4 __attribute__((ext_vector_type(4)));
typedef short s16x8 __attribute__((ext_vector_type(8)));
typedef __bf16 bf16x8 __attribute__((ext_vector_type(8)));

// ---------- mfma wrapper robust to builtin operand type (short8 vs bf16x8) ----------
template <typename V>
__device__ __forceinline__ auto mfma_try(V a, V b, f32x4 c, int)
    -> decltype(__builtin_amdgcn_mfma_f32_16x16x32_bf16(a, b, c, 0, 0, 0)) {
  return __builtin_amdgcn_mfma_f32_16x16x32_bf16(a, b, c, 0, 0, 0);
}
template <typename V>
__device__ __forceinline__ f32x4 mfma_try(V a, V b, f32x4 c, long) {
  return __builtin_amdgcn_mfma_f32_16x16x32_bf16(
      __builtin_bit_cast(bf16x8, a), __builtin_bit_cast(bf16x8, b), c, 0, 0, 0);
}
__device__ __forceinline__ f32x4 mfma_bf16(s16x8 a, s16x8 b, f32x4 c) {
  return mfma_try(a, b, c, 0);
}

__device__ __forceinline__ void gl_lds16(const void* g, void* l) {
  __builtin_amdgcn_global_load_lds((const __attribute__((address_space(1))) void*)g,
                                   (__attribute__((address_space(3))) void*)l, 16, 0, 0);
}

__device__ __forceinline__ unsigned short f2bf(float f) {
  unsigned u = __float_as_uint(f);
  u += 0x7FFFu + ((u >> 16) & 1);
  return (unsigned short)(u >> 16);
}
__device__ __forceinline__ float bf2f(unsigned short s) {
  return __uint_as_float(((unsigned)s) << 16);
}

// ---------- K1: copy hidden -> out, fused with router scores ----------
__global__ __launch_bounds__(256) void k_copy_scores(const float4* __restrict__ hid,
                                                     float4* __restrict__ dst,
                                                     const float4* __restrict__ rw,
                                                     const float* __restrict__ rb,
                                                     float* __restrict__ scores) {
  int row = blockIdx.x, t = threadIdx.x;
  const float4* hr = hid + (size_t)row * (D_ / 4);
  float4* dr = dst + (size_t)row * (D_ / 4);
  float acc = 0.f;
#pragma unroll
  for (int i = 0; i < 2; i++) {
    float4 v = hr[t + i * 256];
    dr[t + i * 256] = v;
    float4 w = rw[t + i * 256];
    acc += v.x * w.x + v.y * w.y + v.z * w.z + v.w * w.w;
  }
#pragma unroll
  for (int d = 32; d; d >>= 1) acc += __shfl_xor(acc, d);
  __shared__ float red[4];
  if ((t & 63) == 0) red[t >> 6] = acc;
  __syncthreads();
  if (t == 0) scores[row] = red[0] + red[1] + red[2] + red[3] + rb[0];
}

// ---------- K3: exact top-k (bitonic, matches jax.lax.top_k tie-break) ----------
__global__ __launch_bounds__(1024) void k_topk(const float* __restrict__ scores,
                                               int* __restrict__ pos) {
  __shared__ unsigned long long keys[T_];
  __shared__ int sidx[K_];
  int b = blockIdx.x, t = threadIdx.x;
  for (int i = t; i < T_; i += 1024) {
    unsigned u = __float_as_uint(scores[b * T_ + i]);
    u = (u & 0x80000000u) ? ~u : (u | 0x80000000u);
    keys[i] = ((unsigned long long)u << 32) | (unsigned)(~(unsigned)i);
  }
  __syncthreads();
  for (int k = 2; k <= T_; k <<= 1)
    for (int j = k >> 1; j > 0; j >>= 1) {
      for (int i = t; i < T_; i += 1024) {
        int l = i ^ j;
        if (l > i) {
          unsigned long long a = keys[i], c = keys[l];
          bool desc = ((i & k) == 0);
          if (desc ? (a < c) : (a > c)) { keys[i] = c; keys[l] = a; }
        }
      }
      __syncthreads();
    }
  if (t < K_) sidx[t] = (int)(~(unsigned)(keys[t] & 0xFFFFFFFFull));
  __syncthreads();
  for (int k = 2; k <= K_; k <<= 1)
    for (int j = k >> 1; j > 0; j >>= 1) {
      if (t < K_) {
        int i = t, l = i ^ j;
        if (l > i && l < K_) {
          int a = sidx[i], c = sidx[l];
          bool asc = ((i & k) == 0);
          if (asc ? (a > c) : (a < c)) { sidx[i] = c; sidx[l] = a; }
        }
      }
      __syncthreads();
    }
  if (t < K_) pos[b * K_ + t] = sidx[t];
}

// ---------- K4: gather + RMS1 + gate + rope tables ----------
__global__ __launch_bounds__(256) void k_gather(const float* __restrict__ hidden,
    const int* __restrict__ pos, const float* __restrict__ scores,
    const float* __restrict__ ln1w, float* __restrict__ x,
    unsigned short* __restrict__ xn, float* __restrict__ gate,
    float* __restrict__ cosb, float* __restrict__ sinb) {
  int s = blockIdx.x, t = threadIdx.x;
  int b = s >> 9, p = pos[s];
  const float* src = hidden + ((size_t)b * T_ + p) * D_;
  float v[8];
  float ss = 0.f;
#pragma unroll
  for (int i = 0; i < 8; i++) { v[i] = src[t + i * 256]; ss += v[i] * v[i]; }
  __shared__ float red[4];
#pragma unroll
  for (int d = 32; d; d >>= 1) ss += __shfl_xor(ss, d);
  if ((t & 63) == 0) red[t >> 6] = ss;
  __syncthreads();
  ss = red[0] + red[1] + red[2] + red[3];
  float scale = rsqrtf(ss / (float)D_ + 1e-6f);
  float* xd = x + (size_t)s * D_;
  unsigned short* xnd = xn + (size_t)s * D_;
#pragma unroll
  for (int i = 0; i < 8; i++) {
    int c = t + i * 256;
    xd[c] = v[i];
    xnd[c] = f2bf(v[i] * scale * ln1w[c]);
  }
  if (t == 0) gate[s] = 1.f / (1.f + expf(-scores[b * T_ + p]));
  if (t < 64) {
    float invf = powf(10000.0f, -(float)t / 64.0f);
    float f = (float)p * invf;
    cosb[s * 64 + t] = cosf(f);
    sinb[s * 64 + t] = sinf(f);
  }
}

// ---------- K5: transpose + f32->bf16, batched via z (ushort4 writes) ----------
__device__ __forceinline__ void transpose_body(const float* __restrict__ src,
                                               unsigned short* __restrict__ dst,
                                               int R, int C) {
  __shared__ float tile[32][33];
  int tx = threadIdx.x & 31, ty = threadIdx.x >> 5;
  int c0 = blockIdx.x * 32, r0 = blockIdx.y * 32;
#pragma unroll
  for (int i = 0; i < 4; i++) {
    int r = ty + i * 8;
    tile[r][tx] = src[(size_t)(r0 + r) * C + c0 + tx];
  }
  __syncthreads();
  int drow = threadIdx.x >> 3;
  int dc4 = (threadIdx.x & 7) * 4;
  ushort4 v;
  v.x = f2bf(tile[dc4 + 0][drow]);
  v.y = f2bf(tile[dc4 + 1][drow]);
  v.z = f2bf(tile[dc4 + 2][drow]);
  v.w = f2bf(tile[dc4 + 3][drow]);
  *(ushort4*)&dst[(size_t)(c0 + drow) * R + r0 + dc4] = v;
}
__global__ __launch_bounds__(256) void k_transpose(const float* __restrict__ src,
                                                   unsigned short* __restrict__ dst,
                                                   int R, int C) {
  transpose_body(src, dst, R, C);
}
__global__ __launch_bounds__(256) void k_transpose4(const float* s0, const float* s1,
                                                    const float* s2, const float* s3,
                                                    unsigned short* d0, unsigned short* d1,
                                                    unsigned short* d2, unsigned short* d3,
                                                    int R, int C) {
  int z = blockIdx.z;
  const float* src = (z == 0) ? s0 : (z == 1) ? s1 : (z == 2) ? s2 : s3;
  unsigned short* dst = (z == 0) ? d0 : (z == 1) ? d1 : (z == 2) ? d2 : d3;
  transpose_body(src, dst, R, C);
}
__global__ __launch_bounds__(256) void k_transpose2(const float* s0, const float* s1,
                                                    unsigned short* d0, unsigned short* d1,
                                                    int R, int C) {
  int z = blockIdx.z;
  transpose_body(z ? s1 : s0, z ? d1 : d0, R, C);
}

// ======================================================================
// 2-phase GEMM helpers (R6-proven skeleton; 64B rows, SWZ swizzle)
// ======================================================================
#define SWZ(row) ((((row) >> 1) & 3) << 4)

__device__ __forceinline__ void stage64r(const unsigned short* __restrict__ g, int ldK,
                                         int row0, int k0, char* lds, int tid) {
  int off = tid * 16;
  int row = off >> 6;
  int cb = (off & 63) ^ SWZ(row);
  gl_lds16(g + (size_t)(row0 + row) * ldK + k0 + (cb >> 1), lds + off);
}
__device__ __forceinline__ void stage128r(const unsigned short* __restrict__ g, int ldK,
                                          int row0, int k0, char* lds, int tid) {
#pragma unroll
  for (int c = 0; c < 2; c++) {
    int off = c * 4096 + tid * 16;
    int row = off >> 6;
    int cb = (off & 63) ^ SWZ(row);
    gl_lds16(g + (size_t)(row0 + row) * ldK + k0 + (cb >> 1), lds + off);
  }
}
__device__ __forceinline__ s16x8 ldfrag(const char* base, int row, int g) {
  return *(const s16x8*)(base + row * 64 + ((g * 16) ^ SWZ(row)));
}

// ======================================================================
// 8-phase GEMM pieces (proven in R10's gup8p): 128B rows, unit = 16KB,
// swizzle involution byte ^= ((row&7)<<4), applied global-side + read.
// ======================================================================
__device__ __forceinline__ void stage_u(const unsigned short* __restrict__ g, int ldK,
                                        int grow0, int k0, char* ldsbase, int tid) {
#pragma unroll
  for (int c = 0; c < 2; c++) {
    int off = c * 8192 + tid * 16;       // 16KB unit = 128 rows x 128B
    int row = off >> 7;
    int cb = (off & 127) ^ ((row & 7) << 4);
    gl_lds16(g + (size_t)(grow0 + row) * ldK + k0 + (cb >> 1), ldsbase + off);
  }
}
__device__ __forceinline__ s16x8 ldfrag128(const char* base, int row, int byteoff) {
  return *(const s16x8*)(base + row * 128 + (byteoff ^ ((row & 7) << 4)));
}

#define PHASE_MFMA(AF, BB, ACC)                                     \
  __builtin_amdgcn_s_barrier();                                     \
  asm volatile("s_waitcnt lgkmcnt(0)" ::: "memory");                \
  __builtin_amdgcn_sched_barrier(0);                                \
  __builtin_amdgcn_s_setprio(1);                                    \
  _Pragma("unroll") for (int m = 0; m < 4; m++)                     \
    _Pragma("unroll") for (int n = 0; n < 4; n++)                   \
      ACC[m][n] = mfma_bf16(AF[m], BB[n], ACC[m][n]);               \
  __builtin_amdgcn_s_setprio(0);                                    \
  __builtin_amdgcn_s_barrier();

// ======================================================================
// K6: fused QKV GEMM — 8-PHASE, 256x256 tile, 8 waves (2M x 4N).
// LDS 2 x 64KB: A rows 0-255 @0 (units A0@0, A1@16384), B rows 0-255
// @32768 (units B0@32768, B1@49152). BK=64, 2 K-tiles/iter.
// Reads: P1/P5 = af(8)+bf(4) kh0; P3/P7 = af(8)+bf(4) kh1; P2/P4/P6/P8 none.
// MFMA: P1 mh0-kh0, P2 mh1-kh0, P3 mh0-kh1, P4 mh1-kh1 (x2 buffers).
// Stage FIFO: P1:t1.A1 P2:t1.B0 P3:t1.B1 P4:t2.A0 P5:t2.A1 P6:t2.B0
//             P7:t2.B1 P8:t3.A0.  vmcnt(2) at P4 & P8 (vmcnt(0) P4 last):
//   P4's vmcnt(2) drains all of t1 (incl. B1 staged P3) before P5 reads
//   both B units; P8's vmcnt(2) drains all of t2 before next-iter P1.
// Region-overwrite safety: stage in phase p targets regions whose current
// data was last read <= p-1 (A read P1-P4 -> staged P4/P5 via read-free P4;
// B read P1,P3 -> staged P6/P7). All stages follow the previous phase's
// trailing barrier, behind every wave's lgkmcnt(0) drain.
// ======================================================================
__global__ __launch_bounds__(512, 1) void k_gemm_qkv8p(const unsigned short* __restrict__ A,
    const unsigned short* __restrict__ Bt, unsigned short* __restrict__ C,
    const float* __restrict__ bq, const float* __restrict__ bk,
    const float* __restrict__ bv) {
  alignas(16) __shared__ char L[2][65536];
  int tid = threadIdx.x;
  int lane = tid & 63, g = lane >> 4, lr = lane & 15;
  int wid = tid >> 6, wm = wid >> 2, wn = wid & 3;
  int m0 = blockIdx.x * 256, n0 = blockIdx.y * 256;
  f32x4 zero4 = {0.f, 0.f, 0.f, 0.f};
  f32x4 acc[8][4];
#pragma unroll
  for (int m = 0; m < 8; m++)
#pragma unroll
    for (int n = 0; n < 4; n++) acc[m][n] = zero4;
  f32x4(*accLo)[4] = &acc[0];
  f32x4(*accHi)[4] = &acc[4];
  int arow = wm * 128 + lr;   // + q*16, q=0..7 (wm's 128-row half)
  int brow = wn * 64 + lr;    // + q*16, q=0..3 (rows 0..255 of B region)
  const int NI = D_ / 128;    // 16 iters, 2 K-tiles each
  // prologue: t0 all 4 units -> buf0; t1.A0 -> buf1
  stage_u(A, D_, m0, 0, &L[0][0], tid);
  stage_u(A, D_, m0 + 128, 0, &L[0][16384], tid);
  stage_u(Bt, D_, n0, 0, &L[0][32768], tid);
  stage_u(Bt, D_, n0 + 128, 0, &L[0][49152], tid);
  stage_u(A, D_, m0, 64, &L[1][0], tid);
  asm volatile("s_waitcnt vmcnt(2)" ::: "memory");
  __builtin_amdgcn_s_barrier();
  for (int i = 0; i < NI; i++) {
    const char* Buf0 = &L[0][0];
    const char* Buf1 = &L[1][0];
    int k1 = i * 128 + 64, k2 = i * 128 + 128, k3 = i * 128 + 192;
    bool more = (i + 1 < NI);
    s16x8 af[8], bf[4];
    // ---- P1: buf0 kh0 mh0; stage t1.A1 ----
#pragma unroll
    for (int q = 0; q < 8; q++) af[q] = ldfrag128(Buf0, arow + q * 16, g * 16);
#pragma unroll
    for (int q = 0; q < 4; q++) bf[q] = ldfrag128(Buf0 + 32768, brow + q * 16, g * 16);
    stage_u(A, D_, m0 + 128, k1, &L[1][16384], tid);
    PHASE_MFMA(af, bf, accLo);
    // ---- P2: buf0 kh0 mh1; stage t1.B0 ----
    stage_u(Bt, D_, n0, k1, &L[1][32768], tid);
    PHASE_MFMA((af + 4), bf, accHi);
    // ---- P3: buf0 kh1 mh0; stage t1.B1 ----
#pragma unroll
    for (int q = 0; q < 8; q++) af[q] = ldfrag128(Buf0, arow + q * 16, 64 + g * 16);
#pragma unroll
    for (int q = 0; q < 4; q++) bf[q] = ldfrag128(Buf0 + 32768, brow + q * 16, 64 + g * 16);
    stage_u(Bt, D_, n0 + 128, k1, &L[1][49152], tid);
    PHASE_MFMA(af, bf, accLo);
    // ---- P4: buf0 kh1 mh1; stage t2.A0; drain t1 ----
    if (more) {
      stage_u(A, D_, m0, k2, &L[0][0], tid);
      asm volatile("s_waitcnt vmcnt(2)" ::: "memory");
    } else {
      asm volatile("s_waitcnt vmcnt(0)" ::: "memory");
    }
    PHASE_MFMA((af + 4), bf, accHi);
    // ---- P5: buf1 kh0 mh0; stage t2.A1 ----
#pragma unroll
    for (int q = 0; q < 8; q++) af[q] = ldfrag128(Buf1, arow + q * 16, g * 16);
#pragma unroll
    for (int q = 0; q < 4; q++) bf[q] = ldfrag128(Buf1 + 32768, brow + q * 16, g * 16);
    if (more) stage_u(A, D_, m0 + 128, k2, &L[0][16384], tid);
    PHASE_MFMA(af, bf, accLo);
    // ---- P6: buf1 kh0 mh1; stage t2.B0 ----
    if (more) stage_u(Bt, D_, n0, k2, &L[0][32768], tid);
    PHASE_MFMA((af + 4), bf, accHi);
    // ---- P7: buf1 kh1 mh0; stage t2.B1 ----
#pragma unroll
    for (int q = 0; q < 8; q++) af[q] = ldfrag128(Buf1, arow + q * 16, 64 + g * 16);
#pragma unroll
    for (int q = 0; q < 4; q++) bf[q] = ldfrag128(Buf1 + 32768, brow + q * 16, 64 + g * 16);
    if (more) stage_u(Bt, D_, n0 + 128, k2, &L[0][49152], tid);
    PHASE_MFMA(af, bf, accLo);
    // ---- P8: buf1 kh1 mh1; stage t3.A0; drain t2 ----
    if (more) {
      stage_u(A, D_, m0, k3, &L[1][0], tid);
      asm volatile("s_waitcnt vmcnt(2)" ::: "memory");
    }
    PHASE_MFMA((af + 4), bf, accHi);
  }
#pragma unroll
  for (int m = 0; m < 8; m++)
#pragma unroll
    for (int n = 0; n < 4; n++)
#pragma unroll
      for (int r = 0; r < 4; r++) {
        int row = m0 + wm * 128 + m * 16 + (g << 2) + r;
        int col = n0 + wn * 64 + n * 16 + lr;
        float bias = (col < D_) ? bq[col] : ((col < 2 * D_) ? bk[col - D_] : bv[col - 2 * D_]);
        C[(size_t)row * D3_ + col] = f2bf(acc[m][n][r] + bias);
      }
}

// ======================================================================
// K11: fused gate/up GEMM — 8-PHASE (R10-proven, unchanged)
// ======================================================================
__global__ __launch_bounds__(512, 1) void k_gemm_gup8p(const unsigned short* __restrict__ A,
    const unsigned short* __restrict__ Bg, const unsigned short* __restrict__ Bu,
    unsigned short* __restrict__ act) {
  alignas(16) __shared__ char L[2][65536];
  int tid = threadIdx.x;
  int lane = tid & 63, g = lane >> 4, lr = lane & 15;
  int wid = tid >> 6, wm = wid >> 1, wn = wid & 1;
  int m0 = blockIdx.x * 256, n0 = blockIdx.y * 128;
  f32x4 zero4 = {0.f, 0.f, 0.f, 0.f};
  f32x4 ag[4][4], au[4][4];
#pragma unroll
  for (int m = 0; m < 4; m++)
#pragma unroll
    for (int n = 0; n < 4; n++) { ag[m][n] = zero4; au[m][n] = zero4; }
  int arow = wm * 64 + lr;
  int brow = wn * 64 + lr;
  const int NI = D_ / 128;
  stage_u(A, D_, m0, 0, &L[0][0], tid);
  stage_u(A, D_, m0 + 128, 0, &L[0][16384], tid);
  stage_u(Bg, D_, n0, 0, &L[0][32768], tid);
  stage_u(Bu, D_, n0, 0, &L[0][49152], tid);
  stage_u(A, D_, m0, 64, &L[1][0], tid);
  asm volatile("s_waitcnt vmcnt(2)" ::: "memory");
  __builtin_amdgcn_s_barrier();
  for (int i = 0; i < NI; i++) {
    const char* B0 = &L[0][0];
    const char* B1 = &L[1][0];
    int k1 = i * 128 + 64;
    int k2 = i * 128 + 128;
    int k3 = i * 128 + 192;
    bool more = (i + 1 < NI);
    s16x8 af0[4], af1[4], bb[4];
    // ---- P1: gate kh0 (buf0); stage t1.A1 ----
#pragma unroll
    for (int q = 0; q < 4; q++) af0[q] = ldfrag128(B0, arow + q * 16, g * 16);
#pragma unroll
    for (int q = 0; q < 4; q++) bb[q] = ldfrag128(B0 + 32768, brow + q * 16, g * 16);
    stage_u(A, D_, m0 + 128, k1, &L[1][16384], tid);
    asm volatile("s_waitcnt vmcnt(4)" ::: "memory");
    PHASE_MFMA(af0, bb, ag);
    // ---- P2: up kh0 (buf0); stage t1.Bg ----
#pragma unroll
    for (int q = 0; q < 4; q++) bb[q] = ldfrag128(B0 + 49152, brow + q * 16, g * 16);
    stage_u(Bg, D_, n0, k1, &L[1][32768], tid);
    PHASE_MFMA(af0, bb, au);
    // ---- P3: gate kh1 (buf0); stage t1.Bu ----
#pragma unroll
    for (int q = 0; q < 4; q++) af1[q] = ldfrag128(B0, arow + q * 16, 64 + g * 16);
#pragma unroll
    for (int q = 0; q < 4; q++) bb[q] = ldfrag128(B0 + 32768, brow + q * 16, 64 + g * 16);
    stage_u(Bu, D_, n0, k1, &L[1][49152], tid);
    PHASE_MFMA(af1, bb, ag);
    // ---- P4: up kh1 (buf0); stage t2.A0 ----
#pragma unroll
    for (int q = 0; q < 4; q++) bb[q] = ldfrag128(B0 + 49152, brow + q * 16, 64 + g * 16);
    if (more) {
      stage_u(A, D_, m0, k2, &L[0][0], tid);
      asm volatile("s_waitcnt vmcnt(4)" ::: "memory");
    } else {
      asm volatile("s_waitcnt vmcnt(0)" ::: "memory");
    }
    PHASE_MFMA(af1, bb, au);
    // ---- P5: gate kh0 (buf1); stage t2.A1 ----
#pragma unroll
    for (int q = 0; q < 4; q++) af0[q] = ldfrag128(B1, arow + q * 16, g * 16);
#pragma unroll
    for (int q = 0; q < 4; q++) bb[q] = ldfrag128(B1 + 32768, brow + q * 16, g * 16);
    if (more) stage_u(A, D_, m0 + 128, k2, &L[0][16384], tid);
    asm volatile("s_waitcnt vmcnt(4)" ::: "memory");
    PHASE_MFMA(af0, bb, ag);
    // ---- P6: up kh0 (buf1); stage t2.Bg ----
#pragma unroll
    for (int q = 0; q < 4; q++) bb[q] = ldfrag128(B1 + 49152, brow + q * 16, g * 16);
    if (more) stage_u(Bg, D_, n0, k2, &L[0][32768], tid);
    PHASE_MFMA(af0, bb, au);
    // ---- P7: gate kh1 (buf1); stage t2.Bu ----
#pragma unroll
    for (int q = 0; q < 4; q++) af1[q] = ldfrag128(B1, arow + q * 16, 64 + g * 16);
#pragma unroll
    for (int q = 0; q < 4; q++) bb[q] = ldfrag128(B1 + 32768, brow + q * 16, 64 + g * 16);
    if (more) stage_u(Bu, D_, n0, k2, &L[0][49152], tid);
    PHASE_MFMA(af1, bb, ag);
    // ---- P8: up kh1 (buf1); stage t3.A0 ----
#pragma unroll
    for (int q = 0; q < 4; q++) bb[q] = ldfrag128(B1 + 49152, brow + q * 16, 64 + g * 16);
    if (more) stage_u(A, D_, m0, k3, &L[1][0], tid);
    asm volatile("s_waitcnt vmcnt(4)" ::: "memory");
    PHASE_MFMA(af1, bb, au);
  }
#pragma unroll
  for (int m = 0; m < 4; m++)
#pragma unroll
    for (int n = 0; n < 4; n++)
#pragma unroll
      for (int r = 0; r < 4; r++) {
        int row = m0 + wm * 64 + m * 16 + (g << 2) + r;
        int col = n0 + wn * 64 + n * 16 + lr;
        float gv = ag[m][n][r], uv = au[m][n][r];
        float si = gv / (1.f + __expf(-gv));
        act[(size_t)row * I_ + col] = f2bf(si * uv);
      }
}

// ---------- K9: wo GEMM + residual, 64x128 tile, 4 waves (R6 schedule) ----------
__global__ __launch_bounds__(256, 2) void k_gemm_wo64(const unsigned short* __restrict__ A,
    const unsigned short* __restrict__ Bt, const float* __restrict__ xres,
    float* __restrict__ x1) {
  alignas(16) __shared__ short As[2][64 * 32];
  alignas(16) __shared__ short Bs[2][128 * 32];
  int tid = threadIdx.x;
  int lane = tid & 63, g = lane >> 4, lr = lane & 15, wid = tid >> 6;
  int m0 = blockIdx.x * 64, n0 = blockIdx.y * 128;
  f32x4 zero4 = {0.f, 0.f, 0.f, 0.f};
  f32x4 acc[4][2];
#pragma unroll
  for (int m = 0; m < 4; m++)
#pragma unroll
    for (int n = 0; n < 2; n++) acc[m][n] = zero4;
  const int nkt = D_ / 32;
  stage64r(A, D_, m0, 0, (char*)As[0], tid);
  stage128r(Bt, D_, n0, 0, (char*)Bs[0], tid);
  stage64r(A, D_, m0, 32, (char*)As[1], tid);
  stage128r(Bt, D_, n0, 32, (char*)Bs[1], tid);
  for (int t = 0; t < nkt; t++) {
    int b = t & 1;
    const char* Ab = (const char*)As[b];
    const char* Bb = (const char*)Bs[b];
    if (t + 1 < nkt) asm volatile("s_waitcnt vmcnt(3)" ::: "memory");
    else             asm volatile("s_waitcnt vmcnt(0)" ::: "memory");
    __builtin_amdgcn_s_barrier();
    s16x8 af[4], bf2[2];
#pragma unroll
    for (int i = 0; i < 4; i++) af[i] = ldfrag(Ab, i * 16 + lr, g);
#pragma unroll
    for (int j = 0; j < 2; j++) bf2[j] = ldfrag(Bb, wid * 32 + j * 16 + lr, g);
    asm volatile("s_waitcnt lgkmcnt(0)" ::: "memory");
    __builtin_amdgcn_s_barrier();
    if (t + 2 < nkt) {
      stage64r(A, D_, m0, (t + 2) * 32, (char*)As[b], tid);
      stage128r(Bt, D_, n0, (t + 2) * 32, (char*)Bs[b], tid);
    }
    __builtin_amdgcn_s_setprio(1);
#pragma unroll
    for (int m = 0; m < 4; m++)
#pragma unroll
      for (int n = 0; n < 2; n++) acc[m][n] = mfma_bf16(af[m], bf2[n], acc[m][n]);
    __builtin_amdgcn_s_setprio(0);
  }
#pragma unroll
  for (int m = 0; m < 4; m++)
#pragma unroll
    for (int n = 0; n < 2; n++)
#pragma unroll
      for (int r = 0; r < 4; r++) {
        int row = m0 + m * 16 + (g << 2) + r;
        int col = n0 + wid * 32 + n * 16 + lr;
        x1[(size_t)row * D_ + col] = acc[m][n][r] + xres[(size_t)row * D_ + col];
      }
}

// ---------- K12: down GEMM + residual + blend + scatter, 64x128 (R6) ----------
__global__ __launch_bounds__(256, 2) void k_gemm_down64(const unsigned short* __restrict__ A,
    const unsigned short* __restrict__ Bt, const float* __restrict__ x1,
    const float* __restrict__ x, const float* __restrict__ gate,
    const int* __restrict__ pos, float* __restrict__ out) {
  alignas(16) __shared__ short As[2][64 * 32];
  alignas(16) __shared__ short Bs[2][128 * 32];
  int tid = threadIdx.x;
  int lane = tid & 63, g = lane >> 4, lr = lane & 15, wid = tid >> 6;
  int m0 = blockIdx.x * 64, n0 = blockIdx.y * 128;
  f32x4 zero4 = {0.f, 0.f, 0.f, 0.f};
  f32x4 acc[4][2];
#pragma unroll
  for (int m = 0; m < 4; m++)
#pragma unroll
    for (int n = 0; n < 2; n++) acc[m][n] = zero4;
  const int nkt = I_ / 32;
  stage64r(A, I_, m0, 0, (char*)As[0], tid);
  stage128r(Bt, I_, n0, 0, (char*)Bs[0], tid);
  stage64r(A, I_, m0, 32, (char*)As[1], tid);
  stage128r(Bt, I_, n0, 32, (char*)Bs[1], tid);
  for (int t = 0; t < nkt; t++) {
    int b = t & 1;
    const char* Ab = (const char*)As[b];
    const char* Bb = (const char*)Bs[b];
    if (t + 1 < nkt) asm volatile("s_waitcnt vmcnt(3)" ::: "memory");
    else             asm volatile("s_waitcnt vmcnt(0)" ::: "memory");
    __builtin_amdgcn_s_barrier();
    s16x8 af[4], bf2[2];
#pragma unroll
    for (int i = 0; i < 4; i++) af[i] = ldfrag(Ab, i * 16 + lr, g);
#pragma unroll
    for (int j = 0; j < 2; j++) bf2[j] = ldfrag(Bb, wid * 32 + j * 16 + lr, g);
    asm volatile("s_waitcnt lgkmcnt(0)" ::: "memory");
    __builtin_amdgcn_s_barrier();
    if (t + 2 < nkt) {
      stage64r(A, I_, m0, (t + 2) * 32, (char*)As[b], tid);
      stage128r(Bt, I_, n0, (t + 2) * 32, (char*)Bs[b], tid);
    }
    __builtin_amdgcn_s_setprio(1);
#pragma unroll
    for (int m = 0; m < 4; m++)
#pragma unroll
      for (int n = 0; n < 2; n++) acc[m][n] = mfma_bf16(af[m], bf2[n], acc[m][n]);
    __builtin_amdgcn_s_setprio(0);
  }
#pragma unroll
  for (int m = 0; m < 4; m++)
#pragma unroll
    for (int n = 0; n < 2; n++)
#pragma unroll
      for (int r = 0; r < 4; r++) {
        int srow = m0 + m * 16 + (g << 2) + r;
        int col = n0 + wid * 32 + n * 16 + lr;
        float proc = acc[m][n][r] + x1[(size_t)srow * D_ + col];
        float gt = gate[srow];
        float xv = x[(size_t)srow * D_ + col];
        int bb = srow >> 9;
        int p = pos[srow];
        out[((size_t)bb * T_ + p) * D_ + col] = gt * proc + (1.f - gt) * xv;
      }
}

// ---------- K7: RoPE + head relayout (q,k row-major per head; v transposed) ----------
__global__ __launch_bounds__(256) void k_rope(const unsigned short* __restrict__ qkv,
    const float* __restrict__ cosb, const float* __restrict__ sinb,
    unsigned short* __restrict__ qh, unsigned short* __restrict__ kh,
    unsigned short* __restrict__ vT) {
  int s0 = blockIdx.x * 64;
  int h = blockIdx.y;
  int t = threadIdx.x;
#pragma unroll
  for (int i = 0; i < 16; i++) {
    int flat = t + i * 256;
    int r = flat >> 6, dp = flat & 63;
    int s = s0 + r;
    float c = cosb[s * 64 + dp], sn = sinb[s * 64 + dp];
    const unsigned short* qrow = qkv + (size_t)s * D3_ + h * HD_;
    float q1 = bf2f(qrow[dp]), q2 = bf2f(qrow[dp + 64]);
    unsigned short* qdst = qh + ((size_t)h * S_ + s) * HD_;
    qdst[dp] = f2bf(q1 * c - q2 * sn);
    qdst[dp + 64] = f2bf(q2 * c + q1 * sn);
    const unsigned short* krow = qrow + D_;
    float k1 = bf2f(krow[dp]), k2 = bf2f(krow[dp + 64]);
    unsigned short* kdst = kh + ((size_t)h * S_ + s) * HD_;
    kdst[dp] = f2bf(k1 * c - k2 * sn);
    kdst[dp + 64] = f2bf(k2 * c + k1 * sn);
  }
  __shared__ unsigned short vt[128][66];
#pragma unroll
  for (int i = 0; i < 32; i++) {
    int flat = t + i * 256;
    int r = flat >> 7, d = flat & 127;
    vt[d][r] = qkv[(size_t)(s0 + r) * D3_ + 2 * D_ + h * HD_ + d];
  }
  __syncthreads();
#pragma unroll
  for (int i = 0; i < 32; i++) {
    int flat = t + i * 256;
    int d = flat >> 6, sc = flat & 63;
    vT[((size_t)h * HD_ + d) * S_ + s0 + sc] = vt[d][sc];
  }
}

// ======================================================================
// K8: flash attention (q-tile 64, LPT order, swizzled LDS, dbuf KV)
// ======================================================================
__device__ __forceinline__ void stage_kv(const unsigned short* __restrict__ kh,
                                         const unsigned short* __restrict__ vT,
                                         size_t hbase, int kt, char* KsB, char* VsB, int tid) {
#pragma unroll
  for (int c = 0; c < 4; c++) {
    int off = c * 4096 + tid * 16;
    int row = off >> 8;
    int cb = (off & 255) ^ ((row & 7) << 4);
    gl_lds16(kh + hbase + (size_t)(kt * 64 + row) * HD_ + (cb >> 1), KsB + off);
  }
#pragma unroll
  for (int c = 0; c < 4; c++) {
    int off = c * 4096 + tid * 16;
    int row = off >> 7;
    int cb = (off & 127) ^ ((row & 7) << 4);
    gl_lds16(vT + hbase + (size_t)row * S_ + kt * 64 + (cb >> 1), VsB + off);
  }
}

__global__ __launch_bounds__(256, 2) void k_attn(const unsigned short* __restrict__ qh,
                                                 const unsigned short* __restrict__ kh,
                                                 const unsigned short* __restrict__ vT,
                                                 unsigned short* __restrict__ ao) {
  alignas(16) __shared__ short Ks[2][64 * 128];
  alignas(16) __shared__ short Vs[2][128 * 64];
  alignas(16) __shared__ short Ps[4][16 * 64];
  int bidx = blockIdx.x;
  int head = bidx & 15;
  int slot = bidx >> 4;
  int qt = (slot < 16) ? (31 - slot) : (slot - 16);
  int q0 = qt * 64;
  int tid = threadIdx.x, w = tid >> 6, lane = tid & 63, g = lane >> 4, lr = lane & 15;
  size_t hbase = (size_t)head * S_ * HD_;
  int qw = q0 + w * 16;
  char* PsW = (char*)&Ps[w][0];
  s16x8 qf[4];
#pragma unroll
  for (int ks = 0; ks < 4; ks++)
    qf[ks] = *(const s16x8*)&qh[hbase + (size_t)(qw + lr) * HD_ + ks * 32 + g * 8];
  f32x4 o[8];
  f32x4 zero4 = {0.f, 0.f, 0.f, 0.f};
#pragma unroll
  for (int nf = 0; nf < 8; nf++) o[nf] = zero4;
  float m_i[4], l_i[4];
#pragma unroll
  for (int r = 0; r < 4; r++) { m_i[r] = -1e30f; l_i[r] = 0.f; }
  const float sc = 0.08838834764831843f;

  stage_kv(kh, vT, hbase, 0, (char*)Ks[0], (char*)Vs[0], tid);
  if (qt > 0) stage_kv(kh, vT, hbase, 1, (char*)Ks[1], (char*)Vs[1], tid);

  for (int kt = 0; kt <= qt; kt++) {
    int b = kt & 1;
    const char* KsB = (const char*)Ks[b];
    const char* VsB = (const char*)Vs[b];
    if (kt < qt) asm volatile("s_waitcnt vmcnt(8)" ::: "memory");
    else         asm volatile("s_waitcnt vmcnt(0)" ::: "memory");
    __builtin_amdgcn_s_barrier();
    f32x4 sacc[4];
#pragma unroll
    for (int nf = 0; nf < 4; nf++) sacc[nf] = zero4;
#pragma unroll
    for (int ks = 0; ks < 4; ks++) {
      s16x8 kf[4];
#pragma unroll
      for (int nf = 0; nf < 4; nf++) {
        int row = nf * 16 + lr;
        kf[nf] = *(const s16x8*)(KsB + row * 256 + (((ks << 6) + (g << 4)) ^ ((row & 7) << 4)));
      }
#pragma unroll
      for (int nf = 0; nf < 4; nf++) sacc[nf] = mfma_bf16(qf[ks], kf[nf], sacc[nf]);
    }
    bool diag = (kt == qt);
#pragma unroll
    for (int r = 0; r < 4; r++) {
      int prow = (g << 2) + r;
      int qrow = qw + prow;
      float pv[4];
      float mx = -1e30f;
#pragma unroll
      for (int nf = 0; nf < 4; nf++) {
        float vv = sacc[nf][r] * sc;
        if (diag) {
          int kc = kt * 64 + nf * 16 + lr;
          vv = (kc <= qrow) ? vv : -1e30f;
        }
        pv[nf] = vv;
        mx = fmaxf(mx, vv);
      }
#pragma unroll
      for (int d = 1; d < 16; d <<= 1) mx = fmaxf(mx, __shfl_xor(mx, d));
      float mold = m_i[r], mnew = fmaxf(mold, mx);
      float corr = __expf(mold - mnew);
      float ssum = 0.f;
#pragma unroll
      for (int nf = 0; nf < 4; nf++) {
        float pe = __expf(pv[nf] - mnew);
        int cb = ((nf * 16 + lr) << 1) ^ ((prow & 7) << 4);
        *(unsigned short*)(PsW + prow * 128 + cb) = f2bf(pe);
        ssum += pe;
      }
#pragma unroll
      for (int d = 1; d < 16; d <<= 1) ssum += __shfl_xor(ssum, d);
      l_i[r] = l_i[r] * corr + ssum;
      m_i[r] = mnew;
#pragma unroll
      for (int nf = 0; nf < 8; nf++) o[nf][r] *= corr;
    }
    s16x8 pa[2];
#pragma unroll
    for (int ks = 0; ks < 2; ks++)
      pa[ks] = *(const s16x8*)(PsW + lr * 128 + (((ks << 6) + (g << 4)) ^ ((lr & 7) << 4)));
#pragma unroll
    for (int nf = 0; nf < 8; nf++) {
#pragma unroll
      for (int ks = 0; ks < 2; ks++) {
        int row = nf * 16 + lr;
        s16x8 vb = *(const s16x8*)(VsB + row * 128 + (((ks << 6) + (g << 4)) ^ ((row & 7) << 4)));
        o[nf] = mfma_bf16(pa[ks], vb, o[nf]);
      }
    }
    asm volatile("s_waitcnt lgkmcnt(0)" ::: "memory");
    __builtin_amdgcn_s_barrier();
    if (kt + 2 <= qt)
      stage_kv(kh, vT, hbase, kt + 2, (char*)Ks[b], (char*)Vs[b], tid);
  }
#pragma unroll
  for (int nf = 0; nf < 8; nf++)
#pragma unroll
    for (int r = 0; r < 4; r++) {
      int row = qw + (g << 2) + r;
      int col = head * HD_ + nf * 16 + lr;
      ao[(size_t)row * D_ + col] = f2bf(o[nf][r] / l_i[r]);
    }
}

// ---------- K10: RMS2 ----------
__global__ __launch_bounds__(256) void k_rms2(const float* __restrict__ x1,
                                              const float* __restrict__ ln2w,
                                              unsigned short* __restrict__ xn2) {
  int s = blockIdx.x, t = threadIdx.x;
  const float* src = x1 + (size_t)s * D_;
  float v[8];
  float ss = 0.f;
#pragma unroll
  for (int i = 0; i < 8; i++) { v[i] = src[t + i * 256]; ss += v[i] * v[i]; }
  __shared__ float red[4];
#pragma unroll
  for (int d = 32; d; d >>= 1) ss += __shfl_xor(ss, d);
  if ((t & 63) == 0) red[t >> 6] = ss;
  __syncthreads();
  ss = red[0] + red[1] + red[2] + red[3];
  float scale = rsqrtf(ss / (float)D_ + 1e-6f);
  unsigned short* dst = xn2 + (size_t)s * D_;
#pragma unroll
  for (int i = 0; i < 8; i++) {
    int c = t + i * 256;
    dst[c] = f2bf(v[i] * scale * ln2w[c]);
  }
}

extern "C" void kernel_launch(void* const* d_in, const int* in_sizes, int n_in,
                              void* d_out, int out_size, void* d_ws, size_t ws_size,
                              hipStream_t stream) {
  (void)in_sizes; (void)n_in; (void)out_size; (void)ws_size;
  const float* hidden = (const float*)d_in[0];
  const float* router_w = (const float*)d_in[1];
  const float* router_b = (const float*)d_in[2];
  const float* ln1w = (const float*)d_in[3];
  const float* ln2w = (const float*)d_in[4];
  const float* wq = (const float*)d_in[5];
  const float* bq = (const float*)d_in[6];
  const float* wk = (const float*)d_in[7];
  const float* bk = (const float*)d_in[8];
  const float* wv = (const float*)d_in[9];
  const float* bv = (const float*)d_in[10];
  const float* wo = (const float*)d_in[11];
  const float* wg = (const float*)d_in[12];
  const float* wu = (const float*)d_in[13];
  const float* wd = (const float*)d_in[14];
  float* out = (float*)d_out;

  char* ws = (char*)d_ws;
  size_t off = 0;
  auto alloc = [&](size_t bytes) {
    char* p = ws + off;
    off += (bytes + 255) & ~(size_t)255;
    return p;
  };
  unsigned short* wqkvT = (unsigned short*)alloc(3ull * D_ * D_ * 2);
  unsigned short* woT = (unsigned short*)alloc((size_t)D_ * D_ * 2);
  unsigned short* wgT = (unsigned short*)alloc((size_t)I_ * D_ * 2);
  unsigned short* wuT = (unsigned short*)alloc((size_t)I_ * D_ * 2);
  unsigned short* wdT = (unsigned short*)alloc((size_t)D_ * I_ * 2);
  float* scores = (float*)alloc((size_t)B_ * T_ * 4);
  int* pos = (int*)alloc((size_t)S_ * 4);
  float* gate = (float*)alloc((size_t)S_ * 4);
  float* x = (float*)alloc((size_t)S_ * D_ * 4);
  float* x1 = (float*)alloc((size_t)S_ * D_ * 4);
  unsigned short* xn = (unsigned short*)alloc((size_t)S_ * D_ * 2);  // reused as x1n
  float* cosb = (float*)alloc((size_t)S_ * 64 * 4);
  float* sinb = (float*)alloc((size_t)S_ * 64 * 4);
  unsigned short* qkv = (unsigned short*)alloc((size_t)S_ * D3_ * 2);  // reused as act
  unsigned short* qh = (unsigned short*)alloc((size_t)H_ * S_ * HD_ * 2);
  unsigned short* kh = (unsigned short*)alloc((size_t)H_ * S_ * HD_ * 2);
  unsigned short* vT = (unsigned short*)alloc((size_t)H_ * S_ * HD_ * 2);
  unsigned short* ao = (unsigned short*)alloc((size_t)S_ * D_ * 2);

  k_copy_scores<<<B_ * T_, 256, 0, stream>>>((const float4*)hidden, (float4*)out,
                                             (const float4*)router_w, router_b, scores);

  k_transpose4<<<dim3(D_ / 32, D_ / 32, 4), 256, 0, stream>>>(
      wq, wk, wv, wo, wqkvT, wqkvT + (size_t)D_ * D_, wqkvT + 2ull * D_ * D_, woT, D_, D_);
  k_transpose2<<<dim3(I_ / 32, D_ / 32, 2), 256, 0, stream>>>(wg, wu, wgT, wuT, D_, I_);
  k_transpose<<<dim3(D_ / 32, I_ / 32), 256, 0, stream>>>(wd, wdT, I_, D_);

  k_topk<<<B_, 1024, 0, stream>>>(scores, pos);
  k_gather<<<S_, 256, 0, stream>>>(hidden, pos, scores, ln1w, x, xn, gate, cosb, sinb);

  k_gemm_qkv8p<<<dim3(S_ / 256, D3_ / 256), 512, 0, stream>>>(xn, wqkvT, qkv, bq, bk, bv);
  k_rope<<<dim3(S_ / 64, H_), 256, 0, stream>>>(qkv, cosb, sinb, qh, kh, vT);
  k_attn<<<32 * H_, 256, 0, stream>>>(qh, kh, vT, ao);
  k_gemm_wo64<<<dim3(S_ / 64, D_ / 128), 256, 0, stream>>>(ao, woT, x, x1);
  k_rms2<<<S_, 256, 0, stream>>>(x1, ln2w, xn);
  k_gemm_gup8p<<<dim3(S_ / 256, I_ / 128), 512, 0, stream>>>(xn, wgT, wuT, qkv);
  k_gemm_down64<<<dim3(S_ / 64, D_ / 128), 256, 0, stream>>>(qkv, wdT, x1, x, gate, pos, out);
}

// Round 12
// 510.054 us; speedup vs baseline: 1.2135x; 1.0263x over previous
//
#include <hip/hip_runtime.h>
#include <stdint.h>

#define B_ 4
#define T_ 2048
#define D_ 2048
#define H_ 16
#define HD_ 128
#define I_ 5632
#define K_ 512
#define S_ 2048
#define D3_ (3 * D_)

typedef float f32x4 __attribute__((ext_vector_type(4)));
typedef short s16x8 __attribute__((ext_vector_type(8)));
typedef __bf16 bf16x8 __attribute__((ext_vector_type(8)));

// ---------- mfma wrapper robust to builtin operand type (short8 vs bf16x8) ----------
template <typename V>
__device__ __forceinline__ auto mfma_try(V a, V b, f32x4 c, int)
    -> decltype(__builtin_amdgcn_mfma_f32_16x16x32_bf16(a, b, c, 0, 0, 0)) {
  return __builtin_amdgcn_mfma_f32_16x16x32_bf16(a, b, c, 0, 0, 0);
}
template <typename V>
__device__ __forceinline__ f32x4 mfma_try(V a, V b, f32x4 c, long) {
  return __builtin_amdgcn_mfma_f32_16x16x32_bf16(
      __builtin_bit_cast(bf16x8, a), __builtin_bit_cast(bf16x8, b), c, 0, 0, 0);
}
__device__ __forceinline__ f32x4 mfma_bf16(s16x8 a, s16x8 b, f32x4 c) {
  return mfma_try(a, b, c, 0);
}

__device__ __forceinline__ void gl_lds16(const void* g, void* l) {
  __builtin_amdgcn_global_load_lds((const __attribute__((address_space(1))) void*)g,
                                   (__attribute__((address_space(3))) void*)l, 16, 0, 0);
}

__device__ __forceinline__ unsigned short f2bf(float f) {
  unsigned u = __float_as_uint(f);
  u += 0x7FFFu + ((u >> 16) & 1);
  return (unsigned short)(u >> 16);
}
__device__ __forceinline__ float bf2f(unsigned short s) {
  return __uint_as_float(((unsigned)s) << 16);
}

// XCD-aware bijective chunked swizzle (T1). nwg must be %8==0.
// nt-fast decomposition: XCD k owns a contiguous band of m-tiles with ALL
// n-tiles -> its A-panel stays L2-resident, B streams once.
__device__ __forceinline__ int xcd_swz(int bid, int cpx) {
  return (bid & 7) * cpx + (bid >> 3);
}

// ---------- K1: copy hidden -> out, fused with router scores ----------
__global__ __launch_bounds__(256) void k_copy_scores(const float4* __restrict__ hid,
                                                     float4* __restrict__ dst,
                                                     const float4* __restrict__ rw,
                                                     const float* __restrict__ rb,
                                                     float* __restrict__ scores) {
  int row = blockIdx.x, t = threadIdx.x;
  const float4* hr = hid + (size_t)row * (D_ / 4);
  float4* dr = dst + (size_t)row * (D_ / 4);
  float acc = 0.f;
#pragma unroll
  for (int i = 0; i < 2; i++) {
    float4 v = hr[t + i * 256];
    dr[t + i * 256] = v;
    float4 w = rw[t + i * 256];
    acc += v.x * w.x + v.y * w.y + v.z * w.z + v.w * w.w;
  }
#pragma unroll
  for (int d = 32; d; d >>= 1) acc += __shfl_xor(acc, d);
  __shared__ float red[4];
  if ((t & 63) == 0) red[t >> 6] = acc;
  __syncthreads();
  if (t == 0) scores[row] = red[0] + red[1] + red[2] + red[3] + rb[0];
}

// ---------- K3: exact top-k (bitonic, matches jax.lax.top_k tie-break) ----------
__global__ __launch_bounds__(1024) void k_topk(const float* __restrict__ scores,
                                               int* __restrict__ pos) {
  __shared__ unsigned long long keys[T_];
  __shared__ int sidx[K_];
  int b = blockIdx.x, t = threadIdx.x;
  for (int i = t; i < T_; i += 1024) {
    unsigned u = __float_as_uint(scores[b * T_ + i]);
    u = (u & 0x80000000u) ? ~u : (u | 0x80000000u);
    keys[i] = ((unsigned long long)u << 32) | (unsigned)(~(unsigned)i);
  }
  __syncthreads();
  for (int k = 2; k <= T_; k <<= 1)
    for (int j = k >> 1; j > 0; j >>= 1) {
      for (int i = t; i < T_; i += 1024) {
        int l = i ^ j;
        if (l > i) {
          unsigned long long a = keys[i], c = keys[l];
          bool desc = ((i & k) == 0);
          if (desc ? (a < c) : (a > c)) { keys[i] = c; keys[l] = a; }
        }
      }
      __syncthreads();
    }
  if (t < K_) sidx[t] = (int)(~(unsigned)(keys[t] & 0xFFFFFFFFull));
  __syncthreads();
  for (int k = 2; k <= K_; k <<= 1)
    for (int j = k >> 1; j > 0; j >>= 1) {
      if (t < K_) {
        int i = t, l = i ^ j;
        if (l > i && l < K_) {
          int a = sidx[i], c = sidx[l];
          bool asc = ((i & k) == 0);
          if (asc ? (a > c) : (a < c)) { sidx[i] = c; sidx[l] = a; }
        }
      }
      __syncthreads();
    }
  if (t < K_) pos[b * K_ + t] = sidx[t];
}

// ---------- K4: gather + RMS1 + gate + rope tables ----------
__global__ __launch_bounds__(256) void k_gather(const float* __restrict__ hidden,
    const int* __restrict__ pos, const float* __restrict__ scores,
    const float* __restrict__ ln1w, float* __restrict__ x,
    unsigned short* __restrict__ xn, float* __restrict__ gate,
    float* __restrict__ cosb, float* __restrict__ sinb) {
  int s = blockIdx.x, t = threadIdx.x;
  int b = s >> 9, p = pos[s];
  const float* src = hidden + ((size_t)b * T_ + p) * D_;
  float v[8];
  float ss = 0.f;
#pragma unroll
  for (int i = 0; i < 8; i++) { v[i] = src[t + i * 256]; ss += v[i] * v[i]; }
  __shared__ float red[4];
#pragma unroll
  for (int d = 32; d; d >>= 1) ss += __shfl_xor(ss, d);
  if ((t & 63) == 0) red[t >> 6] = ss;
  __syncthreads();
  ss = red[0] + red[1] + red[2] + red[3];
  float scale = rsqrtf(ss / (float)D_ + 1e-6f);
  float* xd = x + (size_t)s * D_;
  unsigned short* xnd = xn + (size_t)s * D_;
#pragma unroll
  for (int i = 0; i < 8; i++) {
    int c = t + i * 256;
    xd[c] = v[i];
    xnd[c] = f2bf(v[i] * scale * ln1w[c]);
  }
  if (t == 0) gate[s] = 1.f / (1.f + expf(-scores[b * T_ + p]));
  if (t < 64) {
    float invf = powf(10000.0f, -(float)t / 64.0f);
    float f = (float)p * invf;
    cosb[s * 64 + t] = cosf(f);
    sinb[s * 64 + t] = sinf(f);
  }
}

// ---------- K5: transpose + f32->bf16, batched via z (ushort4 writes) ----------
__device__ __forceinline__ void transpose_body(const float* __restrict__ src,
                                               unsigned short* __restrict__ dst,
                                               int R, int C) {
  __shared__ float tile[32][33];
  int tx = threadIdx.x & 31, ty = threadIdx.x >> 5;
  int c0 = blockIdx.x * 32, r0 = blockIdx.y * 32;
#pragma unroll
  for (int i = 0; i < 4; i++) {
    int r = ty + i * 8;
    tile[r][tx] = src[(size_t)(r0 + r) * C + c0 + tx];
  }
  __syncthreads();
  int drow = threadIdx.x >> 3;
  int dc4 = (threadIdx.x & 7) * 4;
  ushort4 v;
  v.x = f2bf(tile[dc4 + 0][drow]);
  v.y = f2bf(tile[dc4 + 1][drow]);
  v.z = f2bf(tile[dc4 + 2][drow]);
  v.w = f2bf(tile[dc4 + 3][drow]);
  *(ushort4*)&dst[(size_t)(c0 + drow) * R + r0 + dc4] = v;
}
__global__ __launch_bounds__(256) void k_transpose(const float* __restrict__ src,
                                                   unsigned short* __restrict__ dst,
                                                   int R, int C) {
  transpose_body(src, dst, R, C);
}
__global__ __launch_bounds__(256) void k_transpose4(const float* s0, const float* s1,
                                                    const float* s2, const float* s3,
                                                    unsigned short* d0, unsigned short* d1,
                                                    unsigned short* d2, unsigned short* d3,
                                                    int R, int C) {
  int z = blockIdx.z;
  const float* src = (z == 0) ? s0 : (z == 1) ? s1 : (z == 2) ? s2 : s3;
  unsigned short* dst = (z == 0) ? d0 : (z == 1) ? d1 : (z == 2) ? d2 : d3;
  transpose_body(src, dst, R, C);
}
__global__ __launch_bounds__(256) void k_transpose2(const float* s0, const float* s1,
                                                    unsigned short* d0, unsigned short* d1,
                                                    int R, int C) {
  int z = blockIdx.z;
  transpose_body(z ? s1 : s0, z ? d1 : d0, R, C);
}

// ======================================================================
// 2-phase GEMM helpers (R6-proven skeleton; 64B rows, SWZ swizzle)
// ======================================================================
#define SWZ(row) ((((row) >> 1) & 3) << 4)

__device__ __forceinline__ void stage64r(const unsigned short* __restrict__ g, int ldK,
                                         int row0, int k0, char* lds, int tid) {
  int off = tid * 16;
  int row = off >> 6;
  int cb = (off & 63) ^ SWZ(row);
  gl_lds16(g + (size_t)(row0 + row) * ldK + k0 + (cb >> 1), lds + off);
}
__device__ __forceinline__ void stage128r(const unsigned short* __restrict__ g, int ldK,
                                          int row0, int k0, char* lds, int tid) {
#pragma unroll
  for (int c = 0; c < 2; c++) {
    int off = c * 4096 + tid * 16;
    int row = off >> 6;
    int cb = (off & 63) ^ SWZ(row);
    gl_lds16(g + (size_t)(row0 + row) * ldK + k0 + (cb >> 1), lds + off);
  }
}
__device__ __forceinline__ s16x8 ldfrag(const char* base, int row, int g) {
  return *(const s16x8*)(base + row * 64 + ((g * 16) ^ SWZ(row)));
}

// ======================================================================
// 8-phase GEMM pieces (R10/R11-proven): 128B rows, unit = 16KB,
// swizzle involution byte ^= ((row&7)<<4), applied global-side + read.
// ======================================================================
__device__ __forceinline__ void stage_u(const unsigned short* __restrict__ g, int ldK,
                                        int grow0, int k0, char* ldsbase, int tid) {
#pragma unroll
  for (int c = 0; c < 2; c++) {
    int off = c * 8192 + tid * 16;       // 16KB unit = 128 rows x 128B
    int row = off >> 7;
    int cb = (off & 127) ^ ((row & 7) << 4);
    gl_lds16(g + (size_t)(grow0 + row) * ldK + k0 + (cb >> 1), ldsbase + off);
  }
}
__device__ __forceinline__ s16x8 ldfrag128(const char* base, int row, int byteoff) {
  return *(const s16x8*)(base + row * 128 + (byteoff ^ ((row & 7) << 4)));
}

#define PHASE_MFMA(AF, BB, ACC)                                     \
  __builtin_amdgcn_s_barrier();                                     \
  asm volatile("s_waitcnt lgkmcnt(0)" ::: "memory");                \
  __builtin_amdgcn_sched_barrier(0);                                \
  __builtin_amdgcn_s_setprio(1);                                    \
  _Pragma("unroll") for (int m = 0; m < 4; m++)                     \
    _Pragma("unroll") for (int n = 0; n < 4; n++)                   \
      ACC[m][n] = mfma_bf16(AF[m], BB[n], ACC[m][n]);               \
  __builtin_amdgcn_s_setprio(0);                                    \
  __builtin_amdgcn_s_barrier();

// ======================================================================
// K6: fused QKV GEMM — 8-PHASE, 256x256 tile, 8 waves (R11-proven),
// now with XCD swizzle: grid 1D 192 = 8x24, cpx=24, mt=swz/24 (nt-fast).
// ======================================================================
__global__ __launch_bounds__(512, 1) void k_gemm_qkv8p(const unsigned short* __restrict__ A,
    const unsigned short* __restrict__ Bt, unsigned short* __restrict__ C,
    const float* __restrict__ bq, const float* __restrict__ bk,
    const float* __restrict__ bv) {
  alignas(16) __shared__ char L[2][65536];
  int tid = threadIdx.x;
  int lane = tid & 63, g = lane >> 4, lr = lane & 15;
  int wid = tid >> 6, wm = wid >> 2, wn = wid & 3;
  int swz = xcd_swz(blockIdx.x, 24);
  int m0 = (swz / 24) * 256, n0 = (swz % 24) * 256;
  f32x4 zero4 = {0.f, 0.f, 0.f, 0.f};
  f32x4 acc[8][4];
#pragma unroll
  for (int m = 0; m < 8; m++)
#pragma unroll
    for (int n = 0; n < 4; n++) acc[m][n] = zero4;
  f32x4(*accLo)[4] = &acc[0];
  f32x4(*accHi)[4] = &acc[4];
  int arow = wm * 128 + lr;
  int brow = wn * 64 + lr;
  const int NI = D_ / 128;
  stage_u(A, D_, m0, 0, &L[0][0], tid);
  stage_u(A, D_, m0 + 128, 0, &L[0][16384], tid);
  stage_u(Bt, D_, n0, 0, &L[0][32768], tid);
  stage_u(Bt, D_, n0 + 128, 0, &L[0][49152], tid);
  stage_u(A, D_, m0, 64, &L[1][0], tid);
  asm volatile("s_waitcnt vmcnt(2)" ::: "memory");
  __builtin_amdgcn_s_barrier();
  for (int i = 0; i < NI; i++) {
    const char* Buf0 = &L[0][0];
    const char* Buf1 = &L[1][0];
    int k1 = i * 128 + 64, k2 = i * 128 + 128, k3 = i * 128 + 192;
    bool more = (i + 1 < NI);
    s16x8 af[8], bf[4];
    // ---- P1: buf0 kh0 mh0; stage t1.A1 ----
#pragma unroll
    for (int q = 0; q < 8; q++) af[q] = ldfrag128(Buf0, arow + q * 16, g * 16);
#pragma unroll
    for (int q = 0; q < 4; q++) bf[q] = ldfrag128(Buf0 + 32768, brow + q * 16, g * 16);
    stage_u(A, D_, m0 + 128, k1, &L[1][16384], tid);
    PHASE_MFMA(af, bf, accLo);
    // ---- P2: buf0 kh0 mh1; stage t1.B0 ----
    stage_u(Bt, D_, n0, k1, &L[1][32768], tid);
    PHASE_MFMA((af + 4), bf, accHi);
    // ---- P3: buf0 kh1 mh0; stage t1.B1 ----
#pragma unroll
    for (int q = 0; q < 8; q++) af[q] = ldfrag128(Buf0, arow + q * 16, 64 + g * 16);
#pragma unroll
    for (int q = 0; q < 4; q++) bf[q] = ldfrag128(Buf0 + 32768, brow + q * 16, 64 + g * 16);
    stage_u(Bt, D_, n0 + 128, k1, &L[1][49152], tid);
    PHASE_MFMA(af, bf, accLo);
    // ---- P4: buf0 kh1 mh1; stage t2.A0; drain t1 ----
    if (more) {
      stage_u(A, D_, m0, k2, &L[0][0], tid);
      asm volatile("s_waitcnt vmcnt(2)" ::: "memory");
    } else {
      asm volatile("s_waitcnt vmcnt(0)" ::: "memory");
    }
    PHASE_MFMA((af + 4), bf, accHi);
    // ---- P5: buf1 kh0 mh0; stage t2.A1 ----
#pragma unroll
    for (int q = 0; q < 8; q++) af[q] = ldfrag128(Buf1, arow + q * 16, g * 16);
#pragma unroll
    for (int q = 0; q < 4; q++) bf[q] = ldfrag128(Buf1 + 32768, brow + q * 16, g * 16);
    if (more) stage_u(A, D_, m0 + 128, k2, &L[0][16384], tid);
    PHASE_MFMA(af, bf, accLo);
    // ---- P6: buf1 kh0 mh1; stage t2.B0 ----
    if (more) stage_u(Bt, D_, n0, k2, &L[0][32768], tid);
    PHASE_MFMA((af + 4), bf, accHi);
    // ---- P7: buf1 kh1 mh0; stage t2.B1 ----
#pragma unroll
    for (int q = 0; q < 8; q++) af[q] = ldfrag128(Buf1, arow + q * 16, 64 + g * 16);
#pragma unroll
    for (int q = 0; q < 4; q++) bf[q] = ldfrag128(Buf1 + 32768, brow + q * 16, 64 + g * 16);
    if (more) stage_u(Bt, D_, n0 + 128, k2, &L[0][49152], tid);
    PHASE_MFMA(af, bf, accLo);
    // ---- P8: buf1 kh1 mh1; stage t3.A0; drain t2 ----
    if (more) {
      stage_u(A, D_, m0, k3, &L[1][0], tid);
      asm volatile("s_waitcnt vmcnt(2)" ::: "memory");
    }
    PHASE_MFMA((af + 4), bf, accHi);
  }
#pragma unroll
  for (int m = 0; m < 8; m++)
#pragma unroll
    for (int n = 0; n < 4; n++)
#pragma unroll
      for (int r = 0; r < 4; r++) {
        int row = m0 + wm * 128 + m * 16 + (g << 2) + r;
        int col = n0 + wn * 64 + n * 16 + lr;
        float bias = (col < D_) ? bq[col] : ((col < 2 * D_) ? bk[col - D_] : bv[col - 2 * D_]);
        C[(size_t)row * D3_ + col] = f2bf(acc[m][n][r] + bias);
      }
}

// ======================================================================
// K11: fused gate/up GEMM — 8-PHASE (R10-proven) + XCD swizzle:
// grid 1D 352 = 8x44, cpx=44, mt=swz/44 (nt-fast: XCD k owns m-tile k).
// ======================================================================
__global__ __launch_bounds__(512, 1) void k_gemm_gup8p(const unsigned short* __restrict__ A,
    const unsigned short* __restrict__ Bg, const unsigned short* __restrict__ Bu,
    unsigned short* __restrict__ act) {
  alignas(16) __shared__ char L[2][65536];
  int tid = threadIdx.x;
  int lane = tid & 63, g = lane >> 4, lr = lane & 15;
  int wid = tid >> 6, wm = wid >> 1, wn = wid & 1;
  int swz = xcd_swz(blockIdx.x, 44);
  int m0 = (swz / 44) * 256, n0 = (swz % 44) * 128;
  f32x4 zero4 = {0.f, 0.f, 0.f, 0.f};
  f32x4 ag[4][4], au[4][4];
#pragma unroll
  for (int m = 0; m < 4; m++)
#pragma unroll
    for (int n = 0; n < 4; n++) { ag[m][n] = zero4; au[m][n] = zero4; }
  int arow = wm * 64 + lr;
  int brow = wn * 64 + lr;
  const int NI = D_ / 128;
  stage_u(A, D_, m0, 0, &L[0][0], tid);
  stage_u(A, D_, m0 + 128, 0, &L[0][16384], tid);
  stage_u(Bg, D_, n0, 0, &L[0][32768], tid);
  stage_u(Bu, D_, n0, 0, &L[0][49152], tid);
  stage_u(A, D_, m0, 64, &L[1][0], tid);
  asm volatile("s_waitcnt vmcnt(2)" ::: "memory");
  __builtin_amdgcn_s_barrier();
  for (int i = 0; i < NI; i++) {
    const char* B0 = &L[0][0];
    const char* B1 = &L[1][0];
    int k1 = i * 128 + 64;
    int k2 = i * 128 + 128;
    int k3 = i * 128 + 192;
    bool more = (i + 1 < NI);
    s16x8 af0[4], af1[4], bb[4];
    // ---- P1: gate kh0 (buf0); stage t1.A1 ----
#pragma unroll
    for (int q = 0; q < 4; q++) af0[q] = ldfrag128(B0, arow + q * 16, g * 16);
#pragma unroll
    for (int q = 0; q < 4; q++) bb[q] = ldfrag128(B0 + 32768, brow + q * 16, g * 16);
    stage_u(A, D_, m0 + 128, k1, &L[1][16384], tid);
    asm volatile("s_waitcnt vmcnt(4)" ::: "memory");
    PHASE_MFMA(af0, bb, ag);
    // ---- P2: up kh0 (buf0); stage t1.Bg ----
#pragma unroll
    for (int q = 0; q < 4; q++) bb[q] = ldfrag128(B0 + 49152, brow + q * 16, g * 16);
    stage_u(Bg, D_, n0, k1, &L[1][32768], tid);
    PHASE_MFMA(af0, bb, au);
    // ---- P3: gate kh1 (buf0); stage t1.Bu ----
#pragma unroll
    for (int q = 0; q < 4; q++) af1[q] = ldfrag128(B0, arow + q * 16, 64 + g * 16);
#pragma unroll
    for (int q = 0; q < 4; q++) bb[q] = ldfrag128(B0 + 32768, brow + q * 16, 64 + g * 16);
    stage_u(Bu, D_, n0, k1, &L[1][49152], tid);
    PHASE_MFMA(af1, bb, ag);
    // ---- P4: up kh1 (buf0); stage t2.A0 ----
#pragma unroll
    for (int q = 0; q < 4; q++) bb[q] = ldfrag128(B0 + 49152, brow + q * 16, 64 + g * 16);
    if (more) {
      stage_u(A, D_, m0, k2, &L[0][0], tid);
      asm volatile("s_waitcnt vmcnt(4)" ::: "memory");
    } else {
      asm volatile("s_waitcnt vmcnt(0)" ::: "memory");
    }
    PHASE_MFMA(af1, bb, au);
    // ---- P5: gate kh0 (buf1); stage t2.A1 ----
#pragma unroll
    for (int q = 0; q < 4; q++) af0[q] = ldfrag128(B1, arow + q * 16, g * 16);
#pragma unroll
    for (int q = 0; q < 4; q++) bb[q] = ldfrag128(B1 + 32768, brow + q * 16, g * 16);
    if (more) stage_u(A, D_, m0 + 128, k2, &L[0][16384], tid);
    asm volatile("s_waitcnt vmcnt(4)" ::: "memory");
    PHASE_MFMA(af0, bb, ag);
    // ---- P6: up kh0 (buf1); stage t2.Bg ----
#pragma unroll
    for (int q = 0; q < 4; q++) bb[q] = ldfrag128(B1 + 49152, brow + q * 16, g * 16);
    if (more) stage_u(Bg, D_, n0, k2, &L[0][32768], tid);
    PHASE_MFMA(af0, bb, au);
    // ---- P7: gate kh1 (buf1); stage t2.Bu ----
#pragma unroll
    for (int q = 0; q < 4; q++) af1[q] = ldfrag128(B1, arow + q * 16, 64 + g * 16);
#pragma unroll
    for (int q = 0; q < 4; q++) bb[q] = ldfrag128(B1 + 32768, brow + q * 16, 64 + g * 16);
    if (more) stage_u(Bu, D_, n0, k2, &L[0][49152], tid);
    PHASE_MFMA(af1, bb, ag);
    // ---- P8: up kh1 (buf1); stage t3.A0 ----
#pragma unroll
    for (int q = 0; q < 4; q++) bb[q] = ldfrag128(B1 + 49152, brow + q * 16, 64 + g * 16);
    if (more) stage_u(A, D_, m0, k3, &L[1][0], tid);
    asm volatile("s_waitcnt vmcnt(4)" ::: "memory");
    PHASE_MFMA(af1, bb, au);
  }
#pragma unroll
  for (int m = 0; m < 4; m++)
#pragma unroll
    for (int n = 0; n < 4; n++)
#pragma unroll
      for (int r = 0; r < 4; r++) {
        int row = m0 + wm * 64 + m * 16 + (g << 2) + r;
        int col = n0 + wn * 64 + n * 16 + lr;
        float gv = ag[m][n][r], uv = au[m][n][r];
        float si = gv / (1.f + __expf(-gv));
        act[(size_t)row * I_ + col] = f2bf(si * uv);
      }
}

// ---------- K9: wo GEMM + residual, 64x128 tile (R6 schedule) + XCD swizzle ----------
__global__ __launch_bounds__(256, 2) void k_gemm_wo64(const unsigned short* __restrict__ A,
    const unsigned short* __restrict__ Bt, const float* __restrict__ xres,
    float* __restrict__ x1) {
  alignas(16) __shared__ short As[2][64 * 32];
  alignas(16) __shared__ short Bs[2][128 * 32];
  int tid = threadIdx.x;
  int lane = tid & 63, g = lane >> 4, lr = lane & 15, wid = tid >> 6;
  int swz = xcd_swz(blockIdx.x, 64);   // nwg=512
  int m0 = (swz / 16) * 64, n0 = (swz % 16) * 128;
  f32x4 zero4 = {0.f, 0.f, 0.f, 0.f};
  f32x4 acc[4][2];
#pragma unroll
  for (int m = 0; m < 4; m++)
#pragma unroll
    for (int n = 0; n < 2; n++) acc[m][n] = zero4;
  const int nkt = D_ / 32;
  stage64r(A, D_, m0, 0, (char*)As[0], tid);
  stage128r(Bt, D_, n0, 0, (char*)Bs[0], tid);
  stage64r(A, D_, m0, 32, (char*)As[1], tid);
  stage128r(Bt, D_, n0, 32, (char*)Bs[1], tid);
  for (int t = 0; t < nkt; t++) {
    int b = t & 1;
    const char* Ab = (const char*)As[b];
    const char* Bb = (const char*)Bs[b];
    if (t + 1 < nkt) asm volatile("s_waitcnt vmcnt(3)" ::: "memory");
    else             asm volatile("s_waitcnt vmcnt(0)" ::: "memory");
    __builtin_amdgcn_s_barrier();
    s16x8 af[4], bf2[2];
#pragma unroll
    for (int i = 0; i < 4; i++) af[i] = ldfrag(Ab, i * 16 + lr, g);
#pragma unroll
    for (int j = 0; j < 2; j++) bf2[j] = ldfrag(Bb, wid * 32 + j * 16 + lr, g);
    asm volatile("s_waitcnt lgkmcnt(0)" ::: "memory");
    __builtin_amdgcn_s_barrier();
    if (t + 2 < nkt) {
      stage64r(A, D_, m0, (t + 2) * 32, (char*)As[b], tid);
      stage128r(Bt, D_, n0, (t + 2) * 32, (char*)Bs[b], tid);
    }
    __builtin_amdgcn_s_setprio(1);
#pragma unroll
    for (int m = 0; m < 4; m++)
#pragma unroll
      for (int n = 0; n < 2; n++) acc[m][n] = mfma_bf16(af[m], bf2[n], acc[m][n]);
    __builtin_amdgcn_s_setprio(0);
  }
#pragma unroll
  for (int m = 0; m < 4; m++)
#pragma unroll
    for (int n = 0; n < 2; n++)
#pragma unroll
      for (int r = 0; r < 4; r++) {
        int row = m0 + m * 16 + (g << 2) + r;
        int col = n0 + wid * 32 + n * 16 + lr;
        x1[(size_t)row * D_ + col] = acc[m][n][r] + xres[(size_t)row * D_ + col];
      }
}

// ---------- K12: down GEMM + residual + blend + scatter (R6) + XCD swizzle ----------
__global__ __launch_bounds__(256, 2) void k_gemm_down64(const unsigned short* __restrict__ A,
    const unsigned short* __restrict__ Bt, const float* __restrict__ x1,
    const float* __restrict__ x, const float* __restrict__ gate,
    const int* __restrict__ pos, float* __restrict__ out) {
  alignas(16) __shared__ short As[2][64 * 32];
  alignas(16) __shared__ short Bs[2][128 * 32];
  int tid = threadIdx.x;
  int lane = tid & 63, g = lane >> 4, lr = lane & 15, wid = tid >> 6;
  int swz = xcd_swz(blockIdx.x, 64);   // nwg=512
  int m0 = (swz / 16) * 64, n0 = (swz % 16) * 128;
  f32x4 zero4 = {0.f, 0.f, 0.f, 0.f};
  f32x4 acc[4][2];
#pragma unroll
  for (int m = 0; m < 4; m++)
#pragma unroll
    for (int n = 0; n < 2; n++) acc[m][n] = zero4;
  const int nkt = I_ / 32;
  stage64r(A, I_, m0, 0, (char*)As[0], tid);
  stage128r(Bt, I_, n0, 0, (char*)Bs[0], tid);
  stage64r(A, I_, m0, 32, (char*)As[1], tid);
  stage128r(Bt, I_, n0, 32, (char*)Bs[1], tid);
  for (int t = 0; t < nkt; t++) {
    int b = t & 1;
    const char* Ab = (const char*)As[b];
    const char* Bb = (const char*)Bs[b];
    if (t + 1 < nkt) asm volatile("s_waitcnt vmcnt(3)" ::: "memory");
    else             asm volatile("s_waitcnt vmcnt(0)" ::: "memory");
    __builtin_amdgcn_s_barrier();
    s16x8 af[4], bf2[2];
#pragma unroll
    for (int i = 0; i < 4; i++) af[i] = ldfrag(Ab, i * 16 + lr, g);
#pragma unroll
    for (int j = 0; j < 2; j++) bf2[j] = ldfrag(Bb, wid * 32 + j * 16 + lr, g);
    asm volatile("s_waitcnt lgkmcnt(0)" ::: "memory");
    __builtin_amdgcn_s_barrier();
    if (t + 2 < nkt) {
      stage64r(A, I_, m0, (t + 2) * 32, (char*)As[b], tid);
      stage128r(Bt, I_, n0, (t + 2) * 32, (char*)Bs[b], tid);
    }
    __builtin_amdgcn_s_setprio(1);
#pragma unroll
    for (int m = 0; m < 4; m++)
#pragma unroll
      for (int n = 0; n < 2; n++) acc[m][n] = mfma_bf16(af[m], bf2[n], acc[m][n]);
    __builtin_amdgcn_s_setprio(0);
  }
#pragma unroll
  for (int m = 0; m < 4; m++)
#pragma unroll
    for (int n = 0; n < 2; n++)
#pragma unroll
      for (int r = 0; r < 4; r++) {
        int srow = m0 + m * 16 + (g << 2) + r;
        int col = n0 + wid * 32 + n * 16 + lr;
        float proc = acc[m][n][r] + x1[(size_t)srow * D_ + col];
        float gt = gate[srow];
        float xv = x[(size_t)srow * D_ + col];
        int bb = srow >> 9;
        int p = pos[srow];
        out[((size_t)bb * T_ + p) * D_ + col] = gt * proc + (1.f - gt) * xv;
      }
}

// ---------- K7: RoPE + head relayout (q,k row-major per head; v transposed) ----------
__global__ __launch_bounds__(256) void k_rope(const unsigned short* __restrict__ qkv,
    const float* __restrict__ cosb, const float* __restrict__ sinb,
    unsigned short* __restrict__ qh, unsigned short* __restrict__ kh,
    unsigned short* __restrict__ vT) {
  int s0 = blockIdx.x * 64;
  int h = blockIdx.y;
  int t = threadIdx.x;
#pragma unroll
  for (int i = 0; i < 16; i++) {
    int flat = t + i * 256;
    int r = flat >> 6, dp = flat & 63;
    int s = s0 + r;
    float c = cosb[s * 64 + dp], sn = sinb[s * 64 + dp];
    const unsigned short* qrow = qkv + (size_t)s * D3_ + h * HD_;
    float q1 = bf2f(qrow[dp]), q2 = bf2f(qrow[dp + 64]);
    unsigned short* qdst = qh + ((size_t)h * S_ + s) * HD_;
    qdst[dp] = f2bf(q1 * c - q2 * sn);
    qdst[dp + 64] = f2bf(q2 * c + q1 * sn);
    const unsigned short* krow = qrow + D_;
    float k1 = bf2f(krow[dp]), k2 = bf2f(krow[dp + 64]);
    unsigned short* kdst = kh + ((size_t)h * S_ + s) * HD_;
    kdst[dp] = f2bf(k1 * c - k2 * sn);
    kdst[dp + 64] = f2bf(k2 * c + k1 * sn);
  }
  __shared__ unsigned short vt[128][66];
#pragma unroll
  for (int i = 0; i < 32; i++) {
    int flat = t + i * 256;
    int r = flat >> 7, d = flat & 127;
    vt[d][r] = qkv[(size_t)(s0 + r) * D3_ + 2 * D_ + h * HD_ + d];
  }
  __syncthreads();
#pragma unroll
  for (int i = 0; i < 32; i++) {
    int flat = t + i * 256;
    int d = flat >> 6, sc = flat & 63;
    vT[((size_t)h * HD_ + d) * S_ + s0 + sc] = vt[d][sc];
  }
}

// ======================================================================
// K8: flash attention (q-tile 64, LPT order, swizzled LDS, dbuf KV)
// ======================================================================
__device__ __forceinline__ void stage_kv(const unsigned short* __restrict__ kh,
                                         const unsigned short* __restrict__ vT,
                                         size_t hbase, int kt, char* KsB, char* VsB, int tid) {
#pragma unroll
  for (int c = 0; c < 4; c++) {
    int off = c * 4096 + tid * 16;
    int row = off >> 8;
    int cb = (off & 255) ^ ((row & 7) << 4);
    gl_lds16(kh + hbase + (size_t)(kt * 64 + row) * HD_ + (cb >> 1), KsB + off);
  }
#pragma unroll
  for (int c = 0; c < 4; c++) {
    int off = c * 4096 + tid * 16;
    int row = off >> 7;
    int cb = (off & 127) ^ ((row & 7) << 4);
    gl_lds16(vT + hbase + (size_t)row * S_ + kt * 64 + (cb >> 1), VsB + off);
  }
}

__global__ __launch_bounds__(256, 2) void k_attn(const unsigned short* __restrict__ qh,
                                                 const unsigned short* __restrict__ kh,
                                                 const unsigned short* __restrict__ vT,
                                                 unsigned short* __restrict__ ao) {
  alignas(16) __shared__ short Ks[2][64 * 128];
  alignas(16) __shared__ short Vs[2][128 * 64];
  alignas(16) __shared__ short Ps[4][16 * 64];
  int bidx = blockIdx.x;
  int head = bidx & 15;
  int slot = bidx >> 4;
  int qt = (slot < 16) ? (31 - slot) : (slot - 16);
  int q0 = qt * 64;
  int tid = threadIdx.x, w = tid >> 6, lane = tid & 63, g = lane >> 4, lr = lane & 15;
  size_t hbase = (size_t)head * S_ * HD_;
  int qw = q0 + w * 16;
  char* PsW = (char*)&Ps[w][0];
  s16x8 qf[4];
#pragma unroll
  for (int ks = 0; ks < 4; ks++)
    qf[ks] = *(const s16x8*)&qh[hbase + (size_t)(qw + lr) * HD_ + ks * 32 + g * 8];
  f32x4 o[8];
  f32x4 zero4 = {0.f, 0.f, 0.f, 0.f};
#pragma unroll
  for (int nf = 0; nf < 8; nf++) o[nf] = zero4;
  float m_i[4], l_i[4];
#pragma unroll
  for (int r = 0; r < 4; r++) { m_i[r] = -1e30f; l_i[r] = 0.f; }
  const float sc = 0.08838834764831843f;

  stage_kv(kh, vT, hbase, 0, (char*)Ks[0], (char*)Vs[0], tid);
  if (qt > 0) stage_kv(kh, vT, hbase, 1, (char*)Ks[1], (char*)Vs[1], tid);

  for (int kt = 0; kt <= qt; kt++) {
    int b = kt & 1;
    const char* KsB = (const char*)Ks[b];
    const char* VsB = (const char*)Vs[b];
    if (kt < qt) asm volatile("s_waitcnt vmcnt(8)" ::: "memory");
    else         asm volatile("s_waitcnt vmcnt(0)" ::: "memory");
    __builtin_amdgcn_s_barrier();
    f32x4 sacc[4];
#pragma unroll
    for (int nf = 0; nf < 4; nf++) sacc[nf] = zero4;
#pragma unroll
    for (int ks = 0; ks < 4; ks++) {
      s16x8 kf[4];
#pragma unroll
      for (int nf = 0; nf < 4; nf++) {
        int row = nf * 16 + lr;
        kf[nf] = *(const s16x8*)(KsB + row * 256 + (((ks << 6) + (g << 4)) ^ ((row & 7) << 4)));
      }
#pragma unroll
      for (int nf = 0; nf < 4; nf++) sacc[nf] = mfma_bf16(qf[ks], kf[nf], sacc[nf]);
    }
    bool diag = (kt == qt);
#pragma unroll
    for (int r = 0; r < 4; r++) {
      int prow = (g << 2) + r;
      int qrow = qw + prow;
      float pv[4];
      float mx = -1e30f;
#pragma unroll
      for (int nf = 0; nf < 4; nf++) {
        float vv = sacc[nf][r] * sc;
        if (diag) {
          int kc = kt * 64 + nf * 16 + lr;
          vv = (kc <= qrow) ? vv : -1e30f;
        }
        pv[nf] = vv;
        mx = fmaxf(mx, vv);
      }
#pragma unroll
      for (int d = 1; d < 16; d <<= 1) mx = fmaxf(mx, __shfl_xor(mx, d));
      float mold = m_i[r], mnew = fmaxf(mold, mx);
      float corr = __expf(mold - mnew);
      float ssum = 0.f;
#pragma unroll
      for (int nf = 0; nf < 4; nf++) {
        float pe = __expf(pv[nf] - mnew);
        int cb = ((nf * 16 + lr) << 1) ^ ((prow & 7) << 4);
        *(unsigned short*)(PsW + prow * 128 + cb) = f2bf(pe);
        ssum += pe;
      }
#pragma unroll
      for (int d = 1; d < 16; d <<= 1) ssum += __shfl_xor(ssum, d);
      l_i[r] = l_i[r] * corr + ssum;
      m_i[r] = mnew;
#pragma unroll
      for (int nf = 0; nf < 8; nf++) o[nf][r] *= corr;
    }
    s16x8 pa[2];
#pragma unroll
    for (int ks = 0; ks < 2; ks++)
      pa[ks] = *(const s16x8*)(PsW + lr * 128 + (((ks << 6) + (g << 4)) ^ ((lr & 7) << 4)));
#pragma unroll
    for (int nf = 0; nf < 8; nf++) {
#pragma unroll
      for (int ks = 0; ks < 2; ks++) {
        int row = nf * 16 + lr;
        s16x8 vb = *(const s16x8*)(VsB + row * 128 + (((ks << 6) + (g << 4)) ^ ((row & 7) << 4)));
        o[nf] = mfma_bf16(pa[ks], vb, o[nf]);
      }
    }
    asm volatile("s_waitcnt lgkmcnt(0)" ::: "memory");
    __builtin_amdgcn_s_barrier();
    if (kt + 2 <= qt)
      stage_kv(kh, vT, hbase, kt + 2, (char*)Ks[b], (char*)Vs[b], tid);
  }
#pragma unroll
  for (int nf = 0; nf < 8; nf++)
#pragma unroll
    for (int r = 0; r < 4; r++) {
      int row = qw + (g << 2) + r;
      int col = head * HD_ + nf * 16 + lr;
      ao[(size_t)row * D_ + col] = f2bf(o[nf][r] / l_i[r]);
    }
}

// ---------- K10: RMS2 ----------
__global__ __launch_bounds__(256) void k_rms2(const float* __restrict__ x1,
                                              const float* __restrict__ ln2w,
                                              unsigned short* __restrict__ xn2) {
  int s = blockIdx.x, t = threadIdx.x;
  const float* src = x1 + (size_t)s * D_;
  float v[8];
  float ss = 0.f;
#pragma unroll
  for (int i = 0; i < 8; i++) { v[i] = src[t + i * 256]; ss += v[i] * v[i]; }
  __shared__ float red[4];
#pragma unroll
  for (int d = 32; d; d >>= 1) ss += __shfl_xor(ss, d);
  if ((t & 63) == 0) red[t >> 6] = ss;
  __syncthreads();
  ss = red[0] + red[1] + red[2] + red[3];
  float scale = rsqrtf(ss / (float)D_ + 1e-6f);
  unsigned short* dst = xn2 + (size_t)s * D_;
#pragma unroll
  for (int i = 0; i < 8; i++) {
    int c = t + i * 256;
    dst[c] = f2bf(v[i] * scale * ln2w[c]);
  }
}

extern "C" void kernel_launch(void* const* d_in, const int* in_sizes, int n_in,
                              void* d_out, int out_size, void* d_ws, size_t ws_size,
                              hipStream_t stream) {
  (void)in_sizes; (void)n_in; (void)out_size; (void)ws_size;
  const float* hidden = (const float*)d_in[0];
  const float* router_w = (const float*)d_in[1];
  const float* router_b = (const float*)d_in[2];
  const float* ln1w = (const float*)d_in[3];
  const float* ln2w = (const float*)d_in[4];
  const float* wq = (const float*)d_in[5];
  const float* bq = (const float*)d_in[6];
  const float* wk = (const float*)d_in[7];
  const float* bk = (const float*)d_in[8];
  const float* wv = (const float*)d_in[9];
  const float* bv = (const float*)d_in[10];
  const float* wo = (const float*)d_in[11];
  const float* wg = (const float*)d_in[12];
  const float* wu = (const float*)d_in[13];
  const float* wd = (const float*)d_in[14];
  float* out = (float*)d_out;

  char* ws = (char*)d_ws;
  size_t off = 0;
  auto alloc = [&](size_t bytes) {
    char* p = ws + off;
    off += (bytes + 255) & ~(size_t)255;
    return p;
  };
  unsigned short* wqkvT = (unsigned short*)alloc(3ull * D_ * D_ * 2);
  unsigned short* woT = (unsigned short*)alloc((size_t)D_ * D_ * 2);
  unsigned short* wgT = (unsigned short*)alloc((size_t)I_ * D_ * 2);
  unsigned short* wuT = (unsigned short*)alloc((size_t)I_ * D_ * 2);
  unsigned short* wdT = (unsigned short*)alloc((size_t)D_ * I_ * 2);
  float* scores = (float*)alloc((size_t)B_ * T_ * 4);
  int* pos = (int*)alloc((size_t)S_ * 4);
  float* gate = (float*)alloc((size_t)S_ * 4);
  float* x = (float*)alloc((size_t)S_ * D_ * 4);
  float* x1 = (float*)alloc((size_t)S_ * D_ * 4);
  unsigned short* xn = (unsigned short*)alloc((size_t)S_ * D_ * 2);  // reused as x1n
  float* cosb = (float*)alloc((size_t)S_ * 64 * 4);
  float* sinb = (float*)alloc((size_t)S_ * 64 * 4);
  unsigned short* qkv = (unsigned short*)alloc((size_t)S_ * D3_ * 2);  // reused as act
  unsigned short* qh = (unsigned short*)alloc((size_t)H_ * S_ * HD_ * 2);
  unsigned short* kh = (unsigned short*)alloc((size_t)H_ * S_ * HD_ * 2);
  unsigned short* vT = (unsigned short*)alloc((size_t)H_ * S_ * HD_ * 2);
  unsigned short* ao = (unsigned short*)alloc((size_t)S_ * D_ * 2);

  k_copy_scores<<<B_ * T_, 256, 0, stream>>>((const float4*)hidden, (float4*)out,
                                             (const float4*)router_w, router_b, scores);

  k_transpose4<<<dim3(D_ / 32, D_ / 32, 4), 256, 0, stream>>>(
      wq, wk, wv, wo, wqkvT, wqkvT + (size_t)D_ * D_, wqkvT + 2ull * D_ * D_, woT, D_, D_);
  k_transpose2<<<dim3(I_ / 32, D_ / 32, 2), 256, 0, stream>>>(wg, wu, wgT, wuT, D_, I_);
  k_transpose<<<dim3(D_ / 32, I_ / 32), 256, 0, stream>>>(wd, wdT, I_, D_);

  k_topk<<<B_, 1024, 0, stream>>>(scores, pos);
  k_gather<<<S_, 256, 0, stream>>>(hidden, pos, scores, ln1w, x, xn, gate, cosb, sinb);

  k_gemm_qkv8p<<<192, 512, 0, stream>>>(xn, wqkvT, qkv, bq, bk, bv);
  k_rope<<<dim3(S_ / 64, H_), 256, 0, stream>>>(qkv, cosb, sinb, qh, kh, vT);
  k_attn<<<32 * H_, 256, 0, stream>>>(qh, kh, vT, ao);
  k_gemm_wo64<<<512, 256, 0, stream>>>(ao, woT, x, x1);
  k_rms2<<<S_, 256, 0, stream>>>(x1, ln2w, xn);
  k_gemm_gup8p<<<352, 512, 0, stream>>>(xn, wgT, wuT, qkv);
  k_gemm_down64<<<512, 256, 0, stream>>>(qkv, wdT, x1, x, gate, pos, out);
}

// Round 13
// 498.441 us; speedup vs baseline: 1.2418x; 1.0233x over previous
//
#include <hip/hip_runtime.h>
#include <stdint.h>

#define B_ 4
#define T_ 2048
#define D_ 2048
#define H_ 16
#define HD_ 128
#define I_ 5632
#define K_ 512
#define S_ 2048
#define D3_ (3 * D_)

typedef float f32x4 __attribute__((ext_vector_type(4)));
typedef short s16x8 __attribute__((ext_vector_type(8)));
typedef __bf16 bf16x8 __attribute__((ext_vector_type(8)));

// ---------- mfma wrapper robust to builtin operand type (short8 vs bf16x8) ----------
template <typename V>
__device__ __forceinline__ auto mfma_try(V a, V b, f32x4 c, int)
    -> decltype(__builtin_amdgcn_mfma_f32_16x16x32_bf16(a, b, c, 0, 0, 0)) {
  return __builtin_amdgcn_mfma_f32_16x16x32_bf16(a, b, c, 0, 0, 0);
}
template <typename V>
__device__ __forceinline__ f32x4 mfma_try(V a, V b, f32x4 c, long) {
  return __builtin_amdgcn_mfma_f32_16x16x32_bf16(
      __builtin_bit_cast(bf16x8, a), __builtin_bit_cast(bf16x8, b), c, 0, 0, 0);
}
__device__ __forceinline__ f32x4 mfma_bf16(s16x8 a, s16x8 b, f32x4 c) {
  return mfma_try(a, b, c, 0);
}

__device__ __forceinline__ void gl_lds16(const void* g, void* l) {
  __builtin_amdgcn_global_load_lds((const __attribute__((address_space(1))) void*)g,
                                   (__attribute__((address_space(3))) void*)l, 16, 0, 0);
}

__device__ __forceinline__ unsigned short f2bf(float f) {
  unsigned u = __float_as_uint(f);
  u += 0x7FFFu + ((u >> 16) & 1);
  return (unsigned short)(u >> 16);
}
__device__ __forceinline__ float bf2f(unsigned short s) {
  return __uint_as_float(((unsigned)s) << 16);
}

// XCD-aware bijective chunked swizzle (T1). nwg must be %8==0.
__device__ __forceinline__ int xcd_swz(int bid, int cpx) {
  return (bid & 7) * cpx + (bid >> 3);
}

// ---------- K1: copy hidden -> out, fused with router scores ----------
__global__ __launch_bounds__(256) void k_copy_scores(const float4* __restrict__ hid,
                                                     float4* __restrict__ dst,
                                                     const float4* __restrict__ rw,
                                                     const float* __restrict__ rb,
                                                     float* __restrict__ scores) {
  int row = blockIdx.x, t = threadIdx.x;
  const float4* hr = hid + (size_t)row * (D_ / 4);
  float4* dr = dst + (size_t)row * (D_ / 4);
  float acc = 0.f;
#pragma unroll
  for (int i = 0; i < 2; i++) {
    float4 v = hr[t + i * 256];
    dr[t + i * 256] = v;
    float4 w = rw[t + i * 256];
    acc += v.x * w.x + v.y * w.y + v.z * w.z + v.w * w.w;
  }
#pragma unroll
  for (int d = 32; d; d >>= 1) acc += __shfl_xor(acc, d);
  __shared__ float red[4];
  if ((t & 63) == 0) red[t >> 6] = acc;
  __syncthreads();
  if (t == 0) scores[row] = red[0] + red[1] + red[2] + red[3] + rb[0];
}

// ---------- K3: exact top-k (bitonic, matches jax.lax.top_k tie-break) ----------
__global__ __launch_bounds__(1024) void k_topk(const float* __restrict__ scores,
                                               int* __restrict__ pos) {
  __shared__ unsigned long long keys[T_];
  __shared__ int sidx[K_];
  int b = blockIdx.x, t = threadIdx.x;
  for (int i = t; i < T_; i += 1024) {
    unsigned u = __float_as_uint(scores[b * T_ + i]);
    u = (u & 0x80000000u) ? ~u : (u | 0x80000000u);
    keys[i] = ((unsigned long long)u << 32) | (unsigned)(~(unsigned)i);
  }
  __syncthreads();
  for (int k = 2; k <= T_; k <<= 1)
    for (int j = k >> 1; j > 0; j >>= 1) {
      for (int i = t; i < T_; i += 1024) {
        int l = i ^ j;
        if (l > i) {
          unsigned long long a = keys[i], c = keys[l];
          bool desc = ((i & k) == 0);
          if (desc ? (a < c) : (a > c)) { keys[i] = c; keys[l] = a; }
        }
      }
      __syncthreads();
    }
  if (t < K_) sidx[t] = (int)(~(unsigned)(keys[t] & 0xFFFFFFFFull));
  __syncthreads();
  for (int k = 2; k <= K_; k <<= 1)
    for (int j = k >> 1; j > 0; j >>= 1) {
      if (t < K_) {
        int i = t, l = i ^ j;
        if (l > i && l < K_) {
          int a = sidx[i], c = sidx[l];
          bool asc = ((i & k) == 0);
          if (asc ? (a > c) : (a < c)) { sidx[i] = c; sidx[l] = a; }
        }
      }
      __syncthreads();
    }
  if (t < K_) pos[b * K_ + t] = sidx[t];
}

// ---------- K4: gather + RMS1 + gate + rope tables ----------
__global__ __launch_bounds__(256) void k_gather(const float* __restrict__ hidden,
    const int* __restrict__ pos, const float* __restrict__ scores,
    const float* __restrict__ ln1w, float* __restrict__ x,
    unsigned short* __restrict__ xn, float* __restrict__ gate,
    float* __restrict__ cosb, float* __restrict__ sinb) {
  int s = blockIdx.x, t = threadIdx.x;
  int b = s >> 9, p = pos[s];
  const float* src = hidden + ((size_t)b * T_ + p) * D_;
  float v[8];
  float ss = 0.f;
#pragma unroll
  for (int i = 0; i < 8; i++) { v[i] = src[t + i * 256]; ss += v[i] * v[i]; }
  __shared__ float red[4];
#pragma unroll
  for (int d = 32; d; d >>= 1) ss += __shfl_xor(ss, d);
  if ((t & 63) == 0) red[t >> 6] = ss;
  __syncthreads();
  ss = red[0] + red[1] + red[2] + red[3];
  float scale = rsqrtf(ss / (float)D_ + 1e-6f);
  float* xd = x + (size_t)s * D_;
  unsigned short* xnd = xn + (size_t)s * D_;
#pragma unroll
  for (int i = 0; i < 8; i++) {
    int c = t + i * 256;
    xd[c] = v[i];
    xnd[c] = f2bf(v[i] * scale * ln1w[c]);
  }
  if (t == 0) gate[s] = 1.f / (1.f + expf(-scores[b * T_ + p]));
  if (t < 64) {
    float invf = powf(10000.0f, -(float)t / 64.0f);
    float f = (float)p * invf;
    cosb[s * 64 + t] = cosf(f);
    sinb[s * 64 + t] = sinf(f);
  }
}

// ---------- K5: transpose + f32->bf16, batched via z (ushort4 writes) ----------
__device__ __forceinline__ void transpose_body(const float* __restrict__ src,
                                               unsigned short* __restrict__ dst,
                                               int R, int C) {
  __shared__ float tile[32][33];
  int tx = threadIdx.x & 31, ty = threadIdx.x >> 5;
  int c0 = blockIdx.x * 32, r0 = blockIdx.y * 32;
#pragma unroll
  for (int i = 0; i < 4; i++) {
    int r = ty + i * 8;
    tile[r][tx] = src[(size_t)(r0 + r) * C + c0 + tx];
  }
  __syncthreads();
  int drow = threadIdx.x >> 3;
  int dc4 = (threadIdx.x & 7) * 4;
  ushort4 v;
  v.x = f2bf(tile[dc4 + 0][drow]);
  v.y = f2bf(tile[dc4 + 1][drow]);
  v.z = f2bf(tile[dc4 + 2][drow]);
  v.w = f2bf(tile[dc4 + 3][drow]);
  *(ushort4*)&dst[(size_t)(c0 + drow) * R + r0 + dc4] = v;
}
__global__ __launch_bounds__(256) void k_transpose(const float* __restrict__ src,
                                                   unsigned short* __restrict__ dst,
                                                   int R, int C) {
  transpose_body(src, dst, R, C);
}
__global__ __launch_bounds__(256) void k_transpose4(const float* s0, const float* s1,
                                                    const float* s2, const float* s3,
                                                    unsigned short* d0, unsigned short* d1,
                                                    unsigned short* d2, unsigned short* d3,
                                                    int R, int C) {
  int z = blockIdx.z;
  const float* src = (z == 0) ? s0 : (z == 1) ? s1 : (z == 2) ? s2 : s3;
  unsigned short* dst = (z == 0) ? d0 : (z == 1) ? d1 : (z == 2) ? d2 : d3;
  transpose_body(src, dst, R, C);
}
__global__ __launch_bounds__(256) void k_transpose2(const float* s0, const float* s1,
                                                    unsigned short* d0, unsigned short* d1,
                                                    int R, int C) {
  int z = blockIdx.z;
  transpose_body(z ? s1 : s0, z ? d1 : d0, R, C);
}

// ======================================================================
// Shared LDS pieces: 128B rows, swizzle involution byte ^= ((row&7)<<4),
// applied to the GLOBAL source (gl_lds dest linear) and to the read.
// ======================================================================
__device__ __forceinline__ void stage_u(const unsigned short* __restrict__ g, int ldK,
                                        int grow0, int k0, char* ldsbase, int tid) {
#pragma unroll
  for (int c = 0; c < 2; c++) {
    int off = c * 8192 + tid * 16;       // 16KB unit = 128 rows x 128B (512 thr)
    int row = off >> 7;
    int cb = (off & 127) ^ ((row & 7) << 4);
    gl_lds16(g + (size_t)(grow0 + row) * ldK + k0 + (cb >> 1), ldsbase + off);
  }
}
// 256-thread variants (BK=64 2-phase kernels)
__device__ __forceinline__ void stageU64(const unsigned short* __restrict__ g, int ldK,
                                         int grow0, int k0, char* ldsbase, int tid) {
#pragma unroll
  for (int c = 0; c < 2; c++) {
    int off = c * 4096 + tid * 16;       // 8KB = 64 rows x 128B
    int row = off >> 7;
    int cb = (off & 127) ^ ((row & 7) << 4);
    gl_lds16(g + (size_t)(grow0 + row) * ldK + k0 + (cb >> 1), ldsbase + off);
  }
}
__device__ __forceinline__ void stageU128(const unsigned short* __restrict__ g, int ldK,
                                          int grow0, int k0, char* ldsbase, int tid) {
#pragma unroll
  for (int c = 0; c < 4; c++) {
    int off = c * 4096 + tid * 16;       // 16KB = 128 rows x 128B
    int row = off >> 7;
    int cb = (off & 127) ^ ((row & 7) << 4);
    gl_lds16(g + (size_t)(grow0 + row) * ldK + k0 + (cb >> 1), ldsbase + off);
  }
}
__device__ __forceinline__ s16x8 ldfrag128(const char* base, int row, int byteoff) {
  return *(const s16x8*)(base + row * 128 + (byteoff ^ ((row & 7) << 4)));
}

#define PHASE_MFMA(AF, BB, ACC)                                     \
  __builtin_amdgcn_s_barrier();                                     \
  asm volatile("s_waitcnt lgkmcnt(0)" ::: "memory");                \
  __builtin_amdgcn_sched_barrier(0);                                \
  __builtin_amdgcn_s_setprio(1);                                    \
  _Pragma("unroll") for (int m = 0; m < 4; m++)                     \
    _Pragma("unroll") for (int n = 0; n < 4; n++)                   \
      ACC[m][n] = mfma_bf16(AF[m], BB[n], ACC[m][n]);               \
  __builtin_amdgcn_s_setprio(0);                                    \
  __builtin_amdgcn_s_barrier();

// ======================================================================
// K6: fused QKV GEMM — 8-PHASE, 256x256 tile (R11/R12-proven)
// ======================================================================
__global__ __launch_bounds__(512, 1) void k_gemm_qkv8p(const unsigned short* __restrict__ A,
    const unsigned short* __restrict__ Bt, unsigned short* __restrict__ C,
    const float* __restrict__ bq, const float* __restrict__ bk,
    const float* __restrict__ bv) {
  alignas(16) __shared__ char L[2][65536];
  int tid = threadIdx.x;
  int lane = tid & 63, g = lane >> 4, lr = lane & 15;
  int wid = tid >> 6, wm = wid >> 2, wn = wid & 3;
  int swz = xcd_swz(blockIdx.x, 24);
  int m0 = (swz / 24) * 256, n0 = (swz % 24) * 256;
  f32x4 zero4 = {0.f, 0.f, 0.f, 0.f};
  f32x4 acc[8][4];
#pragma unroll
  for (int m = 0; m < 8; m++)
#pragma unroll
    for (int n = 0; n < 4; n++) acc[m][n] = zero4;
  f32x4(*accLo)[4] = &acc[0];
  f32x4(*accHi)[4] = &acc[4];
  int arow = wm * 128 + lr;
  int brow = wn * 64 + lr;
  const int NI = D_ / 128;
  stage_u(A, D_, m0, 0, &L[0][0], tid);
  stage_u(A, D_, m0 + 128, 0, &L[0][16384], tid);
  stage_u(Bt, D_, n0, 0, &L[0][32768], tid);
  stage_u(Bt, D_, n0 + 128, 0, &L[0][49152], tid);
  stage_u(A, D_, m0, 64, &L[1][0], tid);
  asm volatile("s_waitcnt vmcnt(2)" ::: "memory");
  __builtin_amdgcn_s_barrier();
  for (int i = 0; i < NI; i++) {
    const char* Buf0 = &L[0][0];
    const char* Buf1 = &L[1][0];
    int k1 = i * 128 + 64, k2 = i * 128 + 128, k3 = i * 128 + 192;
    bool more = (i + 1 < NI);
    s16x8 af[8], bf[4];
#pragma unroll
    for (int q = 0; q < 8; q++) af[q] = ldfrag128(Buf0, arow + q * 16, g * 16);
#pragma unroll
    for (int q = 0; q < 4; q++) bf[q] = ldfrag128(Buf0 + 32768, brow + q * 16, g * 16);
    stage_u(A, D_, m0 + 128, k1, &L[1][16384], tid);
    PHASE_MFMA(af, bf, accLo);
    stage_u(Bt, D_, n0, k1, &L[1][32768], tid);
    PHASE_MFMA((af + 4), bf, accHi);
#pragma unroll
    for (int q = 0; q < 8; q++) af[q] = ldfrag128(Buf0, arow + q * 16, 64 + g * 16);
#pragma unroll
    for (int q = 0; q < 4; q++) bf[q] = ldfrag128(Buf0 + 32768, brow + q * 16, 64 + g * 16);
    stage_u(Bt, D_, n0 + 128, k1, &L[1][49152], tid);
    PHASE_MFMA(af, bf, accLo);
    if (more) {
      stage_u(A, D_, m0, k2, &L[0][0], tid);
      asm volatile("s_waitcnt vmcnt(2)" ::: "memory");
    } else {
      asm volatile("s_waitcnt vmcnt(0)" ::: "memory");
    }
    PHASE_MFMA((af + 4), bf, accHi);
#pragma unroll
    for (int q = 0; q < 8; q++) af[q] = ldfrag128(Buf1, arow + q * 16, g * 16);
#pragma unroll
    for (int q = 0; q < 4; q++) bf[q] = ldfrag128(Buf1 + 32768, brow + q * 16, g * 16);
    if (more) stage_u(A, D_, m0 + 128, k2, &L[0][16384], tid);
    PHASE_MFMA(af, bf, accLo);
    if (more) stage_u(Bt, D_, n0, k2, &L[0][32768], tid);
    PHASE_MFMA((af + 4), bf, accHi);
#pragma unroll
    for (int q = 0; q < 8; q++) af[q] = ldfrag128(Buf1, arow + q * 16, 64 + g * 16);
#pragma unroll
    for (int q = 0; q < 4; q++) bf[q] = ldfrag128(Buf1 + 32768, brow + q * 16, 64 + g * 16);
    if (more) stage_u(Bt, D_, n0 + 128, k2, &L[0][49152], tid);
    PHASE_MFMA(af, bf, accLo);
    if (more) {
      stage_u(A, D_, m0, k3, &L[1][0], tid);
      asm volatile("s_waitcnt vmcnt(2)" ::: "memory");
    }
    PHASE_MFMA((af + 4), bf, accHi);
  }
#pragma unroll
  for (int m = 0; m < 8; m++)
#pragma unroll
    for (int n = 0; n < 4; n++)
#pragma unroll
      for (int r = 0; r < 4; r++) {
        int row = m0 + wm * 128 + m * 16 + (g << 2) + r;
        int col = n0 + wn * 64 + n * 16 + lr;
        float bias = (col < D_) ? bq[col] : ((col < 2 * D_) ? bk[col - D_] : bv[col - 2 * D_]);
        C[(size_t)row * D3_ + col] = f2bf(acc[m][n][r] + bias);
      }
}

// ======================================================================
// K11: fused gate/up GEMM — 8-PHASE (R10-proven) + XCD swizzle
// ======================================================================
__global__ __launch_bounds__(512, 1) void k_gemm_gup8p(const unsigned short* __restrict__ A,
    const unsigned short* __restrict__ Bg, const unsigned short* __restrict__ Bu,
    unsigned short* __restrict__ act) {
  alignas(16) __shared__ char L[2][65536];
  int tid = threadIdx.x;
  int lane = tid & 63, g = lane >> 4, lr = lane & 15;
  int wid = tid >> 6, wm = wid >> 1, wn = wid & 1;
  int swz = xcd_swz(blockIdx.x, 44);
  int m0 = (swz / 44) * 256, n0 = (swz % 44) * 128;
  f32x4 zero4 = {0.f, 0.f, 0.f, 0.f};
  f32x4 ag[4][4], au[4][4];
#pragma unroll
  for (int m = 0; m < 4; m++)
#pragma unroll
    for (int n = 0; n < 4; n++) { ag[m][n] = zero4; au[m][n] = zero4; }
  int arow = wm * 64 + lr;
  int brow = wn * 64 + lr;
  const int NI = D_ / 128;
  stage_u(A, D_, m0, 0, &L[0][0], tid);
  stage_u(A, D_, m0 + 128, 0, &L[0][16384], tid);
  stage_u(Bg, D_, n0, 0, &L[0][32768], tid);
  stage_u(Bu, D_, n0, 0, &L[0][49152], tid);
  stage_u(A, D_, m0, 64, &L[1][0], tid);
  asm volatile("s_waitcnt vmcnt(2)" ::: "memory");
  __builtin_amdgcn_s_barrier();
  for (int i = 0; i < NI; i++) {
    const char* B0 = &L[0][0];
    const char* B1 = &L[1][0];
    int k1 = i * 128 + 64;
    int k2 = i * 128 + 128;
    int k3 = i * 128 + 192;
    bool more = (i + 1 < NI);
    s16x8 af0[4], af1[4], bb[4];
#pragma unroll
    for (int q = 0; q < 4; q++) af0[q] = ldfrag128(B0, arow + q * 16, g * 16);
#pragma unroll
    for (int q = 0; q < 4; q++) bb[q] = ldfrag128(B0 + 32768, brow + q * 16, g * 16);
    stage_u(A, D_, m0 + 128, k1, &L[1][16384], tid);
    asm volatile("s_waitcnt vmcnt(4)" ::: "memory");
    PHASE_MFMA(af0, bb, ag);
#pragma unroll
    for (int q = 0; q < 4; q++) bb[q] = ldfrag128(B0 + 49152, brow + q * 16, g * 16);
    stage_u(Bg, D_, n0, k1, &L[1][32768], tid);
    PHASE_MFMA(af0, bb, au);
#pragma unroll
    for (int q = 0; q < 4; q++) af1[q] = ldfrag128(B0, arow + q * 16, 64 + g * 16);
#pragma unroll
    for (int q = 0; q < 4; q++) bb[q] = ldfrag128(B0 + 32768, brow + q * 16, 64 + g * 16);
    stage_u(Bu, D_, n0, k1, &L[1][49152], tid);
    PHASE_MFMA(af1, bb, ag);
#pragma unroll
    for (int q = 0; q < 4; q++) bb[q] = ldfrag128(B0 + 49152, brow + q * 16, 64 + g * 16);
    if (more) {
      stage_u(A, D_, m0, k2, &L[0][0], tid);
      asm volatile("s_waitcnt vmcnt(4)" ::: "memory");
    } else {
      asm volatile("s_waitcnt vmcnt(0)" ::: "memory");
    }
    PHASE_MFMA(af1, bb, au);
#pragma unroll
    for (int q = 0; q < 4; q++) af0[q] = ldfrag128(B1, arow + q * 16, g * 16);
#pragma unroll
    for (int q = 0; q < 4; q++) bb[q] = ldfrag128(B1 + 32768, brow + q * 16, g * 16);
    if (more) stage_u(A, D_, m0 + 128, k2, &L[0][16384], tid);
    asm volatile("s_waitcnt vmcnt(4)" ::: "memory");
    PHASE_MFMA(af0, bb, ag);
#pragma unroll
    for (int q = 0; q < 4; q++) bb[q] = ldfrag128(B1 + 49152, brow + q * 16, g * 16);
    if (more) stage_u(Bg, D_, n0, k2, &L[0][32768], tid);
    PHASE_MFMA(af0, bb, au);
#pragma unroll
    for (int q = 0; q < 4; q++) af1[q] = ldfrag128(B1, arow + q * 16, 64 + g * 16);
#pragma unroll
    for (int q = 0; q < 4; q++) bb[q] = ldfrag128(B1 + 32768, brow + q * 16, 64 + g * 16);
    if (more) stage_u(Bu, D_, n0, k2, &L[0][49152], tid);
    PHASE_MFMA(af1, bb, ag);
#pragma unroll
    for (int q = 0; q < 4; q++) bb[q] = ldfrag128(B1 + 49152, brow + q * 16, 64 + g * 16);
    if (more) stage_u(A, D_, m0, k3, &L[1][0], tid);
    asm volatile("s_waitcnt vmcnt(4)" ::: "memory");
    PHASE_MFMA(af1, bb, au);
  }
#pragma unroll
  for (int m = 0; m < 4; m++)
#pragma unroll
    for (int n = 0; n < 4; n++)
#pragma unroll
      for (int r = 0; r < 4; r++) {
        int row = m0 + wm * 64 + m * 16 + (g << 2) + r;
        int col = n0 + wn * 64 + n * 16 + lr;
        float gv = ag[m][n][r], uv = au[m][n][r];
        float si = gv / (1.f + __expf(-gv));
        act[(size_t)row * I_ + col] = f2bf(si * uv);
      }
}

// ======================================================================
// K9: wo GEMM + residual — 64x128 tile, BK=64 2-phase (fewer barriers).
// LDS/buf: A 64x128B (8KB) + B 128x128B (16KB) = 24KB; x2 = 48KB -> 2/CU.
// Loads/thread/tile = 2(A)+4(B) = 6 -> vmcnt(6); vmcnt(0) last tile.
// Schedule (R6-proven order): vmcnt -> bar -> ds_read -> lgkm0 -> bar
//   -> stage(t+2) -> setprio MFMA.
// ======================================================================
__global__ __launch_bounds__(256, 2) void k_gemm_wo64(const unsigned short* __restrict__ A,
    const unsigned short* __restrict__ Bt, const float* __restrict__ xres,
    float* __restrict__ x1) {
  alignas(16) __shared__ char As[2][8192];
  alignas(16) __shared__ char Bs[2][16384];
  int tid = threadIdx.x;
  int lane = tid & 63, g = lane >> 4, lr = lane & 15, wid = tid >> 6;
  int swz = xcd_swz(blockIdx.x, 64);   // nwg=512
  int m0 = (swz / 16) * 64, n0 = (swz % 16) * 128;
  f32x4 zero4 = {0.f, 0.f, 0.f, 0.f};
  f32x4 acc[4][2];
#pragma unroll
  for (int m = 0; m < 4; m++)
#pragma unroll
    for (int n = 0; n < 2; n++) acc[m][n] = zero4;
  const int nkt = D_ / 64;
  stageU64(A, D_, m0, 0, As[0], tid);
  stageU128(Bt, D_, n0, 0, Bs[0], tid);
  stageU64(A, D_, m0, 64, As[1], tid);
  stageU128(Bt, D_, n0, 64, Bs[1], tid);
  for (int t = 0; t < nkt; t++) {
    int b = t & 1;
    const char* Ab = As[b];
    const char* Bb = Bs[b];
    if (t + 1 < nkt) asm volatile("s_waitcnt vmcnt(6)" ::: "memory");
    else             asm volatile("s_waitcnt vmcnt(0)" ::: "memory");
    __builtin_amdgcn_s_barrier();
    s16x8 af[2][4], bf[2][2];
#pragma unroll
    for (int k = 0; k < 2; k++) {
#pragma unroll
      for (int i = 0; i < 4; i++) af[k][i] = ldfrag128(Ab, i * 16 + lr, k * 64 + g * 16);
#pragma unroll
      for (int j = 0; j < 2; j++) bf[k][j] = ldfrag128(Bb, wid * 32 + j * 16 + lr, k * 64 + g * 16);
    }
    asm volatile("s_waitcnt lgkmcnt(0)" ::: "memory");
    __builtin_amdgcn_s_barrier();
    if (t + 2 < nkt) {
      stageU64(A, D_, m0, (t + 2) * 64, As[b], tid);
      stageU128(Bt, D_, n0, (t + 2) * 64, Bs[b], tid);
    }
    __builtin_amdgcn_s_setprio(1);
#pragma unroll
    for (int k = 0; k < 2; k++)
#pragma unroll
      for (int m = 0; m < 4; m++)
#pragma unroll
        for (int n = 0; n < 2; n++) acc[m][n] = mfma_bf16(af[k][m], bf[k][n], acc[m][n]);
    __builtin_amdgcn_s_setprio(0);
  }
#pragma unroll
  for (int m = 0; m < 4; m++)
#pragma unroll
    for (int n = 0; n < 2; n++)
#pragma unroll
      for (int r = 0; r < 4; r++) {
        int row = m0 + m * 16 + (g << 2) + r;
        int col = n0 + wid * 32 + n * 16 + lr;
        x1[(size_t)row * D_ + col] = acc[m][n][r] + xres[(size_t)row * D_ + col];
      }
}

// ======================================================================
// K12: down GEMM + residual + blend + scatter — 64x128, BK=64 2-phase
// ======================================================================
__global__ __launch_bounds__(256, 2) void k_gemm_down64(const unsigned short* __restrict__ A,
    const unsigned short* __restrict__ Bt, const float* __restrict__ x1,
    const float* __restrict__ x, const float* __restrict__ gate,
    const int* __restrict__ pos, float* __restrict__ out) {
  alignas(16) __shared__ char As[2][8192];
  alignas(16) __shared__ char Bs[2][16384];
  int tid = threadIdx.x;
  int lane = tid & 63, g = lane >> 4, lr = lane & 15, wid = tid >> 6;
  int swz = xcd_swz(blockIdx.x, 64);   // nwg=512
  int m0 = (swz / 16) * 64, n0 = (swz % 16) * 128;
  f32x4 zero4 = {0.f, 0.f, 0.f, 0.f};
  f32x4 acc[4][2];
#pragma unroll
  for (int m = 0; m < 4; m++)
#pragma unroll
    for (int n = 0; n < 2; n++) acc[m][n] = zero4;
  const int nkt = I_ / 64;
  stageU64(A, I_, m0, 0, As[0], tid);
  stageU128(Bt, I_, n0, 0, Bs[0], tid);
  stageU64(A, I_, m0, 64, As[1], tid);
  stageU128(Bt, I_, n0, 64, Bs[1], tid);
  for (int t = 0; t < nkt; t++) {
    int b = t & 1;
    const char* Ab = As[b];
    const char* Bb = Bs[b];
    if (t + 1 < nkt) asm volatile("s_waitcnt vmcnt(6)" ::: "memory");
    else             asm volatile("s_waitcnt vmcnt(0)" ::: "memory");
    __builtin_amdgcn_s_barrier();
    s16x8 af[2][4], bf[2][2];
#pragma unroll
    for (int k = 0; k < 2; k++) {
#pragma unroll
      for (int i = 0; i < 4; i++) af[k][i] = ldfrag128(Ab, i * 16 + lr, k * 64 + g * 16);
#pragma unroll
      for (int j = 0; j < 2; j++) bf[k][j] = ldfrag128(Bb, wid * 32 + j * 16 + lr, k * 64 + g * 16);
    }
    asm volatile("s_waitcnt lgkmcnt(0)" ::: "memory");
    __builtin_amdgcn_s_barrier();
    if (t + 2 < nkt) {
      stageU64(A, I_, m0, (t + 2) * 64, As[b], tid);
      stageU128(Bt, I_, n0, (t + 2) * 64, Bs[b], tid);
    }
    __builtin_amdgcn_s_setprio(1);
#pragma unroll
    for (int k = 0; k < 2; k++)
#pragma unroll
      for (int m = 0; m < 4; m++)
#pragma unroll
        for (int n = 0; n < 2; n++) acc[m][n] = mfma_bf16(af[k][m], bf[k][n], acc[m][n]);
    __builtin_amdgcn_s_setprio(0);
  }
#pragma unroll
  for (int m = 0; m < 4; m++)
#pragma unroll
    for (int n = 0; n < 2; n++)
#pragma unroll
      for (int r = 0; r < 4; r++) {
        int srow = m0 + m * 16 + (g << 2) + r;
        int col = n0 + wid * 32 + n * 16 + lr;
        float proc = acc[m][n][r] + x1[(size_t)srow * D_ + col];
        float gt = gate[srow];
        float xv = x[(size_t)srow * D_ + col];
        int bb = srow >> 9;
        int p = pos[srow];
        out[((size_t)bb * T_ + p) * D_ + col] = gt * proc + (1.f - gt) * xv;
      }
}

// ---------- K7: RoPE + head relayout (q,k row-major per head; v transposed) ----------
__global__ __launch_bounds__(256) void k_rope(const unsigned short* __restrict__ qkv,
    const float* __restrict__ cosb, const float* __restrict__ sinb,
    unsigned short* __restrict__ qh, unsigned short* __restrict__ kh,
    unsigned short* __restrict__ vT) {
  int s0 = blockIdx.x * 64;
  int h = blockIdx.y;
  int t = threadIdx.x;
#pragma unroll
  for (int i = 0; i < 16; i++) {
    int flat = t + i * 256;
    int r = flat >> 6, dp = flat & 63;
    int s = s0 + r;
    float c = cosb[s * 64 + dp], sn = sinb[s * 64 + dp];
    const unsigned short* qrow = qkv + (size_t)s * D3_ + h * HD_;
    float q1 = bf2f(qrow[dp]), q2 = bf2f(qrow[dp + 64]);
    unsigned short* qdst = qh + ((size_t)h * S_ + s) * HD_;
    qdst[dp] = f2bf(q1 * c - q2 * sn);
    qdst[dp + 64] = f2bf(q2 * c + q1 * sn);
    const unsigned short* krow = qrow + D_;
    float k1 = bf2f(krow[dp]), k2 = bf2f(krow[dp + 64]);
    unsigned short* kdst = kh + ((size_t)h * S_ + s) * HD_;
    kdst[dp] = f2bf(k1 * c - k2 * sn);
    kdst[dp + 64] = f2bf(k2 * c + k1 * sn);
  }
  __shared__ unsigned short vt[128][66];
#pragma unroll
  for (int i = 0; i < 32; i++) {
    int flat = t + i * 256;
    int r = flat >> 7, d = flat & 127;
    vt[d][r] = qkv[(size_t)(s0 + r) * D3_ + 2 * D_ + h * HD_ + d];
  }
  __syncthreads();
#pragma unroll
  for (int i = 0; i < 32; i++) {
    int flat = t + i * 256;
    int d = flat >> 6, sc = flat & 63;
    vT[((size_t)h * HD_ + d) * S_ + s0 + sc] = vt[d][sc];
  }
}

// ======================================================================
// K8: flash attention (q-tile 64, LPT order, swizzled LDS, dbuf KV)
// + T5 setprio around MFMA clusters
// ======================================================================
__device__ __forceinline__ void stage_kv(const unsigned short* __restrict__ kh,
                                         const unsigned short* __restrict__ vT,
                                         size_t hbase, int kt, char* KsB, char* VsB, int tid) {
#pragma unroll
  for (int c = 0; c < 4; c++) {
    int off = c * 4096 + tid * 16;
    int row = off >> 8;
    int cb = (off & 255) ^ ((row & 7) << 4);
    gl_lds16(kh + hbase + (size_t)(kt * 64 + row) * HD_ + (cb >> 1), KsB + off);
  }
#pragma unroll
  for (int c = 0; c < 4; c++) {
    int off = c * 4096 + tid * 16;
    int row = off >> 7;
    int cb = (off & 127) ^ ((row & 7) << 4);
    gl_lds16(vT + hbase + (size_t)row * S_ + kt * 64 + (cb >> 1), VsB + off);
  }
}

__global__ __launch_bounds__(256, 2) void k_attn(const unsigned short* __restrict__ qh,
                                                 const unsigned short* __restrict__ kh,
                                                 const unsigned short* __restrict__ vT,
                                                 unsigned short* __restrict__ ao) {
  alignas(16) __shared__ short Ks[2][64 * 128];
  alignas(16) __shared__ short Vs[2][128 * 64];
  alignas(16) __shared__ short Ps[4][16 * 64];
  int bidx = blockIdx.x;
  int head = bidx & 15;
  int slot = bidx >> 4;
  int qt = (slot < 16) ? (31 - slot) : (slot - 16);
  int q0 = qt * 64;
  int tid = threadIdx.x, w = tid >> 6, lane = tid & 63, g = lane >> 4, lr = lane & 15;
  size_t hbase = (size_t)head * S_ * HD_;
  int qw = q0 + w * 16;
  char* PsW = (char*)&Ps[w][0];
  s16x8 qf[4];
#pragma unroll
  for (int ks = 0; ks < 4; ks++)
    qf[ks] = *(const s16x8*)&qh[hbase + (size_t)(qw + lr) * HD_ + ks * 32 + g * 8];
  f32x4 o[8];
  f32x4 zero4 = {0.f, 0.f, 0.f, 0.f};
#pragma unroll
  for (int nf = 0; nf < 8; nf++) o[nf] = zero4;
  float m_i[4], l_i[4];
#pragma unroll
  for (int r = 0; r < 4; r++) { m_i[r] = -1e30f; l_i[r] = 0.f; }
  const float sc = 0.08838834764831843f;

  stage_kv(kh, vT, hbase, 0, (char*)Ks[0], (char*)Vs[0], tid);
  if (qt > 0) stage_kv(kh, vT, hbase, 1, (char*)Ks[1], (char*)Vs[1], tid);

  for (int kt = 0; kt <= qt; kt++) {
    int b = kt & 1;
    const char* KsB = (const char*)Ks[b];
    const char* VsB = (const char*)Vs[b];
    if (kt < qt) asm volatile("s_waitcnt vmcnt(8)" ::: "memory");
    else         asm volatile("s_waitcnt vmcnt(0)" ::: "memory");
    __builtin_amdgcn_s_barrier();
    f32x4 sacc[4];
#pragma unroll
    for (int nf = 0; nf < 4; nf++) sacc[nf] = zero4;
    __builtin_amdgcn_s_setprio(1);
#pragma unroll
    for (int ks = 0; ks < 4; ks++) {
      s16x8 kf[4];
#pragma unroll
      for (int nf = 0; nf < 4; nf++) {
        int row = nf * 16 + lr;
        kf[nf] = *(const s16x8*)(KsB + row * 256 + (((ks << 6) + (g << 4)) ^ ((row & 7) << 4)));
      }
#pragma unroll
      for (int nf = 0; nf < 4; nf++) sacc[nf] = mfma_bf16(qf[ks], kf[nf], sacc[nf]);
    }
    __builtin_amdgcn_s_setprio(0);
    bool diag = (kt == qt);
#pragma unroll
    for (int r = 0; r < 4; r++) {
      int prow = (g << 2) + r;
      int qrow = qw + prow;
      float pv[4];
      float mx = -1e30f;
#pragma unroll
      for (int nf = 0; nf < 4; nf++) {
        float vv = sacc[nf][r] * sc;
        if (diag) {
          int kc = kt * 64 + nf * 16 + lr;
          vv = (kc <= qrow) ? vv : -1e30f;
        }
        pv[nf] = vv;
        mx = fmaxf(mx, vv);
      }
#pragma unroll
      for (int d = 1; d < 16; d <<= 1) mx = fmaxf(mx, __shfl_xor(mx, d));
      float mold = m_i[r], mnew = fmaxf(mold, mx);
      float corr = __expf(mold - mnew);
      float ssum = 0.f;
#pragma unroll
      for (int nf = 0; nf < 4; nf++) {
        float pe = __expf(pv[nf] - mnew);
        int cb = ((nf * 16 + lr) << 1) ^ ((prow & 7) << 4);
        *(unsigned short*)(PsW + prow * 128 + cb) = f2bf(pe);
        ssum += pe;
      }
#pragma unroll
      for (int d = 1; d < 16; d <<= 1) ssum += __shfl_xor(ssum, d);
      l_i[r] = l_i[r] * corr + ssum;
      m_i[r] = mnew;
#pragma unroll
      for (int nf = 0; nf < 8; nf++) o[nf][r] *= corr;
    }
    s16x8 pa[2];
#pragma unroll
    for (int ks = 0; ks < 2; ks++)
      pa[ks] = *(const s16x8*)(PsW + lr * 128 + (((ks << 6) + (g << 4)) ^ ((lr & 7) << 4)));
    __builtin_amdgcn_s_setprio(1);
#pragma unroll
    for (int nf = 0; nf < 8; nf++) {
#pragma unroll
      for (int ks = 0; ks < 2; ks++) {
        int row = nf * 16 + lr;
        s16x8 vb = *(const s16x8*)(VsB + row * 128 + (((ks << 6) + (g << 4)) ^ ((row & 7) << 4)));
        o[nf] = mfma_bf16(pa[ks], vb, o[nf]);
      }
    }
    __builtin_amdgcn_s_setprio(0);
    asm volatile("s_waitcnt lgkmcnt(0)" ::: "memory");
    __builtin_amdgcn_s_barrier();
    if (kt + 2 <= qt)
      stage_kv(kh, vT, hbase, kt + 2, (char*)Ks[b], (char*)Vs[b], tid);
  }
#pragma unroll
  for (int nf = 0; nf < 8; nf++)
#pragma unroll
    for (int r = 0; r < 4; r++) {
      int row = qw + (g << 2) + r;
      int col = head * HD_ + nf * 16 + lr;
      ao[(size_t)row * D_ + col] = f2bf(o[nf][r] / l_i[r]);
    }
}

// ---------- K10: RMS2 ----------
__global__ __launch_bounds__(256) void k_rms2(const float* __restrict__ x1,
                                              const float* __restrict__ ln2w,
                                              unsigned short* __restrict__ xn2) {
  int s = blockIdx.x, t = threadIdx.x;
  const float* src = x1 + (size_t)s * D_;
  float v[8];
  float ss = 0.f;
#pragma unroll
  for (int i = 0; i < 8; i++) { v[i] = src[t + i * 256]; ss += v[i] * v[i]; }
  __shared__ float red[4];
#pragma unroll
  for (int d = 32; d; d >>= 1) ss += __shfl_xor(ss, d);
  if ((t & 63) == 0) red[t >> 6] = ss;
  __syncthreads();
  ss = red[0] + red[1] + red[2] + red[3];
  float scale = rsqrtf(ss / (float)D_ + 1e-6f);
  unsigned short* dst = xn2 + (size_t)s * D_;
#pragma unroll
  for (int i = 0; i < 8; i++) {
    int c = t + i * 256;
    dst[c] = f2bf(v[i] * scale * ln2w[c]);
  }
}

extern "C" void kernel_launch(void* const* d_in, const int* in_sizes, int n_in,
                              void* d_out, int out_size, void* d_ws, size_t ws_size,
                              hipStream_t stream) {
  (void)in_sizes; (void)n_in; (void)out_size; (void)ws_size;
  const float* hidden = (const float*)d_in[0];
  const float* router_w = (const float*)d_in[1];
  const float* router_b = (const float*)d_in[2];
  const float* ln1w = (const float*)d_in[3];
  const float* ln2w = (const float*)d_in[4];
  const float* wq = (const float*)d_in[5];
  const float* bq = (const float*)d_in[6];
  const float* wk = (const float*)d_in[7];
  const float* bk = (const float*)d_in[8];
  const float* wv = (const float*)d_in[9];
  const float* bv = (const float*)d_in[10];
  const float* wo = (const float*)d_in[11];
  const float* wg = (const float*)d_in[12];
  const float* wu = (const float*)d_in[13];
  const float* wd = (const float*)d_in[14];
  float* out = (float*)d_out;

  char* ws = (char*)d_ws;
  size_t off = 0;
  auto alloc = [&](size_t bytes) {
    char* p = ws + off;
    off += (bytes + 255) & ~(size_t)255;
    return p;
  };
  unsigned short* wqkvT = (unsigned short*)alloc(3ull * D_ * D_ * 2);
  unsigned short* woT = (unsigned short*)alloc((size_t)D_ * D_ * 2);
  unsigned short* wgT = (unsigned short*)alloc((size_t)I_ * D_ * 2);
  unsigned short* wuT = (unsigned short*)alloc((size_t)I_ * D_ * 2);
  unsigned short* wdT = (unsigned short*)alloc((size_t)D_ * I_ * 2);
  float* scores = (float*)alloc((size_t)B_ * T_ * 4);
  int* pos = (int*)alloc((size_t)S_ * 4);
  float* gate = (float*)alloc((size_t)S_ * 4);
  float* x = (float*)alloc((size_t)S_ * D_ * 4);
  float* x1 = (float*)alloc((size_t)S_ * D_ * 4);
  unsigned short* xn = (unsigned short*)alloc((size_t)S_ * D_ * 2);  // reused as x1n
  float* cosb = (float*)alloc((size_t)S_ * 64 * 4);
  float* sinb = (float*)alloc((size_t)S_ * 64 * 4);
  unsigned short* qkv = (unsigned short*)alloc((size_t)S_ * D3_ * 2);  // reused as act
  unsigned short* qh = (unsigned short*)alloc((size_t)H_ * S_ * HD_ * 2);
  unsigned short* kh = (unsigned short*)alloc((size_t)H_ * S_ * HD_ * 2);
  unsigned short* vT = (unsigned short*)alloc((size_t)H_ * S_ * HD_ * 2);
  unsigned short* ao = (unsigned short*)alloc((size_t)S_ * D_ * 2);

  k_copy_scores<<<B_ * T_, 256, 0, stream>>>((const float4*)hidden, (float4*)out,
                                             (const float4*)router_w, router_b, scores);

  k_transpose4<<<dim3(D_ / 32, D_ / 32, 4), 256, 0, stream>>>(
      wq, wk, wv, wo, wqkvT, wqkvT + (size_t)D_ * D_, wqkvT + 2ull * D_ * D_, woT, D_, D_);
  k_transpose2<<<dim3(I_ / 32, D_ / 32, 2), 256, 0, stream>>>(wg, wu, wgT, wuT, D_, I_);
  k_transpose<<<dim3(D_ / 32, I_ / 32), 256, 0, stream>>>(wd, wdT, I_, D_);

  k_topk<<<B_, 1024, 0, stream>>>(scores, pos);
  k_gather<<<S_, 256, 0, stream>>>(hidden, pos, scores, ln1w, x, xn, gate, cosb, sinb);

  k_gemm_qkv8p<<<192, 512, 0, stream>>>(xn, wqkvT, qkv, bq, bk, bv);
  k_rope<<<dim3(S_ / 64, H_), 256, 0, stream>>>(qkv, cosb, sinb, qh, kh, vT);
  k_attn<<<32 * H_, 256, 0, stream>>>(qh, kh, vT, ao);
  k_gemm_wo64<<<512, 256, 0, stream>>>(ao, woT, x, x1);
  k_rms2<<<S_, 256, 0, stream>>>(x1, ln2w, xn);
  k_gemm_gup8p<<<352, 512, 0, stream>>>(xn, wgT, wuT, qkv);
  k_gemm_down64<<<512, 256, 0, stream>>>(qkv, wdT, x1, x, gate, pos, out);
}